// Round 1
// baseline (5273.135 us; speedup 1.0000x reference)
//
#include <hip/hip_runtime.h>
#include <math.h>

// Problem constants (match reference)
#define NN 20000
#define EE 320000
#define DD 256
#define HH 8
#define DHD 32
#define EDF 64
#define FFD 1024

// workspace float offsets
#define XN_OFF   (0)
#define Q_OFF    (5120000)
#define K_OFF    (10240000)
#define V_OFF    (15360000)
#define EP_OFF   (20480000)
#define SC_OFF   (30720000)
#define MORD_OFF (33280000)
#define SSUM_OFF (33440000)
#define AGG_OFF  (33600000)
#define X1_OFF   (38720000)
#define FF1_OFF  (Q_OFF)   // reuse q/k/v/ep region (free by FFN time)

__device__ __forceinline__ unsigned f2ord(float f) {
    unsigned u = __float_as_uint(f);
    return (u & 0x80000000u) ? ~u : (u | 0x80000000u);
}
__device__ __forceinline__ float ord2f(unsigned u) {
    return (u & 0x80000000u) ? __uint_as_float(u & 0x7FFFFFFFu) : __uint_as_float(~u);
}
__device__ __forceinline__ float gelu_exact(float v) {
    return 0.5f * v * (1.0f + erff(v * 0.70710678118654752f));
}

// -------- LayerNorm: one wave per row (D=256 = 64 lanes x float4) --------
__global__ __launch_bounds__(256) void ln_kernel(const float* __restrict__ x,
                                                 const float* __restrict__ g,
                                                 const float* __restrict__ b,
                                                 float* __restrict__ out) {
    int row = blockIdx.x * 4 + (threadIdx.x >> 6);
    if (row >= NN) return;
    int lane = threadIdx.x & 63;
    float4 v = *(const float4*)&x[(size_t)row * DD + lane * 4];
    float s  = v.x + v.y + v.z + v.w;
    float ss = v.x * v.x + v.y * v.y + v.z * v.z + v.w * v.w;
    #pragma unroll
    for (int o = 32; o >= 1; o >>= 1) {
        s  += __shfl_xor(s, o);
        ss += __shfl_xor(ss, o);
    }
    float mean = s * (1.0f / DD);
    float var  = ss * (1.0f / DD) - mean * mean;
    float inv  = rsqrtf(var + 1e-5f);
    float4 gg = *(const float4*)&g[lane * 4];
    float4 bb = *(const float4*)&b[lane * 4];
    float4 o4;
    o4.x = (v.x - mean) * inv * gg.x + bb.x;
    o4.y = (v.y - mean) * inv * gg.y + bb.y;
    o4.z = (v.z - mean) * inv * gg.z + bb.z;
    o4.w = (v.w - mean) * inv * gg.w + bb.w;
    *(float4*)&out[(size_t)row * DD + lane * 4] = o4;
}

// -------- generic 64x64-tile fp32 GEMM: C = A[MxK] @ W[KxNc] + bias --------
// EPI: 0 = plain, 1 = gelu, 2 = C = res + scale*(A@W+bias)
template <int EPI>
__global__ __launch_bounds__(256) void gemm64(const float* __restrict__ A,
                                              const float* __restrict__ W,
                                              const float* __restrict__ bias,
                                              float* __restrict__ C,
                                              const float* __restrict__ res,
                                              const float* __restrict__ scale,
                                              int M, int K, int Nc) {
    __shared__ float As[16][65];
    __shared__ float Bs[16][65];
    const int bm = blockIdx.x * 64;
    const int bn = blockIdx.y * 64;
    const int tid = threadIdx.x;
    const int tx = tid & 15;
    const int ty = tid >> 4;
    float acc[4][4] = {};

    const int lm = tid >> 2;
    const int lk = (tid & 3) << 2;
    const int wk = tid >> 4;
    const int wn = (tid & 15) << 2;
    const bool arow_ok = (bm + lm) < M;
    const float* Aptr = A + (size_t)(bm + lm) * K + lk;
    const float* Wptr = W + (size_t)wk * Nc + bn + wn;

    for (int k0 = 0; k0 < K; k0 += 16) {
        float4 a = arow_ok ? *(const float4*)(Aptr + k0) : make_float4(0.f, 0.f, 0.f, 0.f);
        float4 w = *(const float4*)(Wptr + (size_t)k0 * Nc);
        As[lk + 0][lm] = a.x; As[lk + 1][lm] = a.y; As[lk + 2][lm] = a.z; As[lk + 3][lm] = a.w;
        Bs[wk][wn + 0] = w.x; Bs[wk][wn + 1] = w.y; Bs[wk][wn + 2] = w.z; Bs[wk][wn + 3] = w.w;
        __syncthreads();
        #pragma unroll
        for (int k = 0; k < 16; k++) {
            float av[4], bv[4];
            #pragma unroll
            for (int i = 0; i < 4; i++) av[i] = As[k][ty * 4 + i];
            #pragma unroll
            for (int j = 0; j < 4; j++) bv[j] = Bs[k][tx * 4 + j];
            #pragma unroll
            for (int i = 0; i < 4; i++)
                #pragma unroll
                for (int j = 0; j < 4; j++) acc[i][j] += av[i] * bv[j];
        }
        __syncthreads();
    }

    float sc = 0.f;
    if constexpr (EPI == 2) sc = scale[0];
    const int col = bn + tx * 4;
    float4 bb = *(const float4*)(bias + col);
    #pragma unroll
    for (int i = 0; i < 4; i++) {
        int row = bm + ty * 4 + i;
        if (row >= M) break;
        float4 o;
        o.x = acc[i][0] + bb.x;
        o.y = acc[i][1] + bb.y;
        o.z = acc[i][2] + bb.z;
        o.w = acc[i][3] + bb.w;
        if constexpr (EPI == 1) {
            o.x = gelu_exact(o.x); o.y = gelu_exact(o.y);
            o.z = gelu_exact(o.z); o.w = gelu_exact(o.w);
        }
        if constexpr (EPI == 2) {
            float4 r = *(const float4*)(res + (size_t)row * Nc + col);
            o.x = r.x + sc * o.x; o.y = r.y + sc * o.y;
            o.z = r.z + sc * o.z; o.w = r.w + sc * o.w;
        }
        *(float4*)(C + (size_t)row * Nc + col) = o;
    }
}

// -------- edge projection: ep[E x 32] = ef[E x 64] @ We[64 x 32] + be --------
__global__ __launch_bounds__(256) void ep_kernel(const float* __restrict__ ef,
                                                 const float* __restrict__ We,
                                                 const float* __restrict__ be,
                                                 float* __restrict__ eproj) {
    __shared__ float Ws[EDF * DHD];
    __shared__ float efs[8][EDF];
    int tid = threadIdx.x;
    for (int i = tid; i < EDF * DHD; i += 256) Ws[i] = We[i];
    int e0 = blockIdx.x * 8;
    for (int i = tid; i < 8 * EDF; i += 256) {
        int r = i >> 6, c = i & 63;
        efs[r][c] = ef[(size_t)(e0 + r) * EDF + c];
    }
    __syncthreads();
    int er = tid >> 5, dh = tid & 31;
    int e = e0 + er;
    float acc = be[dh];
    #pragma unroll
    for (int c = 0; c < EDF; c++) acc += efs[er][c] * Ws[c * DHD + dh];
    eproj[(size_t)e * DHD + dh] = acc;
}

// -------- per-edge, per-head scores + segment max --------
__global__ __launch_bounds__(256) void scores_kernel(const float* __restrict__ q,
                                                     const float* __restrict__ k,
                                                     const float* __restrict__ eproj,
                                                     const int* __restrict__ ei,
                                                     const float* __restrict__ ew,
                                                     float* __restrict__ scores,
                                                     unsigned* __restrict__ m_ord) {
    int t = blockIdx.x * 256 + threadIdx.x;
    int e = t >> 3, h = t & 7;
    int s = ei[e], d = ei[EE + e];
    const float4* qp = (const float4*)(q + (size_t)d * DD + h * DHD);
    const float4* kp = (const float4*)(k + (size_t)s * DD + h * DHD);
    const float4* pp = (const float4*)(eproj + (size_t)e * DHD);
    float acc = 0.f;
    #pragma unroll
    for (int i = 0; i < 8; i++) {
        float4 a = qp[i], b = kp[i], c = pp[i];
        acc += a.x * (b.x + c.x) + a.y * (b.y + c.y) + a.z * (b.z + c.z) + a.w * (b.w + c.w);
    }
    acc *= 0.17677669529663689f * ew[e];
    scores[t] = acc;
    atomicMax(m_ord + d * HH + h, f2ord(acc));
}

// -------- exp(score - m[dst]) and segment sum --------
__global__ __launch_bounds__(256) void expsum_kernel(const int* __restrict__ ei,
                                                     float* __restrict__ scores,
                                                     const unsigned* __restrict__ m_ord,
                                                     float* __restrict__ ssum) {
    int t = blockIdx.x * 256 + threadIdx.x;
    int e = t >> 3, h = t & 7;
    int d = ei[EE + e];
    float m = ord2f(m_ord[d * HH + h]);
    float ex = expf(scores[t] - m);
    scores[t] = ex;
    atomicAdd(ssum + d * HH + h, ex);
}

// -------- weighted V scatter-aggregate --------
__global__ __launch_bounds__(256) void agg_kernel(const int* __restrict__ ei,
                                                  const float* __restrict__ scores,
                                                  const float* __restrict__ ssum,
                                                  const float* __restrict__ v,
                                                  float* __restrict__ agg) {
    int t = blockIdx.x * 256 + threadIdx.x;
    int e = t >> 3, h = t & 7;
    int s = ei[e], d = ei[EE + e];
    float w = scores[t] / ssum[d * HH + h];
    const float4* vp = (const float4*)(v + (size_t)s * DD + h * DHD);
    float* ap = agg + (size_t)d * DD + h * DHD;
    #pragma unroll
    for (int i = 0; i < 8; i++) {
        float4 vv = vp[i];
        atomicAdd(ap + i * 4 + 0, w * vv.x);
        atomicAdd(ap + i * 4 + 1, w * vv.y);
        atomicAdd(ap + i * 4 + 2, w * vv.z);
        atomicAdd(ap + i * 4 + 3, w * vv.w);
    }
}

extern "C" void kernel_launch(void* const* d_in, const int* in_sizes, int n_in,
                              void* d_out, int out_size, void* d_ws, size_t ws_size,
                              hipStream_t stream) {
    const float* x    = (const float*)d_in[0];
    const float* ef   = (const float*)d_in[1];
    const float* ew   = (const float*)d_in[2];
    const int*   ei   = (const int*)d_in[3];
    const float* Wq   = (const float*)d_in[4];
    const float* bq   = (const float*)d_in[5];
    const float* Wk   = (const float*)d_in[6];
    const float* bk   = (const float*)d_in[7];
    const float* Wv   = (const float*)d_in[8];
    const float* bv   = (const float*)d_in[9];
    const float* We   = (const float*)d_in[10];
    const float* be   = (const float*)d_in[11];
    const float* Wo   = (const float*)d_in[12];
    const float* bo   = (const float*)d_in[13];
    const float* ln1g = (const float*)d_in[14];
    const float* ln1b = (const float*)d_in[15];
    const float* ln2g = (const float*)d_in[16];
    const float* ln2b = (const float*)d_in[17];
    const float* W1   = (const float*)d_in[18];
    const float* b1   = (const float*)d_in[19];
    const float* W2   = (const float*)d_in[20];
    const float* b2   = (const float*)d_in[21];
    const float* alpha = (const float*)d_in[22];
    const float* beta  = (const float*)d_in[23];

    float* ws     = (float*)d_ws;
    float* xn     = ws + XN_OFF;
    float* q      = ws + Q_OFF;
    float* kbuf   = ws + K_OFF;
    float* vbuf   = ws + V_OFF;
    float* eproj  = ws + EP_OFF;
    float* scores = ws + SC_OFF;
    unsigned* m_ord = (unsigned*)(ws + MORD_OFF);
    float* ssum   = ws + SSUM_OFF;
    float* agg    = ws + AGG_OFF;
    float* x1     = ws + X1_OFF;
    float* ff1    = ws + FF1_OFF;
    float* out    = (float*)d_out;

    // zero m_ord (ord(0)=0 < any finite mapping), ssum, agg (contiguous)
    hipMemsetAsync(ws + MORD_OFF, 0, (size_t)(2 * NN * HH + NN * DD) * sizeof(float), stream);

    ln_kernel<<<NN / 4, 256, 0, stream>>>(x, ln1g, ln1b, xn);

    dim3 gD((NN + 63) / 64, DD / 64);
    gemm64<0><<<gD, 256, 0, stream>>>(xn, Wq, bq, q,    nullptr, nullptr, NN, DD, DD);
    gemm64<0><<<gD, 256, 0, stream>>>(xn, Wk, bk, kbuf, nullptr, nullptr, NN, DD, DD);
    gemm64<0><<<gD, 256, 0, stream>>>(xn, Wv, bv, vbuf, nullptr, nullptr, NN, DD, DD);

    ep_kernel<<<EE / 8, 256, 0, stream>>>(ef, We, be, eproj);

    scores_kernel<<<EE * HH / 256, 256, 0, stream>>>(q, kbuf, eproj, ei, ew, scores, m_ord);
    expsum_kernel<<<EE * HH / 256, 256, 0, stream>>>(ei, scores, m_ord, ssum);
    agg_kernel<<<EE * HH / 256, 256, 0, stream>>>(ei, scores, ssum, vbuf, agg);

    gemm64<2><<<gD, 256, 0, stream>>>(agg, Wo, bo, x1, x, alpha, NN, DD, DD);

    ln_kernel<<<NN / 4, 256, 0, stream>>>(x1, ln2g, ln2b, xn);

    dim3 gF((NN + 63) / 64, FFD / 64);
    gemm64<1><<<gF, 256, 0, stream>>>(xn, W1, b1, ff1, nullptr, nullptr, NN, DD, FFD);
    gemm64<2><<<gD, 256, 0, stream>>>(ff1, W2, b2, out, x1, beta, NN, FFD, DD);
}

// Round 2
// 968.277 us; speedup vs baseline: 5.4459x; 5.4459x over previous
//
#include <hip/hip_runtime.h>
#include <math.h>

// Problem constants (match reference)
#define NN 20000
#define EE 320000
#define DD 256
#define HH 8
#define DHD 32
#define EDF 64
#define FFD 1024

// workspace float offsets
#define XN_OFF   (0)
#define Q_OFF    (5120000)
#define K_OFF    (10240000)
#define V_OFF    (15360000)
#define EP_OFF   (20480000)
#define AGG_OFF  (30720000)
#define X1_OFF   (35840000)
#define FF1_OFF  (Q_OFF)        // reuse q..ep region (free by FFN time)
#define CSR_OFF  (40960000)     // int region: counts, row_start, cursor, eids

__device__ __forceinline__ float gelu_exact(float v) {
    return 0.5f * v * (1.0f + erff(v * 0.70710678118654752f));
}

// -------- LayerNorm: one wave per row (D=256 = 64 lanes x float4) --------
__global__ __launch_bounds__(256) void ln_kernel(const float* __restrict__ x,
                                                 const float* __restrict__ g,
                                                 const float* __restrict__ b,
                                                 float* __restrict__ out) {
    int row = blockIdx.x * 4 + (threadIdx.x >> 6);
    if (row >= NN) return;
    int lane = threadIdx.x & 63;
    float4 v = *(const float4*)&x[(size_t)row * DD + lane * 4];
    float s  = v.x + v.y + v.z + v.w;
    float ss = v.x * v.x + v.y * v.y + v.z * v.z + v.w * v.w;
    #pragma unroll
    for (int o = 32; o >= 1; o >>= 1) {
        s  += __shfl_xor(s, o);
        ss += __shfl_xor(ss, o);
    }
    float mean = s * (1.0f / DD);
    float var  = ss * (1.0f / DD) - mean * mean;
    float inv  = rsqrtf(var + 1e-5f);
    float4 gg = *(const float4*)&g[lane * 4];
    float4 bb = *(const float4*)&b[lane * 4];
    float4 o4;
    o4.x = (v.x - mean) * inv * gg.x + bb.x;
    o4.y = (v.y - mean) * inv * gg.y + bb.y;
    o4.z = (v.z - mean) * inv * gg.z + bb.z;
    o4.w = (v.w - mean) * inv * gg.w + bb.w;
    *(float4*)&out[(size_t)row * DD + lane * 4] = o4;
}

// -------- generic 64x64-tile fp32 GEMM: C = A[MxK] @ W[KxNc] + bias --------
// EPI: 0 = plain, 1 = gelu, 2 = C = res + scale*(A@W+bias)
template <int EPI>
__global__ __launch_bounds__(256) void gemm64(const float* __restrict__ A,
                                              const float* __restrict__ W,
                                              const float* __restrict__ bias,
                                              float* __restrict__ C,
                                              const float* __restrict__ res,
                                              const float* __restrict__ scale,
                                              int M, int K, int Nc) {
    __shared__ float As[16][65];
    __shared__ float Bs[16][65];
    const int bm = blockIdx.x * 64;
    const int bn = blockIdx.y * 64;
    const int tid = threadIdx.x;
    const int tx = tid & 15;
    const int ty = tid >> 4;
    float acc[4][4] = {};

    const int lm = tid >> 2;
    const int lk = (tid & 3) << 2;
    const int wk = tid >> 4;
    const int wn = (tid & 15) << 2;
    const bool arow_ok = (bm + lm) < M;
    const float* Aptr = A + (size_t)(bm + lm) * K + lk;
    const float* Wptr = W + (size_t)wk * Nc + bn + wn;

    for (int k0 = 0; k0 < K; k0 += 16) {
        float4 a = arow_ok ? *(const float4*)(Aptr + k0) : make_float4(0.f, 0.f, 0.f, 0.f);
        float4 w = *(const float4*)(Wptr + (size_t)k0 * Nc);
        As[lk + 0][lm] = a.x; As[lk + 1][lm] = a.y; As[lk + 2][lm] = a.z; As[lk + 3][lm] = a.w;
        Bs[wk][wn + 0] = w.x; Bs[wk][wn + 1] = w.y; Bs[wk][wn + 2] = w.z; Bs[wk][wn + 3] = w.w;
        __syncthreads();
        #pragma unroll
        for (int k = 0; k < 16; k++) {
            float av[4], bv[4];
            #pragma unroll
            for (int i = 0; i < 4; i++) av[i] = As[k][ty * 4 + i];
            #pragma unroll
            for (int j = 0; j < 4; j++) bv[j] = Bs[k][tx * 4 + j];
            #pragma unroll
            for (int i = 0; i < 4; i++)
                #pragma unroll
                for (int j = 0; j < 4; j++) acc[i][j] += av[i] * bv[j];
        }
        __syncthreads();
    }

    float sc = 0.f;
    if constexpr (EPI == 2) sc = scale[0];
    const int col = bn + tx * 4;
    float4 bb = *(const float4*)(bias + col);
    #pragma unroll
    for (int i = 0; i < 4; i++) {
        int row = bm + ty * 4 + i;
        if (row >= M) break;
        float4 o;
        o.x = acc[i][0] + bb.x;
        o.y = acc[i][1] + bb.y;
        o.z = acc[i][2] + bb.z;
        o.w = acc[i][3] + bb.w;
        if constexpr (EPI == 1) {
            o.x = gelu_exact(o.x); o.y = gelu_exact(o.y);
            o.z = gelu_exact(o.z); o.w = gelu_exact(o.w);
        }
        if constexpr (EPI == 2) {
            float4 r = *(const float4*)(res + (size_t)row * Nc + col);
            o.x = r.x + sc * o.x; o.y = r.y + sc * o.y;
            o.z = r.z + sc * o.z; o.w = r.w + sc * o.w;
        }
        *(float4*)(C + (size_t)row * Nc + col) = o;
    }
}

// -------- edge projection: ep[E x 32] = ef[E x 64] @ We[64 x 32] + be --------
__global__ __launch_bounds__(256) void ep_kernel(const float* __restrict__ ef,
                                                 const float* __restrict__ We,
                                                 const float* __restrict__ be,
                                                 float* __restrict__ eproj) {
    __shared__ float Ws[EDF * DHD];
    __shared__ float efs[8][EDF];
    int tid = threadIdx.x;
    for (int i = tid; i < EDF * DHD; i += 256) Ws[i] = We[i];
    int e0 = blockIdx.x * 8;
    for (int i = tid; i < 8 * EDF; i += 256) {
        int r = i >> 6, c = i & 63;
        efs[r][c] = ef[(size_t)(e0 + r) * EDF + c];
    }
    __syncthreads();
    int er = tid >> 5, dh = tid & 31;
    int e = e0 + er;
    float acc = be[dh];
    #pragma unroll
    for (int c = 0; c < EDF; c++) acc += efs[er][c] * Ws[c * DHD + dh];
    eproj[(size_t)e * DHD + dh] = acc;
}

// ======== CSR build over dst ========
__global__ __launch_bounds__(256) void count_kernel(const int* __restrict__ ei,
                                                    int* __restrict__ counts) {
    int e = blockIdx.x * 256 + threadIdx.x;
    if (e >= EE) return;
    atomicAdd(&counts[ei[EE + e]], 1);
}

__global__ __launch_bounds__(1024) void scan_kernel(const int* __restrict__ counts,
                                                    int* __restrict__ row_start,
                                                    int* __restrict__ cursor) {
    __shared__ int part[1024];
    const int CH = 20;
    int t = threadIdx.x;
    int base = t * CH;
    int loc[CH];
    int s = 0;
    #pragma unroll
    for (int i = 0; i < CH; i++) {
        int idx = base + i;
        int c = (idx < NN) ? counts[idx] : 0;
        loc[i] = s;
        s += c;
    }
    part[t] = s;
    __syncthreads();
    for (int o = 1; o < 1024; o <<= 1) {
        int vv = (t >= o) ? part[t - o] : 0;
        __syncthreads();
        part[t] += vv;
        __syncthreads();
    }
    int off = (t > 0) ? part[t - 1] : 0;
    #pragma unroll
    for (int i = 0; i < CH; i++) {
        int idx = base + i;
        if (idx < NN) {
            int rs = off + loc[i];
            row_start[idx] = rs;
            cursor[idx] = rs;
        }
    }
    if (t == 1023) row_start[NN] = part[1023];
}

__global__ __launch_bounds__(256) void fill_kernel(const int* __restrict__ ei,
                                                   int* __restrict__ cursor,
                                                   int* __restrict__ eids) {
    int e = blockIdx.x * 256 + threadIdx.x;
    if (e >= EE) return;
    int dst = ei[EE + e];
    int pos = atomicAdd(&cursor[dst], 1);
    eids[pos] = e;
}

// ======== fused gather attention: one block per dst node ========
// 256 threads = 8 heads x 32 dims; online softmax over incoming edges.
__global__ __launch_bounds__(256) void attn_kernel(const float* __restrict__ q,
                                                   const float* __restrict__ k,
                                                   const float* __restrict__ v,
                                                   const float* __restrict__ eproj,
                                                   const float* __restrict__ ew,
                                                   const int* __restrict__ ei,
                                                   const int* __restrict__ row_start,
                                                   const int* __restrict__ eids,
                                                   float* __restrict__ agg) {
    int dst = blockIdx.x;
    int tid = threadIdx.x;
    int d = tid & 31;
    int beg = row_start[dst];
    int end = row_start[dst + 1];
    float qv = q[(size_t)dst * DD + tid];
    float m = -INFINITY, ss = 0.f, acc = 0.f;
    for (int i = beg; i < end; ++i) {
        int e = eids[i];
        int s = ei[e];
        float kv  = k[(size_t)s * DD + tid];
        float epv = eproj[(size_t)e * DHD + d];
        float vv  = v[(size_t)s * DD + tid];
        float wgt = ew[e];
        float p = qv * (kv + epv);
        #pragma unroll
        for (int o = 16; o >= 1; o >>= 1) p += __shfl_xor(p, o);
        float score = p * 0.17677669529663689f * wgt;
        float mnew = fmaxf(m, score);
        float corr = __expf(m - mnew);        // m=-inf on first edge -> 0
        float w = __expf(score - mnew);
        ss  = ss * corr + w;
        acc = acc * corr + w * vv;
        m = mnew;
    }
    agg[(size_t)dst * DD + tid] = (end > beg) ? (acc / ss) : 0.f;
}

extern "C" void kernel_launch(void* const* d_in, const int* in_sizes, int n_in,
                              void* d_out, int out_size, void* d_ws, size_t ws_size,
                              hipStream_t stream) {
    const float* x    = (const float*)d_in[0];
    const float* ef   = (const float*)d_in[1];
    const float* ew   = (const float*)d_in[2];
    const int*   ei   = (const int*)d_in[3];
    const float* Wq   = (const float*)d_in[4];
    const float* bq   = (const float*)d_in[5];
    const float* Wk   = (const float*)d_in[6];
    const float* bk   = (const float*)d_in[7];
    const float* Wv   = (const float*)d_in[8];
    const float* bv   = (const float*)d_in[9];
    const float* We   = (const float*)d_in[10];
    const float* be   = (const float*)d_in[11];
    const float* Wo   = (const float*)d_in[12];
    const float* bo   = (const float*)d_in[13];
    const float* ln1g = (const float*)d_in[14];
    const float* ln1b = (const float*)d_in[15];
    const float* ln2g = (const float*)d_in[16];
    const float* ln2b = (const float*)d_in[17];
    const float* W1   = (const float*)d_in[18];
    const float* b1   = (const float*)d_in[19];
    const float* W2   = (const float*)d_in[20];
    const float* b2   = (const float*)d_in[21];
    const float* alpha = (const float*)d_in[22];
    const float* beta  = (const float*)d_in[23];

    float* ws     = (float*)d_ws;
    float* xn     = ws + XN_OFF;
    float* q      = ws + Q_OFF;
    float* kbuf   = ws + K_OFF;
    float* vbuf   = ws + V_OFF;
    float* eproj  = ws + EP_OFF;
    float* agg    = ws + AGG_OFF;
    float* x1     = ws + X1_OFF;
    float* ff1    = ws + FF1_OFF;
    float* out    = (float*)d_out;

    int* counts    = (int*)(ws + CSR_OFF);
    int* row_start = counts + NN;
    int* cursor    = row_start + NN + 1;
    int* eids      = cursor + NN;

    // zero counts
    hipMemsetAsync(counts, 0, (size_t)NN * sizeof(int), stream);

    // CSR build (independent of LN/GEMM results; scheduled first)
    count_kernel<<<EE / 256, 256, 0, stream>>>(ei, counts);
    scan_kernel<<<1, 1024, 0, stream>>>(counts, row_start, cursor);
    fill_kernel<<<EE / 256, 256, 0, stream>>>(ei, cursor, eids);

    ln_kernel<<<NN / 4, 256, 0, stream>>>(x, ln1g, ln1b, xn);

    dim3 gD((NN + 63) / 64, DD / 64);
    gemm64<0><<<gD, 256, 0, stream>>>(xn, Wq, bq, q,    nullptr, nullptr, NN, DD, DD);
    gemm64<0><<<gD, 256, 0, stream>>>(xn, Wk, bk, kbuf, nullptr, nullptr, NN, DD, DD);
    gemm64<0><<<gD, 256, 0, stream>>>(xn, Wv, bv, vbuf, nullptr, nullptr, NN, DD, DD);

    ep_kernel<<<EE / 8, 256, 0, stream>>>(ef, We, be, eproj);

    attn_kernel<<<NN, 256, 0, stream>>>(q, kbuf, vbuf, eproj, ew, ei, row_start, eids, agg);

    gemm64<2><<<gD, 256, 0, stream>>>(agg, Wo, bo, x1, x, alpha, NN, DD, DD);

    ln_kernel<<<NN / 4, 256, 0, stream>>>(x1, ln2g, ln2b, xn);

    dim3 gF((NN + 63) / 64, FFD / 64);
    gemm64<1><<<gF, 256, 0, stream>>>(xn, W1, b1, ff1, nullptr, nullptr, NN, DD, FFD);
    gemm64<2><<<gD, 256, 0, stream>>>(ff1, W2, b2, out, x1, beta, NN, FFD, DD);
}

// Round 3
// 474.367 us; speedup vs baseline: 11.1162x; 2.0412x over previous
//
#include <hip/hip_runtime.h>
#include <math.h>

// Problem constants (match reference)
#define NN 20000
#define EE 320000
#define DD 256
#define HH 8
#define DHD 32
#define EDF 64
#define FFD 1024

typedef unsigned short u16;
typedef __attribute__((ext_vector_type(8))) __bf16 bf16x8;
typedef __attribute__((ext_vector_type(4))) float f32x4;

// workspace float offsets
#define XN_OFF   (0)          // xn bf16 [NN][256]   (2.56M fl)
#define AGGB_OFF (2560000)    // agg bf16 [NN][256]
#define X1_OFF   (5120000)    // x1 fp32 [NN][256]
#define QKV_OFF  (10240000)   // qkv fp32 [NN][768]; ff1 bf16 [NN][1024] overlays later
#define EP_OFF   (25600000)   // eproj fp32 [EE][32]
#define WT_OFF   (35840000)   // bf16 weights: WqkvT, WoT, W1T, W2T
#define BQKV_OFF (36240000)   // bqkv fp32 [768]
#define CSR_OFF  (36250000)   // int region

__device__ __forceinline__ u16 f2bf(float f) {
    unsigned u = __float_as_uint(f);
    return (u16)((u + 0x7FFFu + ((u >> 16) & 1u)) >> 16);
}
__device__ __forceinline__ float gelu_exact(float v) {
    return 0.5f * v * (1.0f + erff(v * 0.70710678118654752f));
}

#define GLDS16(g, l) __builtin_amdgcn_global_load_lds(             \
    (__attribute__((address_space(1))) void*)(g),                  \
    (__attribute__((address_space(3))) void*)(l), 16, 0, 0)

// -------- LayerNorm -> bf16: one wave per row --------
__global__ __launch_bounds__(256) void ln_kernel(const float* __restrict__ x,
                                                 const float* __restrict__ g,
                                                 const float* __restrict__ b,
                                                 u16* __restrict__ out) {
    int row = blockIdx.x * 4 + (threadIdx.x >> 6);
    if (row >= NN) return;
    int lane = threadIdx.x & 63;
    float4 v = *(const float4*)&x[(size_t)row * DD + lane * 4];
    float s  = v.x + v.y + v.z + v.w;
    float ss = v.x * v.x + v.y * v.y + v.z * v.z + v.w * v.w;
    #pragma unroll
    for (int o = 32; o >= 1; o >>= 1) {
        s  += __shfl_xor(s, o);
        ss += __shfl_xor(ss, o);
    }
    float mean = s * (1.0f / DD);
    float var  = ss * (1.0f / DD) - mean * mean;
    float inv  = rsqrtf(var + 1e-5f);
    float4 gg = *(const float4*)&g[lane * 4];
    float4 bb = *(const float4*)&b[lane * 4];
    ushort4 o4;
    o4.x = f2bf((v.x - mean) * inv * gg.x + bb.x);
    o4.y = f2bf((v.y - mean) * inv * gg.y + bb.y);
    o4.z = f2bf((v.z - mean) * inv * gg.z + bb.z);
    o4.w = f2bf((v.w - mean) * inv * gg.w + bb.w);
    *(ushort4*)&out[(size_t)row * DD + lane * 4] = o4;
}

// -------- weight transpose+convert: dst[n][k] = bf16(src[k][n]) --------
__global__ __launch_bounds__(256) void convw(const float* __restrict__ src,
                                             u16* __restrict__ dst, int K, int N) {
    int n = blockIdx.x * 4 + (threadIdx.x >> 6);
    int lane = threadIdx.x & 63;
    if (n >= N) return;
    for (int k = lane * 4; k < K; k += 256) {
        ushort4 o;
        o.x = f2bf(src[(size_t)(k + 0) * N + n]);
        o.y = f2bf(src[(size_t)(k + 1) * N + n]);
        o.z = f2bf(src[(size_t)(k + 2) * N + n]);
        o.w = f2bf(src[(size_t)(k + 3) * N + n]);
        *(ushort4*)&dst[(size_t)n * K + k] = o;
    }
}

__global__ void bias_cat(const float* __restrict__ bq, const float* __restrict__ bk,
                         const float* __restrict__ bv, float* __restrict__ bqkv) {
    int t = threadIdx.x;
    bqkv[t] = bq[t];
    bqkv[256 + t] = bk[t];
    bqkv[512 + t] = bv[t];
}

// ======== bf16 MFMA GEMM: C = A[MxK] @ BT[NxK]^T + bias ========
// 128x128 tile, BK=64, 4 waves (2x2), 64x64 per wave, 16x16x32 bf16 MFMA.
// LDS rows are 128B; XOR-swizzle byte ^= ((row&7)<<4): inverse-swz source +
// swz read (global_load_lds writes linearly).
// EPI: 0 = fp32 out, 1 = gelu->bf16 out, 2 = fp32 out = res + scale*(acc+bias)
template <int EPI>
__global__ __launch_bounds__(256) void gemm_bf16(
    const u16* __restrict__ A, const u16* __restrict__ BT,
    const float* __restrict__ bias,
    float* __restrict__ Cf, u16* __restrict__ Cb,
    const float* __restrict__ res, const float* __restrict__ scale,
    int M, int K, int N)
{
    __shared__ u16 Asm[128 * 64];
    __shared__ u16 Bsm[128 * 64];
    const int tid  = threadIdx.x;
    const int lane = tid & 63;
    const int w    = tid >> 6;
    const int wr   = w >> 1, wc = w & 1;
    const int bm   = blockIdx.x * 128;
    const int bn   = blockIdx.y * 128;

    f32x4 acc[4][4] = {};

    int st_row[4], st_src[4], st_dst[4];
    #pragma unroll
    for (int i = 0; i < 4; i++) {
        int base  = i * 4096 + w * 1024;       // wave-uniform LDS byte base
        int off   = base + lane * 16;          // this lane's 16B lands here
        int row   = off >> 7;
        int inner = off & 127;
        st_row[i] = row;
        st_src[i] = (inner ^ ((row & 7) << 4)) >> 1;  // short idx within k-row
        st_dst[i] = base;
    }
    const int arow0 = wr * 64 + (lane & 15);
    const int brow0 = wc * 64 + (lane & 15);
    const int kb0   = (lane >> 4) * 16;        // byte offset of k in 128B row

    for (int k0 = 0; k0 < K; k0 += 64) {
        #pragma unroll
        for (int i = 0; i < 4; i++) {
            int r = bm + st_row[i]; if (r > M - 1) r = M - 1;
            GLDS16(A + (size_t)r * K + k0 + st_src[i], (char*)Asm + st_dst[i]);
        }
        #pragma unroll
        for (int i = 0; i < 4; i++) {
            int r = bn + st_row[i];
            GLDS16(BT + (size_t)r * K + k0 + st_src[i], (char*)Bsm + st_dst[i]);
        }
        asm volatile("s_waitcnt vmcnt(0)" ::: "memory");
        __syncthreads();
        #pragma unroll
        for (int s = 0; s < 2; s++) {
            bf16x8 af[4], bfv[4];
            #pragma unroll
            for (int i = 0; i < 4; i++) {
                int row  = arow0 + i * 16;
                int byte = (row << 7) + ((kb0 + s * 64) ^ ((row & 7) << 4));
                af[i] = *(const bf16x8*)((const char*)Asm + byte);
            }
            #pragma unroll
            for (int j = 0; j < 4; j++) {
                int row  = brow0 + j * 16;
                int byte = (row << 7) + ((kb0 + s * 64) ^ ((row & 7) << 4));
                bfv[j] = *(const bf16x8*)((const char*)Bsm + byte);
            }
            #pragma unroll
            for (int i = 0; i < 4; i++)
                #pragma unroll
                for (int j = 0; j < 4; j++)
                    acc[i][j] = __builtin_amdgcn_mfma_f32_16x16x32_bf16(
                        af[i], bfv[j], acc[i][j], 0, 0, 0);
        }
        __syncthreads();
    }

    float sc = 0.f;
    if constexpr (EPI == 2) sc = scale[0];
    const int col0 = bn + wc * 64 + (lane & 15);
    const int row0 = bm + wr * 64 + ((lane >> 4) << 2);
    #pragma unroll
    for (int i = 0; i < 4; i++) {
        #pragma unroll
        for (int j = 0; j < 4; j++) {
            int col = col0 + j * 16;
            float bb = bias[col];
            #pragma unroll
            for (int r = 0; r < 4; r++) {
                int row = row0 + i * 16 + r;
                if (row < M) {
                    float o = acc[i][j][r] + bb;
                    if constexpr (EPI == 1) {
                        Cb[(size_t)row * N + col] = f2bf(gelu_exact(o));
                    } else if constexpr (EPI == 2) {
                        Cf[(size_t)row * N + col] = res[(size_t)row * N + col] + sc * o;
                    } else {
                        Cf[(size_t)row * N + col] = o;
                    }
                }
            }
        }
    }
}

// -------- edge projection: ep[E x 32] = ef[E x 64] @ We[64 x 32] + be --------
__global__ __launch_bounds__(256) void ep_kernel(const float* __restrict__ ef,
                                                 const float* __restrict__ We,
                                                 const float* __restrict__ be,
                                                 float* __restrict__ eproj) {
    __shared__ float Ws[EDF * DHD];
    __shared__ float efs[8][EDF];
    int tid = threadIdx.x;
    for (int i = tid; i < EDF * DHD; i += 256) Ws[i] = We[i];
    int e0 = blockIdx.x * 8;
    for (int i = tid; i < 8 * EDF; i += 256) {
        int r = i >> 6, c = i & 63;
        efs[r][c] = ef[(size_t)(e0 + r) * EDF + c];
    }
    __syncthreads();
    int er = tid >> 5, dh = tid & 31;
    int e = e0 + er;
    float acc = be[dh];
    #pragma unroll
    for (int c = 0; c < EDF; c++) acc += efs[er][c] * Ws[c * DHD + dh];
    eproj[(size_t)e * DHD + dh] = acc;
}

// ======== CSR build over dst ========
__global__ __launch_bounds__(256) void count_kernel(const int* __restrict__ ei,
                                                    int* __restrict__ counts) {
    int e = blockIdx.x * 256 + threadIdx.x;
    if (e >= EE) return;
    atomicAdd(&counts[ei[EE + e]], 1);
}

__global__ __launch_bounds__(1024) void scan_kernel(const int* __restrict__ counts,
                                                    int* __restrict__ row_start,
                                                    int* __restrict__ cursor) {
    __shared__ int part[1024];
    const int CH = 20;
    int t = threadIdx.x;
    int base = t * CH;
    int loc[CH];
    int s = 0;
    #pragma unroll
    for (int i = 0; i < CH; i++) {
        int idx = base + i;
        int c = (idx < NN) ? counts[idx] : 0;
        loc[i] = s;
        s += c;
    }
    part[t] = s;
    __syncthreads();
    for (int o = 1; o < 1024; o <<= 1) {
        int vv = (t >= o) ? part[t - o] : 0;
        __syncthreads();
        part[t] += vv;
        __syncthreads();
    }
    int off = (t > 0) ? part[t - 1] : 0;
    #pragma unroll
    for (int i = 0; i < CH; i++) {
        int idx = base + i;
        if (idx < NN) {
            int rs = off + loc[i];
            row_start[idx] = rs;
            cursor[idx] = rs;
        }
    }
    if (t == 1023) row_start[NN] = part[1023];
}

__global__ __launch_bounds__(256) void fill_kernel(const int* __restrict__ ei,
                                                   int* __restrict__ cursor,
                                                   int* __restrict__ eids) {
    int e = blockIdx.x * 256 + threadIdx.x;
    if (e >= EE) return;
    int dst = ei[EE + e];
    int pos = atomicAdd(&cursor[dst], 1);
    eids[pos] = e;
}

// ======== fused gather attention: one block per dst node ========
__global__ __launch_bounds__(256) void attn_kernel(const float* __restrict__ qkv,
                                                   const float* __restrict__ eproj,
                                                   const float* __restrict__ ew,
                                                   const int* __restrict__ ei,
                                                   const int* __restrict__ row_start,
                                                   const int* __restrict__ eids,
                                                   u16* __restrict__ aggb) {
    int dst = blockIdx.x;
    int tid = threadIdx.x;
    int d = tid & 31;
    int beg = row_start[dst];
    int end = row_start[dst + 1];
    float qv = qkv[(size_t)dst * 768 + tid];
    float m = -INFINITY, ss = 0.f, acc = 0.f;
    for (int i = beg; i < end; ++i) {
        int e = eids[i];
        int s = ei[e];
        float kv  = qkv[(size_t)s * 768 + 256 + tid];
        float epv = eproj[(size_t)e * DHD + d];
        float vv  = qkv[(size_t)s * 768 + 512 + tid];
        float wgt = ew[e];
        float p = qv * (kv + epv);
        #pragma unroll
        for (int o = 16; o >= 1; o >>= 1) p += __shfl_xor(p, o);
        float score = p * 0.17677669529663689f * wgt;
        float mnew = fmaxf(m, score);
        float corr = __expf(m - mnew);
        float wq = __expf(score - mnew);
        ss  = ss * corr + wq;
        acc = acc * corr + wq * vv;
        m = mnew;
    }
    aggb[(size_t)dst * DD + tid] = f2bf((end > beg) ? (acc / ss) : 0.f);
}

extern "C" void kernel_launch(void* const* d_in, const int* in_sizes, int n_in,
                              void* d_out, int out_size, void* d_ws, size_t ws_size,
                              hipStream_t stream) {
    const float* x    = (const float*)d_in[0];
    const float* ef   = (const float*)d_in[1];
    const float* ew   = (const float*)d_in[2];
    const int*   ei   = (const int*)d_in[3];
    const float* Wq   = (const float*)d_in[4];
    const float* bq   = (const float*)d_in[5];
    const float* Wk   = (const float*)d_in[6];
    const float* bk   = (const float*)d_in[7];
    const float* Wv   = (const float*)d_in[8];
    const float* bv   = (const float*)d_in[9];
    const float* We   = (const float*)d_in[10];
    const float* be   = (const float*)d_in[11];
    const float* Wo   = (const float*)d_in[12];
    const float* bo   = (const float*)d_in[13];
    const float* ln1g = (const float*)d_in[14];
    const float* ln1b = (const float*)d_in[15];
    const float* ln2g = (const float*)d_in[16];
    const float* ln2b = (const float*)d_in[17];
    const float* W1   = (const float*)d_in[18];
    const float* b1   = (const float*)d_in[19];
    const float* W2   = (const float*)d_in[20];
    const float* b2   = (const float*)d_in[21];
    const float* alpha = (const float*)d_in[22];
    const float* beta  = (const float*)d_in[23];

    float* ws    = (float*)d_ws;
    u16*   xn    = (u16*)(ws + XN_OFF);
    u16*   aggb  = (u16*)(ws + AGGB_OFF);
    float* x1    = ws + X1_OFF;
    float* qkv   = ws + QKV_OFF;
    u16*   ff1   = (u16*)(ws + QKV_OFF);   // overlays qkv after attn
    float* eproj = ws + EP_OFF;
    u16*   wt    = (u16*)(ws + WT_OFF);
    u16*   WqkvT = wt;                      // [768][256]
    u16*   WoT   = wt + 768 * 256;          // [256][256]
    u16*   W1T   = WoT + 256 * 256;         // [1024][256]
    u16*   W2T   = W1T + 1024 * 256;        // [256][1024]
    float* bqkv  = ws + BQKV_OFF;
    float* out   = (float*)d_out;

    int* counts    = (int*)(ws + CSR_OFF);
    int* row_start = counts + NN;
    int* cursor    = row_start + NN + 1;
    int* eids      = cursor + NN;

    hipMemsetAsync(counts, 0, (size_t)NN * sizeof(int), stream);

    // weight converts + CSR build (independent of activation dataflow)
    convw<<<64, 256, 0, stream>>>(Wq, WqkvT, 256, 256);
    convw<<<64, 256, 0, stream>>>(Wk, WqkvT + 256 * 256, 256, 256);
    convw<<<64, 256, 0, stream>>>(Wv, WqkvT + 512 * 256, 256, 256);
    convw<<<64, 256, 0, stream>>>(Wo, WoT, 256, 256);
    convw<<<256, 256, 0, stream>>>(W1, W1T, 256, 1024);
    convw<<<64, 256, 0, stream>>>(W2, W2T, 1024, 256);
    bias_cat<<<1, 256, 0, stream>>>(bq, bk, bv, bqkv);

    count_kernel<<<EE / 256, 256, 0, stream>>>(ei, counts);
    scan_kernel<<<1, 1024, 0, stream>>>(counts, row_start, cursor);
    fill_kernel<<<EE / 256, 256, 0, stream>>>(ei, cursor, eids);

    ln_kernel<<<NN / 4, 256, 0, stream>>>(x, ln1g, ln1b, xn);

    // fused QKV GEMM: [20000 x 256] x [256 x 768]
    gemm_bf16<0><<<dim3(157, 6), 256, 0, stream>>>(xn, WqkvT, bqkv, qkv, nullptr,
                                                   nullptr, nullptr, NN, DD, 768);

    ep_kernel<<<EE / 8, 256, 0, stream>>>(ef, We, be, eproj);

    attn_kernel<<<NN, 256, 0, stream>>>(qkv, eproj, ew, ei, row_start, eids, aggb);

    // Wo GEMM + residual: x1 = x + alpha*(agg @ Wo + bo)
    gemm_bf16<2><<<dim3(157, 2), 256, 0, stream>>>(aggb, WoT, bo, x1, nullptr,
                                                   x, alpha, NN, DD, DD);

    ln_kernel<<<NN / 4, 256, 0, stream>>>(x1, ln2g, ln2b, xn);

    // FFN up + GELU -> bf16
    gemm_bf16<1><<<dim3(157, 8), 256, 0, stream>>>(xn, W1T, b1, nullptr, ff1,
                                                   nullptr, nullptr, NN, DD, FFD);
    // FFN down + residual: out = x1 + beta*(ff1 @ W2 + b2)
    gemm_bf16<2><<<dim3(157, 2), 256, 0, stream>>>(ff1, W2T, b2, out, nullptr,
                                                   x1, beta, NN, FFD, DD);
}

// Round 4
// 440.340 us; speedup vs baseline: 11.9752x; 1.0773x over previous
//
#include <hip/hip_runtime.h>
#include <math.h>

// Problem constants (match reference)
#define NN 20000
#define EE 320000
#define DD 256
#define HH 8
#define DHD 32
#define EDF 64
#define FFD 1024

typedef unsigned short u16;
typedef __attribute__((ext_vector_type(8))) __bf16 bf16x8;
typedef __attribute__((ext_vector_type(4))) float f32x4;

// workspace float offsets
#define XN_OFF   (0)          // xn bf16 [NN][256]
#define AGGB_OFF (2560000)    // agg bf16 [NN][256]
#define X1_OFF   (5120000)    // x1 fp32 [NN][256]
#define QKV_OFF  (10240000)   // q fp32 [NN][256] + kv bf16 [NN][512]; ff1 bf16 overlays later
#define EP_OFF   (25600000)   // eproj bf16 [EE][32]
#define WT_OFF   (35840000)   // bf16 weights: WqkvT, WoT, W1T, W2T
#define BQKV_OFF (36240000)   // bqkv fp32 [768]
#define CSR_OFF  (36250000)   // int region

__device__ __forceinline__ u16 f2bf(float f) {
    unsigned u = __float_as_uint(f);
    return (u16)((u + 0x7FFFu + ((u >> 16) & 1u)) >> 16);
}
__device__ __forceinline__ float bf2f(u16 h) {
    return __uint_as_float(((unsigned)h) << 16);
}
__device__ __forceinline__ float gelu_exact(float v) {
    return 0.5f * v * (1.0f + erff(v * 0.70710678118654752f));
}

#define GLDS16(g, l) __builtin_amdgcn_global_load_lds(             \
    (__attribute__((address_space(1))) void*)(g),                  \
    (__attribute__((address_space(3))) void*)(l), 16, 0, 0)

// -------- LayerNorm -> bf16: one wave per row --------
__global__ __launch_bounds__(256) void ln_kernel(const float* __restrict__ x,
                                                 const float* __restrict__ g,
                                                 const float* __restrict__ b,
                                                 u16* __restrict__ out) {
    int row = blockIdx.x * 4 + (threadIdx.x >> 6);
    if (row >= NN) return;
    int lane = threadIdx.x & 63;
    float4 v = *(const float4*)&x[(size_t)row * DD + lane * 4];
    float s  = v.x + v.y + v.z + v.w;
    float ss = v.x * v.x + v.y * v.y + v.z * v.z + v.w * v.w;
    #pragma unroll
    for (int o = 32; o >= 1; o >>= 1) {
        s  += __shfl_xor(s, o);
        ss += __shfl_xor(ss, o);
    }
    float mean = s * (1.0f / DD);
    float var  = ss * (1.0f / DD) - mean * mean;
    float inv  = rsqrtf(var + 1e-5f);
    float4 gg = *(const float4*)&g[lane * 4];
    float4 bb = *(const float4*)&b[lane * 4];
    ushort4 o4;
    o4.x = f2bf((v.x - mean) * inv * gg.x + bb.x);
    o4.y = f2bf((v.y - mean) * inv * gg.y + bb.y);
    o4.z = f2bf((v.z - mean) * inv * gg.z + bb.z);
    o4.w = f2bf((v.w - mean) * inv * gg.w + bb.w);
    *(ushort4*)&out[(size_t)row * DD + lane * 4] = o4;
}

// -------- weight transpose+convert: dst[n][k] = bf16(src[k][n]) --------
__global__ __launch_bounds__(256) void convw(const float* __restrict__ src,
                                             u16* __restrict__ dst, int K, int N) {
    int n = blockIdx.x * 4 + (threadIdx.x >> 6);
    int lane = threadIdx.x & 63;
    if (n >= N) return;
    for (int k = lane * 4; k < K; k += 256) {
        ushort4 o;
        o.x = f2bf(src[(size_t)(k + 0) * N + n]);
        o.y = f2bf(src[(size_t)(k + 1) * N + n]);
        o.z = f2bf(src[(size_t)(k + 2) * N + n]);
        o.w = f2bf(src[(size_t)(k + 3) * N + n]);
        *(ushort4*)&dst[(size_t)n * K + k] = o;
    }
}

__global__ void bias_cat(const float* __restrict__ bq, const float* __restrict__ bk,
                         const float* __restrict__ bv, float* __restrict__ bqkv) {
    int t = threadIdx.x;
    bqkv[t] = bq[t];
    bqkv[256 + t] = bk[t];
    bqkv[512 + t] = bv[t];
}

// ======== bf16 MFMA GEMM: C = A[MxK] @ BT[NxK]^T + bias ========
// 128x128 tile, BK=64, 4 waves (2x2), 64x64 per wave, 16x16x32 bf16 MFMA.
// EPI: 0 = fp32 out, 1 = gelu->bf16 out, 2 = fp32 out = res + scale*(acc+bias)
//      3 = QKV: col<256 -> q fp32 * invsqrt(dh); col>=256 -> kv bf16 dim-interleaved
template <int EPI>
__global__ __launch_bounds__(256) void gemm_bf16(
    const u16* __restrict__ A, const u16* __restrict__ BT,
    const float* __restrict__ bias,
    float* __restrict__ Cf, u16* __restrict__ Cb,
    const float* __restrict__ res, const float* __restrict__ scale,
    int M, int K, int N)
{
    __shared__ u16 Asm[128 * 64];
    __shared__ u16 Bsm[128 * 64];
    const int tid  = threadIdx.x;
    const int lane = tid & 63;
    const int w    = tid >> 6;
    const int wr   = w >> 1, wc = w & 1;
    const int bm   = blockIdx.x * 128;
    const int bn   = blockIdx.y * 128;

    f32x4 acc[4][4] = {};

    int st_row[4], st_src[4], st_dst[4];
    #pragma unroll
    for (int i = 0; i < 4; i++) {
        int base  = i * 4096 + w * 1024;       // wave-uniform LDS byte base
        int off   = base + lane * 16;          // this lane's 16B lands here
        int row   = off >> 7;
        int inner = off & 127;
        st_row[i] = row;
        st_src[i] = (inner ^ ((row & 7) << 4)) >> 1;  // short idx within k-row
        st_dst[i] = base;
    }
    const int arow0 = wr * 64 + (lane & 15);
    const int brow0 = wc * 64 + (lane & 15);
    const int kb0   = (lane >> 4) * 16;        // byte offset of k in 128B row

    for (int k0 = 0; k0 < K; k0 += 64) {
        #pragma unroll
        for (int i = 0; i < 4; i++) {
            int r = bm + st_row[i]; if (r > M - 1) r = M - 1;
            GLDS16(A + (size_t)r * K + k0 + st_src[i], (char*)Asm + st_dst[i]);
        }
        #pragma unroll
        for (int i = 0; i < 4; i++) {
            int r = bn + st_row[i];
            GLDS16(BT + (size_t)r * K + k0 + st_src[i], (char*)Bsm + st_dst[i]);
        }
        asm volatile("s_waitcnt vmcnt(0)" ::: "memory");
        __syncthreads();
        #pragma unroll
        for (int s = 0; s < 2; s++) {
            bf16x8 af[4], bfv[4];
            #pragma unroll
            for (int i = 0; i < 4; i++) {
                int row  = arow0 + i * 16;
                int byte = (row << 7) + ((kb0 + s * 64) ^ ((row & 7) << 4));
                af[i] = *(const bf16x8*)((const char*)Asm + byte);
            }
            #pragma unroll
            for (int j = 0; j < 4; j++) {
                int row  = brow0 + j * 16;
                int byte = (row << 7) + ((kb0 + s * 64) ^ ((row & 7) << 4));
                bfv[j] = *(const bf16x8*)((const char*)Bsm + byte);
            }
            #pragma unroll
            for (int i = 0; i < 4; i++)
                #pragma unroll
                for (int j = 0; j < 4; j++)
                    acc[i][j] = __builtin_amdgcn_mfma_f32_16x16x32_bf16(
                        af[i], bfv[j], acc[i][j], 0, 0, 0);
        }
        __syncthreads();
    }

    float sc = 0.f;
    if constexpr (EPI == 2) sc = scale[0];
    const int col0 = bn + wc * 64 + (lane & 15);
    const int row0 = bm + wr * 64 + ((lane >> 4) << 2);
    #pragma unroll
    for (int i = 0; i < 4; i++) {
        #pragma unroll
        for (int j = 0; j < 4; j++) {
            int col = col0 + j * 16;
            float bb = bias[col];
            #pragma unroll
            for (int r = 0; r < 4; r++) {
                int row = row0 + i * 16 + r;
                if (row < M) {
                    float o = acc[i][j][r] + bb;
                    if constexpr (EPI == 1) {
                        Cb[(size_t)row * N + col] = f2bf(gelu_exact(o));
                    } else if constexpr (EPI == 2) {
                        Cf[(size_t)row * N + col] = res[(size_t)row * N + col] + sc * o;
                    } else if constexpr (EPI == 3) {
                        if (col < 256) {
                            Cf[(size_t)row * 256 + col] = o * 0.17677669529663689f;
                        } else if (col < 512) {
                            Cb[(size_t)row * 512 + (col - 256) * 2] = f2bf(o);
                        } else {
                            Cb[(size_t)row * 512 + (col - 512) * 2 + 1] = f2bf(o);
                        }
                    } else {
                        Cf[(size_t)row * N + col] = o;
                    }
                }
            }
        }
    }
}

// -------- edge projection: ep[E x 32] = bf16(ef[E x 64] @ We[64 x 32] + be) --------
__global__ __launch_bounds__(256) void ep_kernel(const float* __restrict__ ef,
                                                 const float* __restrict__ We,
                                                 const float* __restrict__ be,
                                                 u16* __restrict__ eproj) {
    __shared__ float Ws[EDF * DHD];
    __shared__ float efs[8][EDF];
    int tid = threadIdx.x;
    for (int i = tid; i < EDF * DHD; i += 256) Ws[i] = We[i];
    int e0 = blockIdx.x * 8;
    for (int i = tid; i < 8 * EDF; i += 256) {
        int r = i >> 6, c = i & 63;
        efs[r][c] = ef[(size_t)(e0 + r) * EDF + c];
    }
    __syncthreads();
    int er = tid >> 5, dh = tid & 31;
    int e = e0 + er;
    float acc = be[dh];
    #pragma unroll
    for (int c = 0; c < EDF; c++) acc += efs[er][c] * Ws[c * DHD + dh];
    eproj[(size_t)e * DHD + dh] = f2bf(acc);
}

// ======== CSR build over dst ========
__global__ __launch_bounds__(256) void count_kernel(const int* __restrict__ ei,
                                                    int* __restrict__ counts) {
    int e = blockIdx.x * 256 + threadIdx.x;
    if (e >= EE) return;
    atomicAdd(&counts[ei[EE + e]], 1);
}

__global__ __launch_bounds__(1024) void scan_kernel(const int* __restrict__ counts,
                                                    int* __restrict__ row_start,
                                                    int* __restrict__ cursor) {
    __shared__ int part[1024];
    const int CH = 20;
    int t = threadIdx.x;
    int base = t * CH;
    int loc[CH];
    int s = 0;
    #pragma unroll
    for (int i = 0; i < CH; i++) {
        int idx = base + i;
        int c = (idx < NN) ? counts[idx] : 0;
        loc[i] = s;
        s += c;
    }
    part[t] = s;
    __syncthreads();
    for (int o = 1; o < 1024; o <<= 1) {
        int vv = (t >= o) ? part[t - o] : 0;
        __syncthreads();
        part[t] += vv;
        __syncthreads();
    }
    int off = (t > 0) ? part[t - 1] : 0;
    #pragma unroll
    for (int i = 0; i < CH; i++) {
        int idx = base + i;
        if (idx < NN) {
            int rs = off + loc[i];
            row_start[idx] = rs;
            cursor[idx] = rs;
        }
    }
    if (t == 1023) row_start[NN] = part[1023];
}

// fill CSR with (src, edge) pairs -> removes one dependent-load level in attn
__global__ __launch_bounds__(256) void fill_kernel(const int* __restrict__ ei,
                                                   int* __restrict__ cursor,
                                                   int2* __restrict__ csr) {
    int e = blockIdx.x * 256 + threadIdx.x;
    if (e >= EE) return;
    int src = ei[e];
    int dst = ei[EE + e];
    int pos = atomicAdd(&cursor[dst], 1);
    csr[pos] = make_int2(src, e);
}

// ======== fused gather attention: one block per dst node ========
// q pre-scaled by dh^-0.5; kv bf16 dim-interleaved; depth-1 software pipeline.
__global__ __launch_bounds__(256) void attn_kernel(const float* __restrict__ q,
                                                   const u16* __restrict__ kv,
                                                   const u16* __restrict__ eproj,
                                                   const float* __restrict__ ew,
                                                   const int2* __restrict__ csr,
                                                   const int* __restrict__ row_start,
                                                   u16* __restrict__ aggb) {
    int dst = blockIdx.x;
    int tid = threadIdx.x;
    int d = tid & 31;
    int beg = row_start[dst];
    int end = row_start[dst + 1];
    float qv = q[(size_t)dst * DD + tid];
    float m = -INFINITY, ss = 0.f, acc = 0.f;

    float kn = 0.f, vn = 0.f, en = 0.f, wn = 0.f;
    if (beg < end) {
        int2 p = csr[beg];
        ushort2 kvp = *(const ushort2*)&kv[(size_t)p.x * 512 + tid * 2];
        kn = bf2f(kvp.x); vn = bf2f(kvp.y);
        en = bf2f(eproj[(size_t)p.y * DHD + d]);
        wn = ew[p.y];
    }
    for (int i = beg; i < end; ++i) {
        float kc = kn, vc = vn, ec = en, wc = wn;
        if (i + 1 < end) {
            int2 p = csr[i + 1];
            ushort2 kvp = *(const ushort2*)&kv[(size_t)p.x * 512 + tid * 2];
            kn = bf2f(kvp.x); vn = bf2f(kvp.y);
            en = bf2f(eproj[(size_t)p.y * DHD + d]);
            wn = ew[p.y];
        }
        float p = qv * (kc + ec);
        #pragma unroll
        for (int o = 16; o >= 1; o >>= 1) p += __shfl_xor(p, o);
        float score = p * wc;
        float mnew = fmaxf(m, score);
        float corr = __expf(m - mnew);
        float wq = __expf(score - mnew);
        ss  = ss * corr + wq;
        acc = acc * corr + wq * vc;
        m = mnew;
    }
    aggb[(size_t)dst * DD + tid] = f2bf((end > beg) ? (acc / ss) : 0.f);
}

extern "C" void kernel_launch(void* const* d_in, const int* in_sizes, int n_in,
                              void* d_out, int out_size, void* d_ws, size_t ws_size,
                              hipStream_t stream) {
    const float* x    = (const float*)d_in[0];
    const float* ef   = (const float*)d_in[1];
    const float* ew   = (const float*)d_in[2];
    const int*   ei   = (const int*)d_in[3];
    const float* Wq   = (const float*)d_in[4];
    const float* bq   = (const float*)d_in[5];
    const float* Wk   = (const float*)d_in[6];
    const float* bk   = (const float*)d_in[7];
    const float* Wv   = (const float*)d_in[8];
    const float* bv   = (const float*)d_in[9];
    const float* We   = (const float*)d_in[10];
    const float* be   = (const float*)d_in[11];
    const float* Wo   = (const float*)d_in[12];
    const float* bo   = (const float*)d_in[13];
    const float* ln1g = (const float*)d_in[14];
    const float* ln1b = (const float*)d_in[15];
    const float* ln2g = (const float*)d_in[16];
    const float* ln2b = (const float*)d_in[17];
    const float* W1   = (const float*)d_in[18];
    const float* b1   = (const float*)d_in[19];
    const float* W2   = (const float*)d_in[20];
    const float* b2   = (const float*)d_in[21];
    const float* alpha = (const float*)d_in[22];
    const float* beta  = (const float*)d_in[23];

    float* ws    = (float*)d_ws;
    u16*   xn    = (u16*)(ws + XN_OFF);
    u16*   aggb  = (u16*)(ws + AGGB_OFF);
    float* x1    = ws + X1_OFF;
    float* q     = ws + QKV_OFF;                 // [NN][256] fp32, pre-scaled
    u16*   kv    = (u16*)(ws + QKV_OFF + NN * DD); // [NN][512] bf16 dim-interleaved
    u16*   ff1   = (u16*)(ws + QKV_OFF);         // overlays q+kv after attn
    u16*   eproj = (u16*)(ws + EP_OFF);
    u16*   wt    = (u16*)(ws + WT_OFF);
    u16*   WqkvT = wt;                      // [768][256]
    u16*   WoT   = wt + 768 * 256;          // [256][256]
    u16*   W1T   = WoT + 256 * 256;         // [1024][256]
    u16*   W2T   = W1T + 1024 * 256;        // [256][1024]
    float* bqkv  = ws + BQKV_OFF;
    float* out   = (float*)d_out;

    int*  counts    = (int*)(ws + CSR_OFF);
    int*  row_start = counts + NN;
    int*  cursor    = row_start + NN + 1;
    int2* csr       = (int2*)(counts + 60002);   // 8B-aligned

    hipMemsetAsync(counts, 0, (size_t)NN * sizeof(int), stream);

    // weight converts + CSR build (independent of activation dataflow)
    convw<<<64, 256, 0, stream>>>(Wq, WqkvT, 256, 256);
    convw<<<64, 256, 0, stream>>>(Wk, WqkvT + 256 * 256, 256, 256);
    convw<<<64, 256, 0, stream>>>(Wv, WqkvT + 512 * 256, 256, 256);
    convw<<<64, 256, 0, stream>>>(Wo, WoT, 256, 256);
    convw<<<256, 256, 0, stream>>>(W1, W1T, 256, 1024);
    convw<<<64, 256, 0, stream>>>(W2, W2T, 1024, 256);
    bias_cat<<<1, 256, 0, stream>>>(bq, bk, bv, bqkv);

    count_kernel<<<EE / 256, 256, 0, stream>>>(ei, counts);
    scan_kernel<<<1, 1024, 0, stream>>>(counts, row_start, cursor);
    fill_kernel<<<EE / 256, 256, 0, stream>>>(ei, cursor, csr);

    ln_kernel<<<NN / 4, 256, 0, stream>>>(x, ln1g, ln1b, xn);

    // fused QKV GEMM: [20000 x 256] x [256 x 768] -> q fp32 (scaled) + kv bf16
    gemm_bf16<3><<<dim3(157, 6), 256, 0, stream>>>(xn, WqkvT, bqkv, q, kv,
                                                   nullptr, nullptr, NN, DD, 768);

    ep_kernel<<<EE / 8, 256, 0, stream>>>(ef, We, be, eproj);

    attn_kernel<<<NN, 256, 0, stream>>>(q, kv, eproj, ew, csr, row_start, aggb);

    // Wo GEMM + residual: x1 = x + alpha*(agg @ Wo + bo)
    gemm_bf16<2><<<dim3(157, 2), 256, 0, stream>>>(aggb, WoT, bo, x1, nullptr,
                                                   x, alpha, NN, DD, DD);

    ln_kernel<<<NN / 4, 256, 0, stream>>>(x1, ln2g, ln2b, xn);

    // FFN up + GELU -> bf16
    gemm_bf16<1><<<dim3(157, 8), 256, 0, stream>>>(xn, W1T, b1, nullptr, ff1,
                                                   nullptr, nullptr, NN, DD, FFD);
    // FFN down + residual: out = x1 + beta*(ff1 @ W2 + b2)
    gemm_bf16<2><<<dim3(157, 2), 256, 0, stream>>>(ff1, W2T, b2, out, nullptr,
                                                   x1, beta, NN, FFD, DD);
}

// Round 5
// 395.477 us; speedup vs baseline: 13.3336x; 1.1134x over previous
//
#include <hip/hip_runtime.h>
#include <math.h>

// Problem constants (match reference)
#define NN 20000
#define EE 320000
#define DD 256
#define HH 8
#define DHD 32
#define EDF 64
#define FFD 1024

typedef unsigned short u16;
typedef __attribute__((ext_vector_type(8))) __bf16 bf16x8;
typedef __attribute__((ext_vector_type(4))) float f32x4;

// workspace float offsets
#define XN_OFF   (0)          // xn bf16 [NN][256]
#define AGGB_OFF (2560000)    // agg bf16 [NN][256]
#define X1_OFF   (5120000)    // x1 fp32 [NN][256]
#define QKV_OFF  (10240000)   // q fp32 [NN][256] + kv bf16 [NN][512]; ff1 bf16 overlays later
#define EP_OFF   (25600000)   // eproj bf16 [EE][32]
#define WT_OFF   (35840000)   // bf16 weights: WqkvT, WoT, W1T, W2T
#define BQKV_OFF (36240000)   // bqkv fp32 [768]
#define CSR_OFF  (36250000)   // int region

__device__ __forceinline__ u16 f2bf(float f) {
    unsigned u = __float_as_uint(f);
    return (u16)((u + 0x7FFFu + ((u >> 16) & 1u)) >> 16);
}
__device__ __forceinline__ float bf2f(u16 h) {
    return __uint_as_float(((unsigned)h) << 16);
}
__device__ __forceinline__ float gelu_exact(float v) {
    return 0.5f * v * (1.0f + erff(v * 0.70710678118654752f));
}

#define GLDS16(g, l) __builtin_amdgcn_global_load_lds(             \
    (__attribute__((address_space(1))) void*)(g),                  \
    (__attribute__((address_space(3))) void*)(l), 16, 0, 0)

// -------- LayerNorm -> bf16: one wave per row --------
__global__ __launch_bounds__(256) void ln_kernel(const float* __restrict__ x,
                                                 const float* __restrict__ g,
                                                 const float* __restrict__ b,
                                                 u16* __restrict__ out) {
    int row = blockIdx.x * 4 + (threadIdx.x >> 6);
    if (row >= NN) return;
    int lane = threadIdx.x & 63;
    float4 v = *(const float4*)&x[(size_t)row * DD + lane * 4];
    float s  = v.x + v.y + v.z + v.w;
    float ss = v.x * v.x + v.y * v.y + v.z * v.z + v.w * v.w;
    #pragma unroll
    for (int o = 32; o >= 1; o >>= 1) {
        s  += __shfl_xor(s, o);
        ss += __shfl_xor(ss, o);
    }
    float mean = s * (1.0f / DD);
    float var  = ss * (1.0f / DD) - mean * mean;
    float inv  = rsqrtf(var + 1e-5f);
    float4 gg = *(const float4*)&g[lane * 4];
    float4 bb = *(const float4*)&b[lane * 4];
    ushort4 o4;
    o4.x = f2bf((v.x - mean) * inv * gg.x + bb.x);
    o4.y = f2bf((v.y - mean) * inv * gg.y + bb.y);
    o4.z = f2bf((v.z - mean) * inv * gg.z + bb.z);
    o4.w = f2bf((v.w - mean) * inv * gg.w + bb.w);
    *(ushort4*)&out[(size_t)row * DD + lane * 4] = o4;
}

// -------- weight transpose+convert: dst[n][k] = bf16(src[k][n]) --------
__global__ __launch_bounds__(256) void convw(const float* __restrict__ src,
                                             u16* __restrict__ dst, int K, int N) {
    int n = blockIdx.x * 4 + (threadIdx.x >> 6);
    int lane = threadIdx.x & 63;
    if (n >= N) return;
    for (int k = lane * 4; k < K; k += 256) {
        ushort4 o;
        o.x = f2bf(src[(size_t)(k + 0) * N + n]);
        o.y = f2bf(src[(size_t)(k + 1) * N + n]);
        o.z = f2bf(src[(size_t)(k + 2) * N + n]);
        o.w = f2bf(src[(size_t)(k + 3) * N + n]);
        *(ushort4*)&dst[(size_t)n * K + k] = o;
    }
}

__global__ void bias_cat(const float* __restrict__ bq, const float* __restrict__ bk,
                         const float* __restrict__ bv, float* __restrict__ bqkv) {
    int t = threadIdx.x;
    bqkv[t] = bq[t];
    bqkv[256 + t] = bk[t];
    bqkv[512 + t] = bv[t];
}

// ======== bf16 MFMA GEMM: C = A[MxK] @ BT[NxK]^T + bias ========
// 128x128 tile, BK=64, 4 waves (2x2), 64x64 per wave, 16x16x32 bf16 MFMA.
// EPI: 0 = fp32 out, 1 = gelu->bf16 out, 2 = fp32 out = res + scale*(acc+bias)
//      3 = QKV: col<256 -> q fp32 * invsqrt(dh); col>=256 -> kv bf16 dim-interleaved
template <int EPI>
__global__ __launch_bounds__(256) void gemm_bf16(
    const u16* __restrict__ A, const u16* __restrict__ BT,
    const float* __restrict__ bias,
    float* __restrict__ Cf, u16* __restrict__ Cb,
    const float* __restrict__ res, const float* __restrict__ scale,
    int M, int K, int N)
{
    __shared__ u16 Asm[128 * 64];
    __shared__ u16 Bsm[128 * 64];
    const int tid  = threadIdx.x;
    const int lane = tid & 63;
    const int w    = tid >> 6;
    const int wr   = w >> 1, wc = w & 1;
    const int bm   = blockIdx.x * 128;
    const int bn   = blockIdx.y * 128;

    f32x4 acc[4][4] = {};

    int st_row[4], st_src[4], st_dst[4];
    #pragma unroll
    for (int i = 0; i < 4; i++) {
        int base  = i * 4096 + w * 1024;       // wave-uniform LDS byte base
        int off   = base + lane * 16;          // this lane's 16B lands here
        int row   = off >> 7;
        int inner = off & 127;
        st_row[i] = row;
        st_src[i] = (inner ^ ((row & 7) << 4)) >> 1;  // short idx within k-row
        st_dst[i] = base;
    }
    const int arow0 = wr * 64 + (lane & 15);
    const int brow0 = wc * 64 + (lane & 15);
    const int kb0   = (lane >> 4) * 16;        // byte offset of k in 128B row

    for (int k0 = 0; k0 < K; k0 += 64) {
        #pragma unroll
        for (int i = 0; i < 4; i++) {
            int r = bm + st_row[i]; if (r > M - 1) r = M - 1;
            GLDS16(A + (size_t)r * K + k0 + st_src[i], (char*)Asm + st_dst[i]);
        }
        #pragma unroll
        for (int i = 0; i < 4; i++) {
            int r = bn + st_row[i];
            GLDS16(BT + (size_t)r * K + k0 + st_src[i], (char*)Bsm + st_dst[i]);
        }
        asm volatile("s_waitcnt vmcnt(0)" ::: "memory");
        __syncthreads();
        #pragma unroll
        for (int s = 0; s < 2; s++) {
            bf16x8 af[4], bfv[4];
            #pragma unroll
            for (int i = 0; i < 4; i++) {
                int row  = arow0 + i * 16;
                int byte = (row << 7) + ((kb0 + s * 64) ^ ((row & 7) << 4));
                af[i] = *(const bf16x8*)((const char*)Asm + byte);
            }
            #pragma unroll
            for (int j = 0; j < 4; j++) {
                int row  = brow0 + j * 16;
                int byte = (row << 7) + ((kb0 + s * 64) ^ ((row & 7) << 4));
                bfv[j] = *(const bf16x8*)((const char*)Bsm + byte);
            }
            #pragma unroll
            for (int i = 0; i < 4; i++)
                #pragma unroll
                for (int j = 0; j < 4; j++)
                    acc[i][j] = __builtin_amdgcn_mfma_f32_16x16x32_bf16(
                        af[i], bfv[j], acc[i][j], 0, 0, 0);
        }
        __syncthreads();
    }

    float sc = 0.f;
    if constexpr (EPI == 2) sc = scale[0];
    const int col0 = bn + wc * 64 + (lane & 15);
    const int row0 = bm + wr * 64 + ((lane >> 4) << 2);
    #pragma unroll
    for (int i = 0; i < 4; i++) {
        #pragma unroll
        for (int j = 0; j < 4; j++) {
            int col = col0 + j * 16;
            float bb = bias[col];
            #pragma unroll
            for (int r = 0; r < 4; r++) {
                int row = row0 + i * 16 + r;
                if (row < M) {
                    float o = acc[i][j][r] + bb;
                    if constexpr (EPI == 1) {
                        Cb[(size_t)row * N + col] = f2bf(gelu_exact(o));
                    } else if constexpr (EPI == 2) {
                        Cf[(size_t)row * N + col] = res[(size_t)row * N + col] + sc * o;
                    } else if constexpr (EPI == 3) {
                        if (col < 256) {
                            Cf[(size_t)row * 256 + col] = o * 0.17677669529663689f;
                        } else if (col < 512) {
                            Cb[(size_t)row * 512 + (col - 256) * 2] = f2bf(o);
                        } else {
                            Cb[(size_t)row * 512 + (col - 512) * 2 + 1] = f2bf(o);
                        }
                    } else {
                        Cf[(size_t)row * N + col] = o;
                    }
                }
            }
        }
    }
}

// -------- edge projection: ep[E x 32] = bf16(ef[E x 64] @ We[64 x 32] + be) --------
__global__ __launch_bounds__(256) void ep_kernel(const float* __restrict__ ef,
                                                 const float* __restrict__ We,
                                                 const float* __restrict__ be,
                                                 u16* __restrict__ eproj) {
    __shared__ float Ws[EDF * DHD];
    __shared__ float efs[8][EDF];
    int tid = threadIdx.x;
    for (int i = tid; i < EDF * DHD; i += 256) Ws[i] = We[i];
    int e0 = blockIdx.x * 8;
    for (int i = tid; i < 8 * EDF; i += 256) {
        int r = i >> 6, c = i & 63;
        efs[r][c] = ef[(size_t)(e0 + r) * EDF + c];
    }
    __syncthreads();
    int er = tid >> 5, dh = tid & 31;
    int e = e0 + er;
    float acc = be[dh];
    #pragma unroll
    for (int c = 0; c < EDF; c++) acc += efs[er][c] * Ws[c * DHD + dh];
    eproj[(size_t)e * DHD + dh] = f2bf(acc);
}

// ======== CSR build over dst ========
__global__ __launch_bounds__(256) void count_kernel(const int* __restrict__ ei,
                                                    int* __restrict__ counts) {
    int e = blockIdx.x * 256 + threadIdx.x;
    if (e >= EE) return;
    atomicAdd(&counts[ei[EE + e]], 1);
}

__global__ __launch_bounds__(1024) void scan_kernel(const int* __restrict__ counts,
                                                    int* __restrict__ row_start,
                                                    int* __restrict__ cursor) {
    __shared__ int part[1024];
    const int CH = 20;
    int t = threadIdx.x;
    int base = t * CH;
    int loc[CH];
    int s = 0;
    #pragma unroll
    for (int i = 0; i < CH; i++) {
        int idx = base + i;
        int c = (idx < NN) ? counts[idx] : 0;
        loc[i] = s;
        s += c;
    }
    part[t] = s;
    __syncthreads();
    for (int o = 1; o < 1024; o <<= 1) {
        int vv = (t >= o) ? part[t - o] : 0;
        __syncthreads();
        part[t] += vv;
        __syncthreads();
    }
    int off = (t > 0) ? part[t - 1] : 0;
    #pragma unroll
    for (int i = 0; i < CH; i++) {
        int idx = base + i;
        if (idx < NN) {
            int rs = off + loc[i];
            row_start[idx] = rs;
            cursor[idx] = rs;
        }
    }
    if (t == 1023) row_start[NN] = part[1023];
}

// fill CSR with (src, edge) pairs -> removes one dependent-load level in attn
__global__ __launch_bounds__(256) void fill_kernel(const int* __restrict__ ei,
                                                   int* __restrict__ cursor,
                                                   int2* __restrict__ csr) {
    int e = blockIdx.x * 256 + threadIdx.x;
    if (e >= EE) return;
    int src = ei[e];
    int dst = ei[EE + e];
    int pos = atomicAdd(&cursor[dst], 1);
    csr[pos] = make_int2(src, e);
}

// ======== fused gather attention: one block per dst node ========
// q pre-scaled by dh^-0.5. No max-subtraction: scores are O(10) (LN'd inputs,
// ew in [0,1]) so exp is far from overflow, and softmax is shift-invariant —
// this removes the serial (m,ss,acc) dependence. 4-edge unroll interleaves
// 4 independent butterfly-reduce chains to hide cross-lane latency.
__global__ __launch_bounds__(256) void attn_kernel(const float* __restrict__ q,
                                                   const u16* __restrict__ kv,
                                                   const u16* __restrict__ eproj,
                                                   const float* __restrict__ ew,
                                                   const int2* __restrict__ csr,
                                                   const int* __restrict__ row_start,
                                                   u16* __restrict__ aggb) {
    int dst = blockIdx.x;
    int tid = threadIdx.x;
    int d = tid & 31;
    int beg = row_start[dst];
    int end = row_start[dst + 1];
    float qv = q[(size_t)dst * DD + tid];
    float ss = 0.f, acc = 0.f;

    int i = beg;
    for (; i + 4 <= end; i += 4) {
        float kk[4], vv[4], wt[4];
        #pragma unroll
        for (int u = 0; u < 4; u++) {
            int2 p = csr[i + u];
            ushort2 kvp = *(const ushort2*)&kv[(size_t)p.x * 512 + tid * 2];
            kk[u] = bf2f(kvp.x) + bf2f(eproj[(size_t)p.y * DHD + d]);
            vv[u] = bf2f(kvp.y);
            wt[u] = ew[p.y];
        }
        float pp[4];
        #pragma unroll
        for (int u = 0; u < 4; u++) pp[u] = qv * kk[u];
        #pragma unroll
        for (int o = 16; o >= 1; o >>= 1) {
            #pragma unroll
            for (int u = 0; u < 4; u++) pp[u] += __shfl_xor(pp[u], o);
        }
        #pragma unroll
        for (int u = 0; u < 4; u++) {
            float wq = __expf(pp[u] * wt[u]);
            ss += wq;
            acc = fmaf(wq, vv[u], acc);
        }
    }
    for (; i < end; ++i) {
        int2 p = csr[i];
        ushort2 kvp = *(const ushort2*)&kv[(size_t)p.x * 512 + tid * 2];
        float pv = qv * (bf2f(kvp.x) + bf2f(eproj[(size_t)p.y * DHD + d]));
        #pragma unroll
        for (int o = 16; o >= 1; o >>= 1) pv += __shfl_xor(pv, o);
        float wq = __expf(pv * ew[p.y]);
        ss += wq;
        acc = fmaf(wq, bf2f(kvp.y), acc);
    }
    aggb[(size_t)dst * DD + tid] = f2bf((end > beg) ? (acc / ss) : 0.f);
}

extern "C" void kernel_launch(void* const* d_in, const int* in_sizes, int n_in,
                              void* d_out, int out_size, void* d_ws, size_t ws_size,
                              hipStream_t stream) {
    const float* x    = (const float*)d_in[0];
    const float* ef   = (const float*)d_in[1];
    const float* ew   = (const float*)d_in[2];
    const int*   ei   = (const int*)d_in[3];
    const float* Wq   = (const float*)d_in[4];
    const float* bq   = (const float*)d_in[5];
    const float* Wk   = (const float*)d_in[6];
    const float* bk   = (const float*)d_in[7];
    const float* Wv   = (const float*)d_in[8];
    const float* bv   = (const float*)d_in[9];
    const float* We   = (const float*)d_in[10];
    const float* be   = (const float*)d_in[11];
    const float* Wo   = (const float*)d_in[12];
    const float* bo   = (const float*)d_in[13];
    const float* ln1g = (const float*)d_in[14];
    const float* ln1b = (const float*)d_in[15];
    const float* ln2g = (const float*)d_in[16];
    const float* ln2b = (const float*)d_in[17];
    const float* W1   = (const float*)d_in[18];
    const float* b1   = (const float*)d_in[19];
    const float* W2   = (const float*)d_in[20];
    const float* b2   = (const float*)d_in[21];
    const float* alpha = (const float*)d_in[22];
    const float* beta  = (const float*)d_in[23];

    float* ws    = (float*)d_ws;
    u16*   xn    = (u16*)(ws + XN_OFF);
    u16*   aggb  = (u16*)(ws + AGGB_OFF);
    float* x1    = ws + X1_OFF;
    float* q     = ws + QKV_OFF;                 // [NN][256] fp32, pre-scaled
    u16*   kv    = (u16*)(ws + QKV_OFF + NN * DD); // [NN][512] bf16 dim-interleaved
    u16*   ff1   = (u16*)(ws + QKV_OFF);         // overlays q+kv after attn
    u16*   eproj = (u16*)(ws + EP_OFF);
    u16*   wt    = (u16*)(ws + WT_OFF);
    u16*   WqkvT = wt;                      // [768][256]
    u16*   WoT   = wt + 768 * 256;          // [256][256]
    u16*   W1T   = WoT + 256 * 256;         // [1024][256]
    u16*   W2T   = W1T + 1024 * 256;        // [256][1024]
    float* bqkv  = ws + BQKV_OFF;
    float* out   = (float*)d_out;

    int*  counts    = (int*)(ws + CSR_OFF);
    int*  row_start = counts + NN;
    int*  cursor    = row_start + NN + 1;
    int2* csr       = (int2*)(counts + 60002);   // 8B-aligned

    hipMemsetAsync(counts, 0, (size_t)NN * sizeof(int), stream);

    // weight converts + CSR build (independent of activation dataflow)
    convw<<<64, 256, 0, stream>>>(Wq, WqkvT, 256, 256);
    convw<<<64, 256, 0, stream>>>(Wk, WqkvT + 256 * 256, 256, 256);
    convw<<<64, 256, 0, stream>>>(Wv, WqkvT + 512 * 256, 256, 256);
    convw<<<64, 256, 0, stream>>>(Wo, WoT, 256, 256);
    convw<<<256, 256, 0, stream>>>(W1, W1T, 256, 1024);
    convw<<<64, 256, 0, stream>>>(W2, W2T, 1024, 256);
    bias_cat<<<1, 256, 0, stream>>>(bq, bk, bv, bqkv);

    count_kernel<<<EE / 256, 256, 0, stream>>>(ei, counts);
    scan_kernel<<<1, 1024, 0, stream>>>(counts, row_start, cursor);
    fill_kernel<<<EE / 256, 256, 0, stream>>>(ei, cursor, csr);

    ln_kernel<<<NN / 4, 256, 0, stream>>>(x, ln1g, ln1b, xn);

    // fused QKV GEMM: [20000 x 256] x [256 x 768] -> q fp32 (scaled) + kv bf16
    gemm_bf16<3><<<dim3(157, 6), 256, 0, stream>>>(xn, WqkvT, bqkv, q, kv,
                                                   nullptr, nullptr, NN, DD, 768);

    ep_kernel<<<EE / 8, 256, 0, stream>>>(ef, We, be, eproj);

    attn_kernel<<<NN, 256, 0, stream>>>(q, kv, eproj, ew, csr, row_start, aggb);

    // Wo GEMM + residual: x1 = x + alpha*(agg @ Wo + bo)
    gemm_bf16<2><<<dim3(157, 2), 256, 0, stream>>>(aggb, WoT, bo, x1, nullptr,
                                                   x, alpha, NN, DD, DD);

    ln_kernel<<<NN / 4, 256, 0, stream>>>(x1, ln2g, ln2b, xn);

    // FFN up + GELU -> bf16
    gemm_bf16<1><<<dim3(157, 8), 256, 0, stream>>>(xn, W1T, b1, nullptr, ff1,
                                                   nullptr, nullptr, NN, DD, FFD);
    // FFN down + residual: out = x1 + beta*(ff1 @ W2 + b2)
    gemm_bf16<2><<<dim3(157, 2), 256, 0, stream>>>(ff1, W2T, b2, out, nullptr,
                                                   x1, beta, NN, FFD, DD);
}

// Round 6
// 349.137 us; speedup vs baseline: 15.1033x; 1.1327x over previous
//
#include <hip/hip_runtime.h>
#include <math.h>

// Problem constants (match reference)
#define NN 20000
#define EE 320000
#define DD 256
#define HH 8
#define DHD 32
#define EDF 64
#define FFD 1024

typedef unsigned short u16;
typedef __attribute__((ext_vector_type(8))) __bf16 bf16x8;
typedef __attribute__((ext_vector_type(4))) float f32x4;

// workspace float offsets
#define XN_OFF   (0)          // xn bf16 [NN][256]
#define AGGB_OFF (2560000)    // agg bf16 [NN][256]
#define X1_OFF   (5120000)    // x1 fp32 [NN][256]
#define QKV_OFF  (10240000)   // q fp32 [NN][256] + kv bf16 [NN][512]; ff1 bf16 overlays later
#define EP_OFF   (25600000)   // eproj bf16 [EE][32]
#define WT_OFF   (35840000)   // bf16 weights: WqkvT, WoT, W1T, W2T, WeT
#define BQKV_OFF (36240000)   // bqkv fp32 [768]
#define CSR_OFF  (36250000)   // int region

__device__ __forceinline__ u16 f2bf(float f) {
    unsigned u = __float_as_uint(f);
    return (u16)((u + 0x7FFFu + ((u >> 16) & 1u)) >> 16);
}
__device__ __forceinline__ float bf2f(u16 h) {
    return __uint_as_float(((unsigned)h) << 16);
}
__device__ __forceinline__ float gelu_exact(float v) {
    return 0.5f * v * (1.0f + erff(v * 0.70710678118654752f));
}

#define GLDS16(g, l) __builtin_amdgcn_global_load_lds(             \
    (__attribute__((address_space(1))) void*)(g),                  \
    (__attribute__((address_space(3))) void*)(l), 16, 0, 0)

// -------- LayerNorm -> bf16: one wave per row --------
__global__ __launch_bounds__(256) void ln_kernel(const float* __restrict__ x,
                                                 const float* __restrict__ g,
                                                 const float* __restrict__ b,
                                                 u16* __restrict__ out) {
    int row = blockIdx.x * 4 + (threadIdx.x >> 6);
    if (row >= NN) return;
    int lane = threadIdx.x & 63;
    float4 v = *(const float4*)&x[(size_t)row * DD + lane * 4];
    float s  = v.x + v.y + v.z + v.w;
    float ss = v.x * v.x + v.y * v.y + v.z * v.z + v.w * v.w;
    #pragma unroll
    for (int o = 32; o >= 1; o >>= 1) {
        s  += __shfl_xor(s, o);
        ss += __shfl_xor(ss, o);
    }
    float mean = s * (1.0f / DD);
    float var  = ss * (1.0f / DD) - mean * mean;
    float inv  = rsqrtf(var + 1e-5f);
    float4 gg = *(const float4*)&g[lane * 4];
    float4 bb = *(const float4*)&b[lane * 4];
    ushort4 o4;
    o4.x = f2bf((v.x - mean) * inv * gg.x + bb.x);
    o4.y = f2bf((v.y - mean) * inv * gg.y + bb.y);
    o4.z = f2bf((v.z - mean) * inv * gg.z + bb.z);
    o4.w = f2bf((v.w - mean) * inv * gg.w + bb.w);
    *(ushort4*)&out[(size_t)row * DD + lane * 4] = o4;
}

// -------- weight transpose+convert: dst[n][k] = bf16(src[k][n]) --------
__global__ __launch_bounds__(256) void convw(const float* __restrict__ src,
                                             u16* __restrict__ dst, int K, int N) {
    int n = blockIdx.x * 4 + (threadIdx.x >> 6);
    int lane = threadIdx.x & 63;
    if (n >= N) return;
    for (int k = lane * 4; k < K; k += 256) {
        ushort4 o;
        o.x = f2bf(src[(size_t)(k + 0) * N + n]);
        o.y = f2bf(src[(size_t)(k + 1) * N + n]);
        o.z = f2bf(src[(size_t)(k + 2) * N + n]);
        o.w = f2bf(src[(size_t)(k + 3) * N + n]);
        *(ushort4*)&dst[(size_t)n * K + k] = o;
    }
}

__global__ void bias_cat(const float* __restrict__ bq, const float* __restrict__ bk,
                         const float* __restrict__ bv, float* __restrict__ bqkv) {
    int t = threadIdx.x;
    bqkv[t] = bq[t];
    bqkv[256 + t] = bk[t];
    bqkv[512 + t] = bv[t];
}

// ======== bf16 MFMA GEMM: C = A[MxK] @ BT[NxK]^T + bias ========
// 128x128 tile, BK=64, 4 waves (2x2), 64x64 per wave, 16x16x32 bf16 MFMA.
// EPI: 0 = fp32 out, 1 = gelu->bf16 out, 2 = fp32 out = res + scale*(acc+bias)
//      3 = QKV: col<256 -> q fp32 * invsqrt(dh); col>=256 -> kv bf16 dim-interleaved
template <int EPI>
__global__ __launch_bounds__(256) void gemm_bf16(
    const u16* __restrict__ A, const u16* __restrict__ BT,
    const float* __restrict__ bias,
    float* __restrict__ Cf, u16* __restrict__ Cb,
    const float* __restrict__ res, const float* __restrict__ scale,
    int M, int K, int N)
{
    __shared__ u16 Asm[128 * 64];
    __shared__ u16 Bsm[128 * 64];
    const int tid  = threadIdx.x;
    const int lane = tid & 63;
    const int w    = tid >> 6;
    const int wr   = w >> 1, wc = w & 1;
    const int bm   = blockIdx.x * 128;
    const int bn   = blockIdx.y * 128;

    f32x4 acc[4][4] = {};

    int st_row[4], st_src[4], st_dst[4];
    #pragma unroll
    for (int i = 0; i < 4; i++) {
        int base  = i * 4096 + w * 1024;       // wave-uniform LDS byte base
        int off   = base + lane * 16;          // this lane's 16B lands here
        int row   = off >> 7;
        int inner = off & 127;
        st_row[i] = row;
        st_src[i] = (inner ^ ((row & 7) << 4)) >> 1;  // short idx within k-row
        st_dst[i] = base;
    }
    const int arow0 = wr * 64 + (lane & 15);
    const int brow0 = wc * 64 + (lane & 15);
    const int kb0   = (lane >> 4) * 16;        // byte offset of k in 128B row

    for (int k0 = 0; k0 < K; k0 += 64) {
        #pragma unroll
        for (int i = 0; i < 4; i++) {
            int r = bm + st_row[i]; if (r > M - 1) r = M - 1;
            GLDS16(A + (size_t)r * K + k0 + st_src[i], (char*)Asm + st_dst[i]);
        }
        #pragma unroll
        for (int i = 0; i < 4; i++) {
            int r = bn + st_row[i];
            GLDS16(BT + (size_t)r * K + k0 + st_src[i], (char*)Bsm + st_dst[i]);
        }
        asm volatile("s_waitcnt vmcnt(0)" ::: "memory");
        __syncthreads();
        #pragma unroll
        for (int s = 0; s < 2; s++) {
            bf16x8 af[4], bfv[4];
            #pragma unroll
            for (int i = 0; i < 4; i++) {
                int row  = arow0 + i * 16;
                int byte = (row << 7) + ((kb0 + s * 64) ^ ((row & 7) << 4));
                af[i] = *(const bf16x8*)((const char*)Asm + byte);
            }
            #pragma unroll
            for (int j = 0; j < 4; j++) {
                int row  = brow0 + j * 16;
                int byte = (row << 7) + ((kb0 + s * 64) ^ ((row & 7) << 4));
                bfv[j] = *(const bf16x8*)((const char*)Bsm + byte);
            }
            #pragma unroll
            for (int i = 0; i < 4; i++)
                #pragma unroll
                for (int j = 0; j < 4; j++)
                    acc[i][j] = __builtin_amdgcn_mfma_f32_16x16x32_bf16(
                        af[i], bfv[j], acc[i][j], 0, 0, 0);
        }
        __syncthreads();
    }

    float sc = 0.f;
    if constexpr (EPI == 2) sc = scale[0];
    const int col0 = bn + wc * 64 + (lane & 15);
    const int row0 = bm + wr * 64 + ((lane >> 4) << 2);
    #pragma unroll
    for (int i = 0; i < 4; i++) {
        #pragma unroll
        for (int j = 0; j < 4; j++) {
            int col = col0 + j * 16;
            float bb = bias[col];
            #pragma unroll
            for (int r = 0; r < 4; r++) {
                int row = row0 + i * 16 + r;
                if (row < M) {
                    float o = acc[i][j][r] + bb;
                    if constexpr (EPI == 1) {
                        Cb[(size_t)row * N + col] = f2bf(gelu_exact(o));
                    } else if constexpr (EPI == 2) {
                        Cf[(size_t)row * N + col] = res[(size_t)row * N + col] + sc * o;
                    } else if constexpr (EPI == 3) {
                        if (col < 256) {
                            Cf[(size_t)row * 256 + col] = o * 0.17677669529663689f;
                        } else if (col < 512) {
                            Cb[(size_t)row * 512 + (col - 256) * 2] = f2bf(o);
                        } else {
                            Cb[(size_t)row * 512 + (col - 512) * 2 + 1] = f2bf(o);
                        }
                    } else {
                        Cf[(size_t)row * N + col] = o;
                    }
                }
            }
        }
    }
}

// -------- edge projection via MFMA: ep[E x 32] = bf16(ef @ We + be) --------
// One wave per 16 edges; A-frag loaded straight from global fp32 ef (32B/lane),
// converted to bf16 in registers; B = WeT bf16 [32][64] (L1-resident).
// No LDS. 4 MFMAs per wave (2 col-frags x K=64).
__global__ __launch_bounds__(256) void ep_mfma(const float* __restrict__ ef,
                                               const u16* __restrict__ WeT,
                                               const float* __restrict__ be,
                                               u16* __restrict__ eproj) {
    const int lane = threadIdx.x & 63;
    const int wv   = threadIdx.x >> 6;
    const int e0   = blockIdx.x * 64 + wv * 16;     // 16 edges per wave
    const int ar   = lane & 15;                      // A row within frag
    const int k8   = (lane >> 4) * 8;                // k-offset of this lane's 8 elems

    f32x4 acc[2] = {};
    #pragma unroll
    for (int s = 0; s < 2; s++) {
        // A fragment: ef[e0+ar][s*32 + k8 .. +7], fp32 -> bf16
        const float* ap = ef + (size_t)(e0 + ar) * EDF + s * 32 + k8;
        float4 a0 = *(const float4*)ap;
        float4 a1 = *(const float4*)(ap + 4);
        bf16x8 af;
        af[0] = (__bf16)a0.x; af[1] = (__bf16)a0.y; af[2] = (__bf16)a0.z; af[3] = (__bf16)a0.w;
        af[4] = (__bf16)a1.x; af[5] = (__bf16)a1.y; af[6] = (__bf16)a1.z; af[7] = (__bf16)a1.w;
        #pragma unroll
        for (int j = 0; j < 2; j++) {
            // B fragment: WeT[j*16 + (lane&15)][s*32 + k8 .. +7]
            bf16x8 bf = *(const bf16x8*)&WeT[(size_t)(j * 16 + ar) * EDF + s * 32 + k8];
            acc[j] = __builtin_amdgcn_mfma_f32_16x16x32_bf16(af, bf, acc[j], 0, 0, 0);
        }
    }
    const int row0 = (lane >> 4) << 2;
    #pragma unroll
    for (int j = 0; j < 2; j++) {
        int col = j * 16 + ar;
        float bb = be[col];
        #pragma unroll
        for (int r = 0; r < 4; r++) {
            eproj[(size_t)(e0 + row0 + r) * DHD + col] = f2bf(acc[j][r] + bb);
        }
    }
}

// ======== CSR build over dst ========
__global__ __launch_bounds__(256) void count_kernel(const int* __restrict__ ei,
                                                    int* __restrict__ counts) {
    int e = blockIdx.x * 256 + threadIdx.x;
    if (e >= EE) return;
    atomicAdd(&counts[ei[EE + e]], 1);
}

__global__ __launch_bounds__(1024) void scan_kernel(const int* __restrict__ counts,
                                                    int* __restrict__ row_start,
                                                    int* __restrict__ cursor) {
    __shared__ int part[1024];
    const int CH = 20;
    int t = threadIdx.x;
    int base = t * CH;
    int loc[CH];
    int s = 0;
    #pragma unroll
    for (int i = 0; i < CH; i++) {
        int idx = base + i;
        int c = (idx < NN) ? counts[idx] : 0;
        loc[i] = s;
        s += c;
    }
    part[t] = s;
    __syncthreads();
    for (int o = 1; o < 1024; o <<= 1) {
        int vv = (t >= o) ? part[t - o] : 0;
        __syncthreads();
        part[t] += vv;
        __syncthreads();
    }
    int off = (t > 0) ? part[t - 1] : 0;
    #pragma unroll
    for (int i = 0; i < CH; i++) {
        int idx = base + i;
        if (idx < NN) {
            int rs = off + loc[i];
            row_start[idx] = rs;
            cursor[idx] = rs;
        }
    }
    if (t == 1023) row_start[NN] = part[1023];
}

// fill CSR with (src, edge) pairs -> removes one dependent-load level in attn
__global__ __launch_bounds__(256) void fill_kernel(const int* __restrict__ ei,
                                                   int* __restrict__ cursor,
                                                   int2* __restrict__ csr) {
    int e = blockIdx.x * 256 + threadIdx.x;
    if (e >= EE) return;
    int src = ei[e];
    int dst = ei[EE + e];
    int pos = atomicAdd(&cursor[dst], 1);
    csr[pos] = make_int2(src, e);
}

// ======== fused gather attention: one block per dst node ========
// q pre-scaled by dh^-0.5. No max-subtraction (softmax shift-invariance;
// scores bounded ~|10| with LN'd inputs) -> no serial (m,ss,acc) chain.
// 4-edge unroll interleaves 4 independent butterfly reduces.
__global__ __launch_bounds__(256) void attn_kernel(const float* __restrict__ q,
                                                   const u16* __restrict__ kv,
                                                   const u16* __restrict__ eproj,
                                                   const float* __restrict__ ew,
                                                   const int2* __restrict__ csr,
                                                   const int* __restrict__ row_start,
                                                   u16* __restrict__ aggb) {
    int dst = blockIdx.x;
    int tid = threadIdx.x;
    int d = tid & 31;
    int beg = row_start[dst];
    int end = row_start[dst + 1];
    float qv = q[(size_t)dst * DD + tid];
    float ss = 0.f, acc = 0.f;

    int i = beg;
    for (; i + 4 <= end; i += 4) {
        float kk[4], vv[4], wt[4];
        #pragma unroll
        for (int u = 0; u < 4; u++) {
            int2 p = csr[i + u];
            ushort2 kvp = *(const ushort2*)&kv[(size_t)p.x * 512 + tid * 2];
            kk[u] = bf2f(kvp.x) + bf2f(eproj[(size_t)p.y * DHD + d]);
            vv[u] = bf2f(kvp.y);
            wt[u] = ew[p.y];
        }
        float pp[4];
        #pragma unroll
        for (int u = 0; u < 4; u++) pp[u] = qv * kk[u];
        #pragma unroll
        for (int o = 16; o >= 1; o >>= 1) {
            #pragma unroll
            for (int u = 0; u < 4; u++) pp[u] += __shfl_xor(pp[u], o);
        }
        #pragma unroll
        for (int u = 0; u < 4; u++) {
            float wq = __expf(pp[u] * wt[u]);
            ss += wq;
            acc = fmaf(wq, vv[u], acc);
        }
    }
    for (; i < end; ++i) {
        int2 p = csr[i];
        ushort2 kvp = *(const ushort2*)&kv[(size_t)p.x * 512 + tid * 2];
        float pv = qv * (bf2f(kvp.x) + bf2f(eproj[(size_t)p.y * DHD + d]));
        #pragma unroll
        for (int o = 16; o >= 1; o >>= 1) pv += __shfl_xor(pv, o);
        float wq = __expf(pv * ew[p.y]);
        ss += wq;
        acc = fmaf(wq, bf2f(kvp.y), acc);
    }
    aggb[(size_t)dst * DD + tid] = f2bf((end > beg) ? (acc / ss) : 0.f);
}

extern "C" void kernel_launch(void* const* d_in, const int* in_sizes, int n_in,
                              void* d_out, int out_size, void* d_ws, size_t ws_size,
                              hipStream_t stream) {
    const float* x    = (const float*)d_in[0];
    const float* ef   = (const float*)d_in[1];
    const float* ew   = (const float*)d_in[2];
    const int*   ei   = (const int*)d_in[3];
    const float* Wq   = (const float*)d_in[4];
    const float* bq   = (const float*)d_in[5];
    const float* Wk   = (const float*)d_in[6];
    const float* bk   = (const float*)d_in[7];
    const float* Wv   = (const float*)d_in[8];
    const float* bv   = (const float*)d_in[9];
    const float* We   = (const float*)d_in[10];
    const float* be   = (const float*)d_in[11];
    const float* Wo   = (const float*)d_in[12];
    const float* bo   = (const float*)d_in[13];
    const float* ln1g = (const float*)d_in[14];
    const float* ln1b = (const float*)d_in[15];
    const float* ln2g = (const float*)d_in[16];
    const float* ln2b = (const float*)d_in[17];
    const float* W1   = (const float*)d_in[18];
    const float* b1   = (const float*)d_in[19];
    const float* W2   = (const float*)d_in[20];
    const float* b2   = (const float*)d_in[21];
    const float* alpha = (const float*)d_in[22];
    const float* beta  = (const float*)d_in[23];

    float* ws    = (float*)d_ws;
    u16*   xn    = (u16*)(ws + XN_OFF);
    u16*   aggb  = (u16*)(ws + AGGB_OFF);
    float* x1    = ws + X1_OFF;
    float* q     = ws + QKV_OFF;                 // [NN][256] fp32, pre-scaled
    u16*   kv    = (u16*)(ws + QKV_OFF + NN * DD); // [NN][512] bf16 dim-interleaved
    u16*   ff1   = (u16*)(ws + QKV_OFF);         // overlays q+kv after attn
    u16*   eproj = (u16*)(ws + EP_OFF);
    u16*   wt    = (u16*)(ws + WT_OFF);
    u16*   WqkvT = wt;                      // [768][256]
    u16*   WoT   = wt + 768 * 256;          // [256][256]
    u16*   W1T   = WoT + 256 * 256;         // [1024][256]
    u16*   W2T   = W1T + 1024 * 256;        // [256][1024]
    u16*   WeT   = W2T + 256 * 1024;        // [32][64]
    float* bqkv  = ws + BQKV_OFF;
    float* out   = (float*)d_out;

    int*  counts    = (int*)(ws + CSR_OFF);
    int*  row_start = counts + NN;
    int*  cursor    = row_start + NN + 1;
    int2* csr       = (int2*)(counts + 60002);   // 8B-aligned

    hipMemsetAsync(counts, 0, (size_t)NN * sizeof(int), stream);

    // weight converts + CSR build (independent of activation dataflow)
    convw<<<64, 256, 0, stream>>>(Wq, WqkvT, 256, 256);
    convw<<<64, 256, 0, stream>>>(Wk, WqkvT + 256 * 256, 256, 256);
    convw<<<64, 256, 0, stream>>>(Wv, WqkvT + 512 * 256, 256, 256);
    convw<<<64, 256, 0, stream>>>(Wo, WoT, 256, 256);
    convw<<<256, 256, 0, stream>>>(W1, W1T, 256, 1024);
    convw<<<64, 256, 0, stream>>>(W2, W2T, 1024, 256);
    convw<<<8, 256, 0, stream>>>(We, WeT, 64, 32);
    bias_cat<<<1, 256, 0, stream>>>(bq, bk, bv, bqkv);

    count_kernel<<<EE / 256, 256, 0, stream>>>(ei, counts);
    scan_kernel<<<1, 1024, 0, stream>>>(counts, row_start, cursor);
    fill_kernel<<<EE / 256, 256, 0, stream>>>(ei, cursor, csr);

    ln_kernel<<<NN / 4, 256, 0, stream>>>(x, ln1g, ln1b, xn);

    // fused QKV GEMM: [20000 x 256] x [256 x 768] -> q fp32 (scaled) + kv bf16
    gemm_bf16<3><<<dim3(157, 6), 256, 0, stream>>>(xn, WqkvT, bqkv, q, kv,
                                                   nullptr, nullptr, NN, DD, 768);

    ep_mfma<<<EE / 64, 256, 0, stream>>>(ef, WeT, be, eproj);

    attn_kernel<<<NN, 256, 0, stream>>>(q, kv, eproj, ew, csr, row_start, aggb);

    // Wo GEMM + residual: x1 = x + alpha*(agg @ Wo + bo)
    gemm_bf16<2><<<dim3(157, 2), 256, 0, stream>>>(aggb, WoT, bo, x1, nullptr,
                                                   x, alpha, NN, DD, DD);

    ln_kernel<<<NN / 4, 256, 0, stream>>>(x1, ln2g, ln2b, xn);

    // FFN up + GELU -> bf16
    gemm_bf16<1><<<dim3(157, 8), 256, 0, stream>>>(xn, W1T, b1, nullptr, ff1,
                                                   nullptr, nullptr, NN, DD, FFD);
    // FFN down + residual: out = x1 + beta*(ff1 @ W2 + b2)
    gemm_bf16<2><<<dim3(157, 2), 256, 0, stream>>>(ff1, W2T, b2, out, nullptr,
                                                   x1, beta, NN, FFD, DD);
}

// Round 7
// 319.318 us; speedup vs baseline: 16.5137x; 1.0934x over previous
//
#include <hip/hip_runtime.h>
#include <math.h>

// Problem constants (match reference)
#define NN 20000
#define EE 320000
#define DD 256
#define HH 8
#define DHD 32
#define EDF 64
#define FFD 1024

typedef unsigned short u16;
typedef __attribute__((ext_vector_type(8))) __bf16 bf16x8;
typedef __attribute__((ext_vector_type(4))) float f32x4;

// workspace float offsets
#define XN_OFF   (0)          // xn bf16 [NN][256]
#define AGGB_OFF (2560000)    // agg bf16 [NN][256]
#define X1_OFF   (5120000)    // x1 fp32 [NN][256]
#define QKV_OFF  (10240000)   // q fp32 [NN][256] + kv bf16 [NN][512]; ff1 bf16 overlays later
#define EP_OFF   (25600000)   // eproj bf16 [EE][32]
#define WT_OFF   (35840000)   // bf16 weights: WqkvT, WoT, W1T, W2T, WeT
#define BQKV_OFF (36240000)   // bqkv fp32 [768]
#define CSR_OFF  (36250000)   // int region

__device__ __forceinline__ u16 f2bf(float f) {
    unsigned u = __float_as_uint(f);
    return (u16)((u + 0x7FFFu + ((u >> 16) & 1u)) >> 16);
}
__device__ __forceinline__ float bf2f(u16 h) {
    return __uint_as_float(((unsigned)h) << 16);
}
__device__ __forceinline__ float gelu_exact(float v) {
    return 0.5f * v * (1.0f + erff(v * 0.70710678118654752f));
}

#define GLDS16(g, l) __builtin_amdgcn_global_load_lds(             \
    (__attribute__((address_space(1))) void*)(g),                  \
    (__attribute__((address_space(3))) void*)(l), 16, 0, 0)

// -------- LayerNorm -> bf16: one wave per row --------
__global__ __launch_bounds__(256) void ln_kernel(const float* __restrict__ x,
                                                 const float* __restrict__ g,
                                                 const float* __restrict__ b,
                                                 u16* __restrict__ out) {
    int row = blockIdx.x * 4 + (threadIdx.x >> 6);
    if (row >= NN) return;
    int lane = threadIdx.x & 63;
    float4 v = *(const float4*)&x[(size_t)row * DD + lane * 4];
    float s  = v.x + v.y + v.z + v.w;
    float ss = v.x * v.x + v.y * v.y + v.z * v.z + v.w * v.w;
    #pragma unroll
    for (int o = 32; o >= 1; o >>= 1) {
        s  += __shfl_xor(s, o);
        ss += __shfl_xor(ss, o);
    }
    float mean = s * (1.0f / DD);
    float var  = ss * (1.0f / DD) - mean * mean;
    float inv  = rsqrtf(var + 1e-5f);
    float4 gg = *(const float4*)&g[lane * 4];
    float4 bb = *(const float4*)&b[lane * 4];
    ushort4 o4;
    o4.x = f2bf((v.x - mean) * inv * gg.x + bb.x);
    o4.y = f2bf((v.y - mean) * inv * gg.y + bb.y);
    o4.z = f2bf((v.z - mean) * inv * gg.z + bb.z);
    o4.w = f2bf((v.w - mean) * inv * gg.w + bb.w);
    *(ushort4*)&out[(size_t)row * DD + lane * 4] = o4;
}

// -------- weight transpose+convert body: dst[n][k] = bf16(src[k][n]) --------
__device__ __forceinline__ void convw_body(const float* __restrict__ src,
                                           u16* __restrict__ dst, int K, int N,
                                           int vb) {
    int n = vb * 4 + (threadIdx.x >> 6);
    int lane = threadIdx.x & 63;
    if (n >= N) return;
    for (int k = lane * 4; k < K; k += 256) {
        ushort4 o;
        o.x = f2bf(src[(size_t)(k + 0) * N + n]);
        o.y = f2bf(src[(size_t)(k + 1) * N + n]);
        o.z = f2bf(src[(size_t)(k + 2) * N + n]);
        o.w = f2bf(src[(size_t)(k + 3) * N + n]);
        *(ushort4*)&dst[(size_t)n * K + k] = o;
    }
}

// single merged weight-prep kernel (saves 7 serial launches)
__global__ __launch_bounds__(256) void prep_kernel(
    const float* __restrict__ Wq, const float* __restrict__ Wk,
    const float* __restrict__ Wv, const float* __restrict__ Wo,
    const float* __restrict__ W1, const float* __restrict__ W2,
    const float* __restrict__ We,
    const float* __restrict__ bq, const float* __restrict__ bk,
    const float* __restrict__ bv,
    u16* __restrict__ WqkvT, u16* __restrict__ WoT, u16* __restrict__ W1T,
    u16* __restrict__ W2T, u16* __restrict__ WeT, float* __restrict__ bqkv) {
    int b = blockIdx.x;
    if      (b < 64)  convw_body(Wq, WqkvT,            256, 256,  b);
    else if (b < 128) convw_body(Wk, WqkvT + 65536,    256, 256,  b - 64);
    else if (b < 192) convw_body(Wv, WqkvT + 131072,   256, 256,  b - 128);
    else if (b < 256) convw_body(Wo, WoT,              256, 256,  b - 192);
    else if (b < 512) convw_body(W1, W1T,              256, 1024, b - 256);
    else if (b < 576) convw_body(W2, W2T,              1024, 256, b - 512);
    else if (b < 584) convw_body(We, WeT,              64,  32,   b - 576);
    else {
        int t = threadIdx.x;
        bqkv[t] = bq[t];
        bqkv[256 + t] = bk[t];
        bqkv[512 + t] = bv[t];
    }
}

// ======== bf16 MFMA GEMM: C = A[MxK] @ BT[NxK]^T + bias ========
// 128x128 tile, BK=64, 4 waves (2x2), 64x64 per wave, 16x16x32 bf16 MFMA.
// EPI: 0 = fp32 out, 1 = gelu->bf16 out, 2 = fp32 out = res + scale*(acc+bias)
//      3 = QKV: col<256 -> q fp32 * invsqrt(dh); col>=256 -> kv bf16 dim-interleaved
template <int EPI>
__global__ __launch_bounds__(256) void gemm_bf16(
    const u16* __restrict__ A, const u16* __restrict__ BT,
    const float* __restrict__ bias,
    float* __restrict__ Cf, u16* __restrict__ Cb,
    const float* __restrict__ res, const float* __restrict__ scale,
    int M, int K, int N)
{
    __shared__ u16 Asm[128 * 64];
    __shared__ u16 Bsm[128 * 64];
    const int tid  = threadIdx.x;
    const int lane = tid & 63;
    const int w    = tid >> 6;
    const int wr   = w >> 1, wc = w & 1;
    const int bm   = blockIdx.x * 128;
    const int bn   = blockIdx.y * 128;

    f32x4 acc[4][4] = {};

    int st_row[4], st_src[4], st_dst[4];
    #pragma unroll
    for (int i = 0; i < 4; i++) {
        int base  = i * 4096 + w * 1024;       // wave-uniform LDS byte base
        int off   = base + lane * 16;          // this lane's 16B lands here
        int row   = off >> 7;
        int inner = off & 127;
        st_row[i] = row;
        st_src[i] = (inner ^ ((row & 7) << 4)) >> 1;  // short idx within k-row
        st_dst[i] = base;
    }
    const int arow0 = wr * 64 + (lane & 15);
    const int brow0 = wc * 64 + (lane & 15);
    const int kb0   = (lane >> 4) * 16;        // byte offset of k in 128B row

    for (int k0 = 0; k0 < K; k0 += 64) {
        #pragma unroll
        for (int i = 0; i < 4; i++) {
            int r = bm + st_row[i]; if (r > M - 1) r = M - 1;
            GLDS16(A + (size_t)r * K + k0 + st_src[i], (char*)Asm + st_dst[i]);
        }
        #pragma unroll
        for (int i = 0; i < 4; i++) {
            int r = bn + st_row[i];
            GLDS16(BT + (size_t)r * K + k0 + st_src[i], (char*)Bsm + st_dst[i]);
        }
        asm volatile("s_waitcnt vmcnt(0)" ::: "memory");
        __syncthreads();
        #pragma unroll
        for (int s = 0; s < 2; s++) {
            bf16x8 af[4], bfv[4];
            #pragma unroll
            for (int i = 0; i < 4; i++) {
                int row  = arow0 + i * 16;
                int byte = (row << 7) + ((kb0 + s * 64) ^ ((row & 7) << 4));
                af[i] = *(const bf16x8*)((const char*)Asm + byte);
            }
            #pragma unroll
            for (int j = 0; j < 4; j++) {
                int row  = brow0 + j * 16;
                int byte = (row << 7) + ((kb0 + s * 64) ^ ((row & 7) << 4));
                bfv[j] = *(const bf16x8*)((const char*)Bsm + byte);
            }
            #pragma unroll
            for (int i = 0; i < 4; i++)
                #pragma unroll
                for (int j = 0; j < 4; j++)
                    acc[i][j] = __builtin_amdgcn_mfma_f32_16x16x32_bf16(
                        af[i], bfv[j], acc[i][j], 0, 0, 0);
        }
        __syncthreads();
    }

    float sc = 0.f;
    if constexpr (EPI == 2) sc = scale[0];
    const int col0 = bn + wc * 64 + (lane & 15);
    const int row0 = bm + wr * 64 + ((lane >> 4) << 2);
    #pragma unroll
    for (int i = 0; i < 4; i++) {
        #pragma unroll
        for (int j = 0; j < 4; j++) {
            int col = col0 + j * 16;
            float bb = bias[col];
            #pragma unroll
            for (int r = 0; r < 4; r++) {
                int row = row0 + i * 16 + r;
                if (row < M) {
                    float o = acc[i][j][r] + bb;
                    if constexpr (EPI == 1) {
                        Cb[(size_t)row * N + col] = f2bf(gelu_exact(o));
                    } else if constexpr (EPI == 2) {
                        Cf[(size_t)row * N + col] = res[(size_t)row * N + col] + sc * o;
                    } else if constexpr (EPI == 3) {
                        if (col < 256) {
                            Cf[(size_t)row * 256 + col] = o * 0.17677669529663689f;
                        } else if (col < 512) {
                            Cb[(size_t)row * 512 + (col - 256) * 2] = f2bf(o);
                        } else {
                            Cb[(size_t)row * 512 + (col - 512) * 2 + 1] = f2bf(o);
                        }
                    } else {
                        Cf[(size_t)row * N + col] = o;
                    }
                }
            }
        }
    }
}

// -------- edge projection via MFMA: ep[E x 32] = bf16(ef @ We + be) --------
__global__ __launch_bounds__(256) void ep_mfma(const float* __restrict__ ef,
                                               const u16* __restrict__ WeT,
                                               const float* __restrict__ be,
                                               u16* __restrict__ eproj) {
    const int lane = threadIdx.x & 63;
    const int wv   = threadIdx.x >> 6;
    const int e0   = blockIdx.x * 64 + wv * 16;     // 16 edges per wave
    const int ar   = lane & 15;                      // A row within frag
    const int k8   = (lane >> 4) * 8;                // k-offset of this lane's 8 elems

    f32x4 acc[2] = {};
    #pragma unroll
    for (int s = 0; s < 2; s++) {
        const float* ap = ef + (size_t)(e0 + ar) * EDF + s * 32 + k8;
        float4 a0 = *(const float4*)ap;
        float4 a1 = *(const float4*)(ap + 4);
        bf16x8 af;
        af[0] = (__bf16)a0.x; af[1] = (__bf16)a0.y; af[2] = (__bf16)a0.z; af[3] = (__bf16)a0.w;
        af[4] = (__bf16)a1.x; af[5] = (__bf16)a1.y; af[6] = (__bf16)a1.z; af[7] = (__bf16)a1.w;
        #pragma unroll
        for (int j = 0; j < 2; j++) {
            bf16x8 bf = *(const bf16x8*)&WeT[(size_t)(j * 16 + ar) * EDF + s * 32 + k8];
            acc[j] = __builtin_amdgcn_mfma_f32_16x16x32_bf16(af, bf, acc[j], 0, 0, 0);
        }
    }
    const int row0 = (lane >> 4) << 2;
    #pragma unroll
    for (int j = 0; j < 2; j++) {
        int col = j * 16 + ar;
        float bb = be[col];
        #pragma unroll
        for (int r = 0; r < 4; r++) {
            eproj[(size_t)(e0 + row0 + r) * DHD + col] = f2bf(acc[j][r] + bb);
        }
    }
}

// ======== CSR build over dst ========
__global__ __launch_bounds__(256) void count_kernel(const int* __restrict__ ei,
                                                    int* __restrict__ counts) {
    int e = blockIdx.x * 256 + threadIdx.x;
    if (e >= EE) return;
    atomicAdd(&counts[ei[EE + e]], 1);
}

__global__ __launch_bounds__(1024) void scan_kernel(const int* __restrict__ counts,
                                                    int* __restrict__ row_start,
                                                    int* __restrict__ cursor) {
    __shared__ int part[1024];
    const int CH = 20;
    int t = threadIdx.x;
    int base = t * CH;
    int loc[CH];
    int s = 0;
    #pragma unroll
    for (int i = 0; i < CH; i++) {
        int idx = base + i;
        int c = (idx < NN) ? counts[idx] : 0;
        loc[i] = s;
        s += c;
    }
    part[t] = s;
    __syncthreads();
    for (int o = 1; o < 1024; o <<= 1) {
        int vv = (t >= o) ? part[t - o] : 0;
        __syncthreads();
        part[t] += vv;
        __syncthreads();
    }
    int off = (t > 0) ? part[t - 1] : 0;
    #pragma unroll
    for (int i = 0; i < CH; i++) {
        int idx = base + i;
        if (idx < NN) {
            int rs = off + loc[i];
            row_start[idx] = rs;
            cursor[idx] = rs;
        }
    }
    if (t == 1023) row_start[NN] = part[1023];
}

// fill CSR with (src, edge) pairs -> removes one dependent-load level in attn
__global__ __launch_bounds__(256) void fill_kernel(const int* __restrict__ ei,
                                                   int* __restrict__ cursor,
                                                   int2* __restrict__ csr) {
    int e = blockIdx.x * 256 + threadIdx.x;
    if (e >= EE) return;
    int src = ei[e];
    int dst = ei[EE + e];
    int pos = atomicAdd(&cursor[dst], 1);
    csr[pos] = make_int2(src, e);
}

// ======== fused gather attention: ONE WAVE per dst node ========
// lane = h*8+g handles dims d0=h*32+g*4..+3. kv gather is one dwordx4
// (4 interleaved k,v pairs), eproj one dwordx2; dot = 4 local FMA + 3-stage
// shfl_xor within the 8-lane head group. No max-subtraction (shift-invariant
// softmax, scores bounded ~|10|). 4-edge unroll for ILP.
__global__ __launch_bounds__(256) void attn_kernel(const float* __restrict__ q,
                                                   const u16* __restrict__ kv,
                                                   const u16* __restrict__ eproj,
                                                   const float* __restrict__ ew,
                                                   const int2* __restrict__ csr,
                                                   const int* __restrict__ row_start,
                                                   u16* __restrict__ aggb) {
    const int dst  = blockIdx.x * 4 + (threadIdx.x >> 6);
    const int lane = threadIdx.x & 63;
    const int g    = lane & 7;
    const int d0   = (lane >> 3) * 32 + g * 4;     // first of this lane's 4 dims
    const int beg = row_start[dst];
    const int end = row_start[dst + 1];
    float4 qv = *(const float4*)&q[(size_t)dst * DD + d0];
    float ss = 0.f;
    float4 acc = make_float4(0.f, 0.f, 0.f, 0.f);

    int i = beg;
    for (; i + 4 <= end; i += 4) {
        float4 vv[4];
        float pp[4], wt[4];
        #pragma unroll
        for (int u = 0; u < 4; u++) {
            int2 p = csr[i + u];
            const u16* kvr = &kv[(size_t)p.x * 512 + d0 * 2];
            ushort4 a = *(const ushort4*)kvr;        // k0,v0,k1,v1
            ushort4 b = *(const ushort4*)(kvr + 4);  // k2,v2,k3,v3
            ushort4 e4 = *(const ushort4*)&eproj[(size_t)p.y * DHD + g * 4];
            float k0 = bf2f(a.x) + bf2f(e4.x);
            float k1 = bf2f(a.z) + bf2f(e4.y);
            float k2 = bf2f(b.x) + bf2f(e4.z);
            float k3 = bf2f(b.z) + bf2f(e4.w);
            vv[u] = make_float4(bf2f(a.y), bf2f(a.w), bf2f(b.y), bf2f(b.w));
            wt[u] = ew[p.y];
            pp[u] = fmaf(qv.x, k0, fmaf(qv.y, k1, fmaf(qv.z, k2, qv.w * k3)));
        }
        #pragma unroll
        for (int o = 4; o >= 1; o >>= 1) {
            #pragma unroll
            for (int u = 0; u < 4; u++) pp[u] += __shfl_xor(pp[u], o);
        }
        #pragma unroll
        for (int u = 0; u < 4; u++) {
            float wq = __expf(pp[u] * wt[u]);
            ss += wq;
            acc.x = fmaf(wq, vv[u].x, acc.x);
            acc.y = fmaf(wq, vv[u].y, acc.y);
            acc.z = fmaf(wq, vv[u].z, acc.z);
            acc.w = fmaf(wq, vv[u].w, acc.w);
        }
    }
    for (; i < end; ++i) {
        int2 p = csr[i];
        const u16* kvr = &kv[(size_t)p.x * 512 + d0 * 2];
        ushort4 a = *(const ushort4*)kvr;
        ushort4 b = *(const ushort4*)(kvr + 4);
        ushort4 e4 = *(const ushort4*)&eproj[(size_t)p.y * DHD + g * 4];
        float k0 = bf2f(a.x) + bf2f(e4.x);
        float k1 = bf2f(a.z) + bf2f(e4.y);
        float k2 = bf2f(b.x) + bf2f(e4.z);
        float k3 = bf2f(b.z) + bf2f(e4.w);
        float pv = fmaf(qv.x, k0, fmaf(qv.y, k1, fmaf(qv.z, k2, qv.w * k3)));
        #pragma unroll
        for (int o = 4; o >= 1; o >>= 1) pv += __shfl_xor(pv, o);
        float wq = __expf(pv * ew[p.y]);
        ss += wq;
        acc.x = fmaf(wq, bf2f(a.y), acc.x);
        acc.y = fmaf(wq, bf2f(a.w), acc.y);
        acc.z = fmaf(wq, bf2f(b.y), acc.z);
        acc.w = fmaf(wq, bf2f(b.w), acc.w);
    }
    float inv = (end > beg) ? 1.f / ss : 0.f;
    ushort4 o4;
    o4.x = f2bf(acc.x * inv);
    o4.y = f2bf(acc.y * inv);
    o4.z = f2bf(acc.z * inv);
    o4.w = f2bf(acc.w * inv);
    *(ushort4*)&aggb[(size_t)dst * DD + d0] = o4;
}

extern "C" void kernel_launch(void* const* d_in, const int* in_sizes, int n_in,
                              void* d_out, int out_size, void* d_ws, size_t ws_size,
                              hipStream_t stream) {
    const float* x    = (const float*)d_in[0];
    const float* ef   = (const float*)d_in[1];
    const float* ew   = (const float*)d_in[2];
    const int*   ei   = (const int*)d_in[3];
    const float* Wq   = (const float*)d_in[4];
    const float* bq   = (const float*)d_in[5];
    const float* Wk   = (const float*)d_in[6];
    const float* bk   = (const float*)d_in[7];
    const float* Wv   = (const float*)d_in[8];
    const float* bv   = (const float*)d_in[9];
    const float* We   = (const float*)d_in[10];
    const float* be   = (const float*)d_in[11];
    const float* Wo   = (const float*)d_in[12];
    const float* bo   = (const float*)d_in[13];
    const float* ln1g = (const float*)d_in[14];
    const float* ln1b = (const float*)d_in[15];
    const float* ln2g = (const float*)d_in[16];
    const float* ln2b = (const float*)d_in[17];
    const float* W1   = (const float*)d_in[18];
    const float* b1   = (const float*)d_in[19];
    const float* W2   = (const float*)d_in[20];
    const float* b2   = (const float*)d_in[21];
    const float* alpha = (const float*)d_in[22];
    const float* beta  = (const float*)d_in[23];

    float* ws    = (float*)d_ws;
    u16*   xn    = (u16*)(ws + XN_OFF);
    u16*   aggb  = (u16*)(ws + AGGB_OFF);
    float* x1    = ws + X1_OFF;
    float* q     = ws + QKV_OFF;                 // [NN][256] fp32, pre-scaled
    u16*   kv    = (u16*)(ws + QKV_OFF + NN * DD); // [NN][512] bf16 dim-interleaved
    u16*   ff1   = (u16*)(ws + QKV_OFF);         // overlays q+kv after attn
    u16*   eproj = (u16*)(ws + EP_OFF);
    u16*   wt    = (u16*)(ws + WT_OFF);
    u16*   WqkvT = wt;                      // [768][256]
    u16*   WoT   = wt + 768 * 256;          // [256][256]
    u16*   W1T   = WoT + 256 * 256;         // [1024][256]
    u16*   W2T   = W1T + 1024 * 256;        // [256][1024]
    u16*   WeT   = W2T + 256 * 1024;        // [32][64]
    float* bqkv  = ws + BQKV_OFF;
    float* out   = (float*)d_out;

    int*  counts    = (int*)(ws + CSR_OFF);
    int*  row_start = counts + NN;
    int*  cursor    = row_start + NN + 1;
    int2* csr       = (int2*)(counts + 60002);   // 8B-aligned

    hipMemsetAsync(counts, 0, (size_t)NN * sizeof(int), stream);

    prep_kernel<<<585, 256, 0, stream>>>(Wq, Wk, Wv, Wo, W1, W2, We, bq, bk, bv,
                                         WqkvT, WoT, W1T, W2T, WeT, bqkv);

    count_kernel<<<EE / 256, 256, 0, stream>>>(ei, counts);
    scan_kernel<<<1, 1024, 0, stream>>>(counts, row_start, cursor);
    fill_kernel<<<EE / 256, 256, 0, stream>>>(ei, cursor, csr);

    ln_kernel<<<NN / 4, 256, 0, stream>>>(x, ln1g, ln1b, xn);

    // fused QKV GEMM: [20000 x 256] x [256 x 768] -> q fp32 (scaled) + kv bf16
    gemm_bf16<3><<<dim3(157, 6), 256, 0, stream>>>(xn, WqkvT, bqkv, q, kv,
                                                   nullptr, nullptr, NN, DD, 768);

    ep_mfma<<<EE / 64, 256, 0, stream>>>(ef, WeT, be, eproj);

    attn_kernel<<<NN / 4, 256, 0, stream>>>(q, kv, eproj, ew, csr, row_start, aggb);

    // Wo GEMM + residual: x1 = x + alpha*(agg @ Wo + bo)
    gemm_bf16<2><<<dim3(157, 2), 256, 0, stream>>>(aggb, WoT, bo, x1, nullptr,
                                                   x, alpha, NN, DD, DD);

    ln_kernel<<<NN / 4, 256, 0, stream>>>(x1, ln2g, ln2b, xn);

    // FFN up + GELU -> bf16
    gemm_bf16<1><<<dim3(157, 8), 256, 0, stream>>>(xn, W1T, b1, nullptr, ff1,
                                                   nullptr, nullptr, NN, DD, FFD);
    // FFN down + residual: out = x1 + beta*(ff1 @ W2 + b2)
    gemm_bf16<2><<<dim3(157, 2), 256, 0, stream>>>(ff1, W2T, b2, out, nullptr,
                                                   x1, beta, NN, FFD, DD);
}

// Round 8
// 304.585 us; speedup vs baseline: 17.3125x; 1.0484x over previous
//
#include <hip/hip_runtime.h>
#include <math.h>

// Problem constants (match reference)
#define NN 20000
#define EE 320000
#define DD 256
#define HH 8
#define DHD 32
#define EDF 64
#define FFD 1024

typedef unsigned short u16;
typedef __attribute__((ext_vector_type(8))) __bf16 bf16x8;
typedef __attribute__((ext_vector_type(4))) float f32x4;

// workspace float offsets
#define XN_OFF   (0)          // xn bf16 [NN][256]
#define AGGB_OFF (2560000)    // agg bf16 [NN][256]
#define X1_OFF   (5120000)    // x1 fp32 [NN][256]
#define QKV_OFF  (10240000)   // q fp32 [NN][256] + kv bf16 [NN][512]; ff1 bf16 overlays later
#define EP_OFF   (25600000)   // epc bf16 [EE][32] (CSR-ordered edge projections)
#define WT_OFF   (35840000)   // bf16 weights: WqkvT, WoT, W1T, W2T, WeT
#define BQKV_OFF (36240000)   // bqkv fp32 [768]
#define CSR_OFF  (36250000)   // int region

__device__ __forceinline__ u16 f2bf(float f) {
    unsigned u = __float_as_uint(f);
    return (u16)((u + 0x7FFFu + ((u >> 16) & 1u)) >> 16);
}
__device__ __forceinline__ float bf2f(u16 h) {
    return __uint_as_float(((unsigned)h) << 16);
}
__device__ __forceinline__ float gelu_exact(float v) {
    return 0.5f * v * (1.0f + erff(v * 0.70710678118654752f));
}

#define GLDS16(g, l) __builtin_amdgcn_global_load_lds(             \
    (__attribute__((address_space(1))) void*)(g),                  \
    (__attribute__((address_space(3))) void*)(l), 16, 0, 0)

// -------- LayerNorm -> bf16: one wave per row --------
__global__ __launch_bounds__(256) void ln_kernel(const float* __restrict__ x,
                                                 const float* __restrict__ g,
                                                 const float* __restrict__ b,
                                                 u16* __restrict__ out) {
    int row = blockIdx.x * 4 + (threadIdx.x >> 6);
    if (row >= NN) return;
    int lane = threadIdx.x & 63;
    float4 v = *(const float4*)&x[(size_t)row * DD + lane * 4];
    float s  = v.x + v.y + v.z + v.w;
    float ss = v.x * v.x + v.y * v.y + v.z * v.z + v.w * v.w;
    #pragma unroll
    for (int o = 32; o >= 1; o >>= 1) {
        s  += __shfl_xor(s, o);
        ss += __shfl_xor(ss, o);
    }
    float mean = s * (1.0f / DD);
    float var  = ss * (1.0f / DD) - mean * mean;
    float inv  = rsqrtf(var + 1e-5f);
    float4 gg = *(const float4*)&g[lane * 4];
    float4 bb = *(const float4*)&b[lane * 4];
    ushort4 o4;
    o4.x = f2bf((v.x - mean) * inv * gg.x + bb.x);
    o4.y = f2bf((v.y - mean) * inv * gg.y + bb.y);
    o4.z = f2bf((v.z - mean) * inv * gg.z + bb.z);
    o4.w = f2bf((v.w - mean) * inv * gg.w + bb.w);
    *(ushort4*)&out[(size_t)row * DD + lane * 4] = o4;
}

// -------- weight transpose+convert body: dst[n][k] = bf16(src[k][n]) --------
__device__ __forceinline__ void convw_body(const float* __restrict__ src,
                                           u16* __restrict__ dst, int K, int N,
                                           int vb) {
    int n = vb * 4 + (threadIdx.x >> 6);
    int lane = threadIdx.x & 63;
    if (n >= N) return;
    for (int k = lane * 4; k < K; k += 256) {
        ushort4 o;
        o.x = f2bf(src[(size_t)(k + 0) * N + n]);
        o.y = f2bf(src[(size_t)(k + 1) * N + n]);
        o.z = f2bf(src[(size_t)(k + 2) * N + n]);
        o.w = f2bf(src[(size_t)(k + 3) * N + n]);
        *(ushort4*)&dst[(size_t)n * K + k] = o;
    }
}

// single merged weight-prep kernel
__global__ __launch_bounds__(256) void prep_kernel(
    const float* __restrict__ Wq, const float* __restrict__ Wk,
    const float* __restrict__ Wv, const float* __restrict__ Wo,
    const float* __restrict__ W1, const float* __restrict__ W2,
    const float* __restrict__ We,
    const float* __restrict__ bq, const float* __restrict__ bk,
    const float* __restrict__ bv,
    u16* __restrict__ WqkvT, u16* __restrict__ WoT, u16* __restrict__ W1T,
    u16* __restrict__ W2T, u16* __restrict__ WeT, float* __restrict__ bqkv) {
    int b = blockIdx.x;
    if      (b < 64)  convw_body(Wq, WqkvT,            256, 256,  b);
    else if (b < 128) convw_body(Wk, WqkvT + 65536,    256, 256,  b - 64);
    else if (b < 192) convw_body(Wv, WqkvT + 131072,   256, 256,  b - 128);
    else if (b < 256) convw_body(Wo, WoT,              256, 256,  b - 192);
    else if (b < 512) convw_body(W1, W1T,              256, 1024, b - 256);
    else if (b < 576) convw_body(W2, W2T,              1024, 256, b - 512);
    else if (b < 584) convw_body(We, WeT,              64,  32,   b - 576);
    else {
        int t = threadIdx.x;
        bqkv[t] = bq[t];
        bqkv[256 + t] = bk[t];
        bqkv[512 + t] = bv[t];
    }
}

// ======== bf16 MFMA GEMM: C = A[MxK] @ BT[NxK]^T + bias ========
// BMxBN tile, BK=64, 4 waves (2x2), 16x16x32 bf16 MFMA, XOR-swizzled LDS.
// EPI: 0 = fp32 out, 1 = gelu->bf16 out, 2 = fp32 out = res + scale*(acc+bias)
//      3 = QKV: col<256 -> q fp32 * invsqrt(dh); col>=256 -> kv bf16 dim-interleaved
template <int BM, int BN, int EPI>
__global__ __launch_bounds__(256) void gemm_bf16(
    const u16* __restrict__ A, const u16* __restrict__ BT,
    const float* __restrict__ bias,
    float* __restrict__ Cf, u16* __restrict__ Cb,
    const float* __restrict__ res, const float* __restrict__ scale,
    int M, int K, int N)
{
    constexpr int FM = BM / 32, FN = BN / 32;
    constexpr int nA = BM / 32, nB = BN / 32;
    constexpr int NST = (nA > nB) ? nA : nB;
    __shared__ u16 Asm[BM * 64];
    __shared__ u16 Bsm[BN * 64];
    const int tid  = threadIdx.x;
    const int lane = tid & 63;
    const int w    = tid >> 6;
    const int wr   = w >> 1, wc = w & 1;
    const int bm   = blockIdx.x * BM;
    const int bn   = blockIdx.y * BN;

    f32x4 acc[FM][FN] = {};

    int st_row[NST], st_src[NST], st_dst[NST];
    #pragma unroll
    for (int i = 0; i < NST; i++) {
        int base  = i * 4096 + w * 1024;       // wave-uniform LDS byte base
        int off   = base + lane * 16;          // this lane's 16B lands here
        int row   = off >> 7;
        int inner = off & 127;
        st_row[i] = row;
        st_src[i] = (inner ^ ((row & 7) << 4)) >> 1;  // short idx within k-row
        st_dst[i] = base;
    }
    const int arow0 = wr * (BM / 2) + (lane & 15);
    const int brow0 = wc * (BN / 2) + (lane & 15);
    const int kb0   = (lane >> 4) * 16;        // byte offset of k in 128B row

    for (int k0 = 0; k0 < K; k0 += 64) {
        #pragma unroll
        for (int i = 0; i < nA; i++) {
            int r = bm + st_row[i]; if (r > M - 1) r = M - 1;
            GLDS16(A + (size_t)r * K + k0 + st_src[i], (char*)Asm + st_dst[i]);
        }
        #pragma unroll
        for (int i = 0; i < nB; i++) {
            int r = bn + st_row[i];
            GLDS16(BT + (size_t)r * K + k0 + st_src[i], (char*)Bsm + st_dst[i]);
        }
        asm volatile("s_waitcnt vmcnt(0)" ::: "memory");
        __syncthreads();
        #pragma unroll
        for (int s = 0; s < 2; s++) {
            bf16x8 af[FM], bfv[FN];
            #pragma unroll
            for (int i = 0; i < FM; i++) {
                int row  = arow0 + i * 16;
                int byte = (row << 7) + ((kb0 + s * 64) ^ ((row & 7) << 4));
                af[i] = *(const bf16x8*)((const char*)Asm + byte);
            }
            #pragma unroll
            for (int j = 0; j < FN; j++) {
                int row  = brow0 + j * 16;
                int byte = (row << 7) + ((kb0 + s * 64) ^ ((row & 7) << 4));
                bfv[j] = *(const bf16x8*)((const char*)Bsm + byte);
            }
            #pragma unroll
            for (int i = 0; i < FM; i++)
                #pragma unroll
                for (int j = 0; j < FN; j++)
                    acc[i][j] = __builtin_amdgcn_mfma_f32_16x16x32_bf16(
                        af[i], bfv[j], acc[i][j], 0, 0, 0);
        }
        __syncthreads();
    }

    float sc = 0.f;
    if constexpr (EPI == 2) sc = scale[0];
    const int col0 = bn + wc * (BN / 2) + (lane & 15);
    const int row0 = bm + wr * (BM / 2) + ((lane >> 4) << 2);
    #pragma unroll
    for (int i = 0; i < FM; i++) {
        #pragma unroll
        for (int j = 0; j < FN; j++) {
            int col = col0 + j * 16;
            float bb = bias[col];
            #pragma unroll
            for (int r = 0; r < 4; r++) {
                int row = row0 + i * 16 + r;
                if (row < M) {
                    float o = acc[i][j][r] + bb;
                    if constexpr (EPI == 1) {
                        Cb[(size_t)row * N + col] = f2bf(gelu_exact(o));
                    } else if constexpr (EPI == 2) {
                        Cf[(size_t)row * N + col] = res[(size_t)row * N + col] + sc * o;
                    } else if constexpr (EPI == 3) {
                        if (col < 256) {
                            Cf[(size_t)row * 256 + col] = o * 0.17677669529663689f;
                        } else if (col < 512) {
                            Cb[(size_t)row * 512 + (col - 256) * 2] = f2bf(o);
                        } else {
                            Cb[(size_t)row * 512 + (col - 512) * 2 + 1] = f2bf(o);
                        }
                    } else {
                        Cf[(size_t)row * N + col] = o;
                    }
                }
            }
        }
    }
}

// -------- edge projection via MFMA, scatter-written in CSR order --------
__global__ __launch_bounds__(256) void ep_mfma(const float* __restrict__ ef,
                                               const u16* __restrict__ WeT,
                                               const float* __restrict__ be,
                                               const int* __restrict__ epos,
                                               u16* __restrict__ epc) {
    const int lane = threadIdx.x & 63;
    const int wv   = threadIdx.x >> 6;
    const int e0   = blockIdx.x * 64 + wv * 16;     // 16 edges per wave
    const int ar   = lane & 15;                      // A row within frag
    const int k8   = (lane >> 4) * 8;                // k-offset of this lane's 8 elems

    f32x4 acc[2] = {};
    #pragma unroll
    for (int s = 0; s < 2; s++) {
        const float* ap = ef + (size_t)(e0 + ar) * EDF + s * 32 + k8;
        float4 a0 = *(const float4*)ap;
        float4 a1 = *(const float4*)(ap + 4);
        bf16x8 af;
        af[0] = (__bf16)a0.x; af[1] = (__bf16)a0.y; af[2] = (__bf16)a0.z; af[3] = (__bf16)a0.w;
        af[4] = (__bf16)a1.x; af[5] = (__bf16)a1.y; af[6] = (__bf16)a1.z; af[7] = (__bf16)a1.w;
        #pragma unroll
        for (int j = 0; j < 2; j++) {
            bf16x8 bf = *(const bf16x8*)&WeT[(size_t)(j * 16 + ar) * EDF + s * 32 + k8];
            acc[j] = __builtin_amdgcn_mfma_f32_16x16x32_bf16(af, bf, acc[j], 0, 0, 0);
        }
    }
    const int row0 = (lane >> 4) << 2;
    #pragma unroll
    for (int r = 0; r < 4; r++) {
        int pos = epos[e0 + row0 + r];
        #pragma unroll
        for (int j = 0; j < 2; j++) {
            int col = j * 16 + ar;
            epc[(size_t)pos * DHD + col] = f2bf(acc[j][r] + be[col]);
        }
    }
}

// ======== CSR build over dst ========
__global__ __launch_bounds__(256) void count_kernel(const int* __restrict__ ei,
                                                    int* __restrict__ counts) {
    int e = blockIdx.x * 256 + threadIdx.x;
    if (e >= EE) return;
    atomicAdd(&counts[ei[EE + e]], 1);
}

__global__ __launch_bounds__(1024) void scan_kernel(const int* __restrict__ counts,
                                                    int* __restrict__ row_start,
                                                    int* __restrict__ cursor) {
    __shared__ int part[1024];
    const int CH = 20;
    int t = threadIdx.x;
    int base = t * CH;
    int loc[CH];
    int s = 0;
    #pragma unroll
    for (int i = 0; i < CH; i++) {
        int idx = base + i;
        int c = (idx < NN) ? counts[idx] : 0;
        loc[i] = s;
        s += c;
    }
    part[t] = s;
    __syncthreads();
    for (int o = 1; o < 1024; o <<= 1) {
        int vv = (t >= o) ? part[t - o] : 0;
        __syncthreads();
        part[t] += vv;
        __syncthreads();
    }
    int off = (t > 0) ? part[t - 1] : 0;
    #pragma unroll
    for (int i = 0; i < CH; i++) {
        int idx = base + i;
        if (idx < NN) {
            int rs = off + loc[i];
            row_start[idx] = rs;
            cursor[idx] = rs;
        }
    }
    if (t == 1023) row_start[NN] = part[1023];
}

// fill CSR with (src, ew) pairs + inverse permutation epos[e] = pos
__global__ __launch_bounds__(256) void fill_kernel(const int* __restrict__ ei,
                                                   const float* __restrict__ ew,
                                                   int* __restrict__ cursor,
                                                   int2* __restrict__ csr,
                                                   int* __restrict__ epos) {
    int e = blockIdx.x * 256 + threadIdx.x;
    if (e >= EE) return;
    int src = ei[e];
    int dst = ei[EE + e];
    int pos = atomicAdd(&cursor[dst], 1);
    csr[pos] = make_int2(src, __float_as_int(ew[e]));
    epos[e] = pos;
}

// ======== fused gather attention: ONE WAVE per dst node ========
// lane = h*8+g handles dims d0=h*32+g*4..+3. Per edge: csr 8B broadcast
// (src+ew), epc 64B SEQUENTIAL (CSR-ordered), kv 16B/lane coalesced row.
// No max-subtraction (shift-invariant softmax, bounded scores).
// 8-edge unroll for memory-level parallelism.
__global__ __launch_bounds__(256) void attn_kernel(const float* __restrict__ q,
                                                   const u16* __restrict__ kv,
                                                   const u16* __restrict__ epc,
                                                   const int2* __restrict__ csr,
                                                   const int* __restrict__ row_start,
                                                   u16* __restrict__ aggb) {
    const int dst  = blockIdx.x * 4 + (threadIdx.x >> 6);
    const int lane = threadIdx.x & 63;
    const int g    = lane & 7;
    const int d0   = (lane >> 3) * 32 + g * 4;     // first of this lane's 4 dims
    const int beg = row_start[dst];
    const int end = row_start[dst + 1];
    float4 qv = *(const float4*)&q[(size_t)dst * DD + d0];
    float ss = 0.f;
    float4 acc = make_float4(0.f, 0.f, 0.f, 0.f);

    int i = beg;
    for (; i + 8 <= end; i += 8) {
        ushort4 a[8], b[8], e4[8];
        float wt[8];
        #pragma unroll
        for (int u = 0; u < 8; u++) {
            int2 p = csr[i + u];
            const u16* kvr = &kv[(size_t)p.x * 512 + d0 * 2];
            a[u]  = *(const ushort4*)kvr;        // k0,v0,k1,v1
            b[u]  = *(const ushort4*)(kvr + 4);  // k2,v2,k3,v3
            e4[u] = *(const ushort4*)&epc[(size_t)(i + u) * DHD + g * 4];
            wt[u] = __int_as_float(p.y);
        }
        float pp[8];
        #pragma unroll
        for (int u = 0; u < 8; u++) {
            float k0 = bf2f(a[u].x) + bf2f(e4[u].x);
            float k1 = bf2f(a[u].z) + bf2f(e4[u].y);
            float k2 = bf2f(b[u].x) + bf2f(e4[u].z);
            float k3 = bf2f(b[u].z) + bf2f(e4[u].w);
            pp[u] = fmaf(qv.x, k0, fmaf(qv.y, k1, fmaf(qv.z, k2, qv.w * k3)));
        }
        #pragma unroll
        for (int o = 4; o >= 1; o >>= 1) {
            #pragma unroll
            for (int u = 0; u < 8; u++) pp[u] += __shfl_xor(pp[u], o);
        }
        #pragma unroll
        for (int u = 0; u < 8; u++) {
            float wq = __expf(pp[u] * wt[u]);
            ss += wq;
            acc.x = fmaf(wq, bf2f(a[u].y), acc.x);
            acc.y = fmaf(wq, bf2f(a[u].w), acc.y);
            acc.z = fmaf(wq, bf2f(b[u].y), acc.z);
            acc.w = fmaf(wq, bf2f(b[u].w), acc.w);
        }
    }
    if (i + 4 <= end) {
        ushort4 a[4], b[4], e4[4];
        float wt[4];
        #pragma unroll
        for (int u = 0; u < 4; u++) {
            int2 p = csr[i + u];
            const u16* kvr = &kv[(size_t)p.x * 512 + d0 * 2];
            a[u]  = *(const ushort4*)kvr;
            b[u]  = *(const ushort4*)(kvr + 4);
            e4[u] = *(const ushort4*)&epc[(size_t)(i + u) * DHD + g * 4];
            wt[u] = __int_as_float(p.y);
        }
        float pp[4];
        #pragma unroll
        for (int u = 0; u < 4; u++) {
            float k0 = bf2f(a[u].x) + bf2f(e4[u].x);
            float k1 = bf2f(a[u].z) + bf2f(e4[u].y);
            float k2 = bf2f(b[u].x) + bf2f(e4[u].z);
            float k3 = bf2f(b[u].z) + bf2f(e4[u].w);
            pp[u] = fmaf(qv.x, k0, fmaf(qv.y, k1, fmaf(qv.z, k2, qv.w * k3)));
        }
        #pragma unroll
        for (int o = 4; o >= 1; o >>= 1) {
            #pragma unroll
            for (int u = 0; u < 4; u++) pp[u] += __shfl_xor(pp[u], o);
        }
        #pragma unroll
        for (int u = 0; u < 4; u++) {
            float wq = __expf(pp[u] * wt[u]);
            ss += wq;
            acc.x = fmaf(wq, bf2f(a[u].y), acc.x);
            acc.y = fmaf(wq, bf2f(a[u].w), acc.y);
            acc.z = fmaf(wq, bf2f(b[u].y), acc.z);
            acc.w = fmaf(wq, bf2f(b[u].w), acc.w);
        }
        i += 4;
    }
    for (; i < end; ++i) {
        int2 p = csr[i];
        const u16* kvr = &kv[(size_t)p.x * 512 + d0 * 2];
        ushort4 a = *(const ushort4*)kvr;
        ushort4 b = *(const ushort4*)(kvr + 4);
        ushort4 e4 = *(const ushort4*)&epc[(size_t)i * DHD + g * 4];
        float k0 = bf2f(a.x) + bf2f(e4.x);
        float k1 = bf2f(a.z) + bf2f(e4.y);
        float k2 = bf2f(b.x) + bf2f(e4.z);
        float k3 = bf2f(b.z) + bf2f(e4.w);
        float pv = fmaf(qv.x, k0, fmaf(qv.y, k1, fmaf(qv.z, k2, qv.w * k3)));
        #pragma unroll
        for (int o = 4; o >= 1; o >>= 1) pv += __shfl_xor(pv, o);
        float wq = __expf(pv * __int_as_float(p.y));
        ss += wq;
        acc.x = fmaf(wq, bf2f(a.y), acc.x);
        acc.y = fmaf(wq, bf2f(a.w), acc.y);
        acc.z = fmaf(wq, bf2f(b.y), acc.z);
        acc.w = fmaf(wq, bf2f(b.w), acc.w);
    }
    float inv = (end > beg) ? 1.f / ss : 0.f;
    ushort4 o4;
    o4.x = f2bf(acc.x * inv);
    o4.y = f2bf(acc.y * inv);
    o4.z = f2bf(acc.z * inv);
    o4.w = f2bf(acc.w * inv);
    *(ushort4*)&aggb[(size_t)dst * DD + d0] = o4;
}

extern "C" void kernel_launch(void* const* d_in, const int* in_sizes, int n_in,
                              void* d_out, int out_size, void* d_ws, size_t ws_size,
                              hipStream_t stream) {
    const float* x    = (const float*)d_in[0];
    const float* ef   = (const float*)d_in[1];
    const float* ew   = (const float*)d_in[2];
    const int*   ei   = (const int*)d_in[3];
    const float* Wq   = (const float*)d_in[4];
    const float* bq   = (const float*)d_in[5];
    const float* Wk   = (const float*)d_in[6];
    const float* bk   = (const float*)d_in[7];
    const float* Wv   = (const float*)d_in[8];
    const float* bv   = (const float*)d_in[9];
    const float* We   = (const float*)d_in[10];
    const float* be   = (const float*)d_in[11];
    const float* Wo   = (const float*)d_in[12];
    const float* bo   = (const float*)d_in[13];
    const float* ln1g = (const float*)d_in[14];
    const float* ln1b = (const float*)d_in[15];
    const float* ln2g = (const float*)d_in[16];
    const float* ln2b = (const float*)d_in[17];
    const float* W1   = (const float*)d_in[18];
    const float* b1   = (const float*)d_in[19];
    const float* W2   = (const float*)d_in[20];
    const float* b2   = (const float*)d_in[21];
    const float* alpha = (const float*)d_in[22];
    const float* beta  = (const float*)d_in[23];

    float* ws    = (float*)d_ws;
    u16*   xn    = (u16*)(ws + XN_OFF);
    u16*   aggb  = (u16*)(ws + AGGB_OFF);
    float* x1    = ws + X1_OFF;
    float* q     = ws + QKV_OFF;                 // [NN][256] fp32, pre-scaled
    u16*   kv    = (u16*)(ws + QKV_OFF + NN * DD); // [NN][512] bf16 dim-interleaved
    u16*   ff1   = (u16*)(ws + QKV_OFF);         // overlays q+kv after attn
    u16*   epc   = (u16*)(ws + EP_OFF);          // [EE][32] CSR-ordered
    u16*   wt    = (u16*)(ws + WT_OFF);
    u16*   WqkvT = wt;                      // [768][256]
    u16*   WoT   = wt + 768 * 256;          // [256][256]
    u16*   W1T   = WoT + 256 * 256;         // [1024][256]
    u16*   W2T   = W1T + 1024 * 256;        // [256][1024]
    u16*   WeT   = W2T + 256 * 1024;        // [32][64]
    float* bqkv  = ws + BQKV_OFF;
    float* out   = (float*)d_out;

    int*  counts    = (int*)(ws + CSR_OFF);
    int*  row_start = counts + NN;
    int*  cursor    = row_start + NN + 1;
    int2* csr       = (int2*)(counts + 60002);       // 8B-aligned
    int*  epos      = counts + 60002 + 2 * EE;       // [EE]

    hipMemsetAsync(counts, 0, (size_t)NN * sizeof(int), stream);

    prep_kernel<<<585, 256, 0, stream>>>(Wq, Wk, Wv, Wo, W1, W2, We, bq, bk, bv,
                                         WqkvT, WoT, W1T, W2T, WeT, bqkv);

    count_kernel<<<EE / 256, 256, 0, stream>>>(ei, counts);
    scan_kernel<<<1, 1024, 0, stream>>>(counts, row_start, cursor);
    fill_kernel<<<EE / 256, 256, 0, stream>>>(ei, ew, cursor, csr, epos);

    ln_kernel<<<NN / 4, 256, 0, stream>>>(x, ln1g, ln1b, xn);

    // fused QKV GEMM: [20000 x 256] x [256 x 768] -> q fp32 (scaled) + kv bf16
    gemm_bf16<128, 128, 3><<<dim3(157, 6), 256, 0, stream>>>(
        xn, WqkvT, bqkv, q, kv, nullptr, nullptr, NN, DD, 768);

    ep_mfma<<<EE / 64, 256, 0, stream>>>(ef, WeT, be, epos, epc);

    attn_kernel<<<NN / 4, 256, 0, stream>>>(q, kv, epc, csr, row_start, aggb);

    // Wo GEMM + residual: x1 = x + alpha*(agg @ Wo + bo)  (64x128 tiles: 626 blocks)
    gemm_bf16<64, 128, 2><<<dim3(313, 2), 256, 0, stream>>>(
        aggb, WoT, bo, x1, nullptr, x, alpha, NN, DD, DD);

    ln_kernel<<<NN / 4, 256, 0, stream>>>(x1, ln2g, ln2b, xn);

    // FFN up + GELU -> bf16
    gemm_bf16<128, 128, 1><<<dim3(157, 8), 256, 0, stream>>>(
        xn, W1T, b1, nullptr, ff1, nullptr, nullptr, NN, DD, FFD);
    // FFN down + residual: out = x1 + beta*(ff1 @ W2 + b2)  (64x128 tiles)
    gemm_bf16<64, 128, 2><<<dim3(313, 2), 256, 0, stream>>>(
        ff1, W2T, b2, out, nullptr, x1, beta, NN, FFD, DD);
}

// Round 9
// 301.726 us; speedup vs baseline: 17.4766x; 1.0095x over previous
//
#include <hip/hip_runtime.h>
#include <math.h>

// Problem constants (match reference)
#define NN 20000
#define EE 320000
#define DD 256
#define HH 8
#define DHD 32
#define EDF 64
#define FFD 1024

typedef unsigned short u16;
typedef __attribute__((ext_vector_type(8))) __bf16 bf16x8;
typedef __attribute__((ext_vector_type(4))) float f32x4;

// workspace float offsets
#define XN_OFF   (0)          // xn bf16 [NN][256]
#define AGGB_OFF (2560000)    // agg bf16 [NN][256]
#define X1_OFF   (5120000)    // x1 fp32 [NN][256]
#define QKV_OFF  (10240000)   // q bf16 [NN][256] + kv bf16 [NN][512]; ff1 bf16 overlays later
#define EP_OFF   (25600000)   // epc bf16 [EE][32] (CSR-ordered edge projections)
#define WT_OFF   (35840000)   // bf16 weights: WqkvT, WoT, W1T, W2T, WeT
#define BQKV_OFF (36240000)   // bqkv fp32 [768]
#define CSR_OFF  (36250000)   // int region

__device__ __forceinline__ u16 f2bf(float f) {
    unsigned u = __float_as_uint(f);
    return (u16)((u + 0x7FFFu + ((u >> 16) & 1u)) >> 16);
}
__device__ __forceinline__ float bf2f(u16 h) {
    return __uint_as_float(((unsigned)h) << 16);
}
__device__ __forceinline__ float gelu_exact(float v) {
    return 0.5f * v * (1.0f + erff(v * 0.70710678118654752f));
}

#define GLDS16(g, l) __builtin_amdgcn_global_load_lds(             \
    (__attribute__((address_space(1))) void*)(g),                  \
    (__attribute__((address_space(3))) void*)(l), 16, 0, 0)

// -------- LayerNorm -> bf16: one wave per row --------
__global__ __launch_bounds__(256) void ln_kernel(const float* __restrict__ x,
                                                 const float* __restrict__ g,
                                                 const float* __restrict__ b,
                                                 u16* __restrict__ out) {
    int row = blockIdx.x * 4 + (threadIdx.x >> 6);
    if (row >= NN) return;
    int lane = threadIdx.x & 63;
    float4 v = *(const float4*)&x[(size_t)row * DD + lane * 4];
    float s  = v.x + v.y + v.z + v.w;
    float ss = v.x * v.x + v.y * v.y + v.z * v.z + v.w * v.w;
    #pragma unroll
    for (int o = 32; o >= 1; o >>= 1) {
        s  += __shfl_xor(s, o);
        ss += __shfl_xor(ss, o);
    }
    float mean = s * (1.0f / DD);
    float var  = ss * (1.0f / DD) - mean * mean;
    float inv  = rsqrtf(var + 1e-5f);
    float4 gg = *(const float4*)&g[lane * 4];
    float4 bb = *(const float4*)&b[lane * 4];
    ushort4 o4;
    o4.x = f2bf((v.x - mean) * inv * gg.x + bb.x);
    o4.y = f2bf((v.y - mean) * inv * gg.y + bb.y);
    o4.z = f2bf((v.z - mean) * inv * gg.z + bb.z);
    o4.w = f2bf((v.w - mean) * inv * gg.w + bb.w);
    *(ushort4*)&out[(size_t)row * DD + lane * 4] = o4;
}

// -------- weight transpose+convert body: dst[n][k] = bf16(src[k][n]) --------
__device__ __forceinline__ void convw_body(const float* __restrict__ src,
                                           u16* __restrict__ dst, int K, int N,
                                           int vb) {
    int n = vb * 4 + (threadIdx.x >> 6);
    int lane = threadIdx.x & 63;
    if (n >= N) return;
    for (int k = lane * 4; k < K; k += 256) {
        ushort4 o;
        o.x = f2bf(src[(size_t)(k + 0) * N + n]);
        o.y = f2bf(src[(size_t)(k + 1) * N + n]);
        o.z = f2bf(src[(size_t)(k + 2) * N + n]);
        o.w = f2bf(src[(size_t)(k + 3) * N + n]);
        *(ushort4*)&dst[(size_t)n * K + k] = o;
    }
}

// single merged weight-prep kernel
__global__ __launch_bounds__(256) void prep_kernel(
    const float* __restrict__ Wq, const float* __restrict__ Wk,
    const float* __restrict__ Wv, const float* __restrict__ Wo,
    const float* __restrict__ W1, const float* __restrict__ W2,
    const float* __restrict__ We,
    const float* __restrict__ bq, const float* __restrict__ bk,
    const float* __restrict__ bv,
    u16* __restrict__ WqkvT, u16* __restrict__ WoT, u16* __restrict__ W1T,
    u16* __restrict__ W2T, u16* __restrict__ WeT, float* __restrict__ bqkv) {
    int b = blockIdx.x;
    if      (b < 64)  convw_body(Wq, WqkvT,            256, 256,  b);
    else if (b < 128) convw_body(Wk, WqkvT + 65536,    256, 256,  b - 64);
    else if (b < 192) convw_body(Wv, WqkvT + 131072,   256, 256,  b - 128);
    else if (b < 256) convw_body(Wo, WoT,              256, 256,  b - 192);
    else if (b < 512) convw_body(W1, W1T,              256, 1024, b - 256);
    else if (b < 576) convw_body(W2, W2T,              1024, 256, b - 512);
    else if (b < 584) convw_body(We, WeT,              64,  32,   b - 576);
    else {
        int t = threadIdx.x;
        bqkv[t] = bq[t];
        bqkv[256 + t] = bk[t];
        bqkv[512 + t] = bv[t];
    }
}

// ======== bf16 MFMA GEMM: C = A[MxK] @ BT[NxK]^T + bias ========
// BMxBN tile, BK=64, 4 waves (2x2), 16x16x32 bf16 MFMA, XOR-swizzled LDS.
// EPI: 0 = fp32 out, 1 = gelu->bf16 out, 2 = fp32 out = res + scale*(acc+bias)
//      3 = QKV: col<256 -> q bf16 * invsqrt(dh); col>=256 -> kv bf16 dim-interleaved
//          (Cb = base of q bf16 [NN][256]; kv block starts at Cb + NN*256)
template <int BM, int BN, int EPI>
__global__ __launch_bounds__(256) void gemm_bf16(
    const u16* __restrict__ A, const u16* __restrict__ BT,
    const float* __restrict__ bias,
    float* __restrict__ Cf, u16* __restrict__ Cb,
    const float* __restrict__ res, const float* __restrict__ scale,
    int M, int K, int N)
{
    constexpr int FM = BM / 32, FN = BN / 32;
    constexpr int nA = BM / 32, nB = BN / 32;
    constexpr int NST = (nA > nB) ? nA : nB;
    __shared__ u16 Asm[BM * 64];
    __shared__ u16 Bsm[BN * 64];
    const int tid  = threadIdx.x;
    const int lane = tid & 63;
    const int w    = tid >> 6;
    const int wr   = w >> 1, wc = w & 1;
    const int bm   = blockIdx.x * BM;
    const int bn   = blockIdx.y * BN;

    f32x4 acc[FM][FN] = {};

    int st_row[NST], st_src[NST], st_dst[NST];
    #pragma unroll
    for (int i = 0; i < NST; i++) {
        int base  = i * 4096 + w * 1024;       // wave-uniform LDS byte base
        int off   = base + lane * 16;          // this lane's 16B lands here
        int row   = off >> 7;
        int inner = off & 127;
        st_row[i] = row;
        st_src[i] = (inner ^ ((row & 7) << 4)) >> 1;  // short idx within k-row
        st_dst[i] = base;
    }
    const int arow0 = wr * (BM / 2) + (lane & 15);
    const int brow0 = wc * (BN / 2) + (lane & 15);
    const int kb0   = (lane >> 4) * 16;        // byte offset of k in 128B row

    for (int k0 = 0; k0 < K; k0 += 64) {
        #pragma unroll
        for (int i = 0; i < nA; i++) {
            int r = bm + st_row[i]; if (r > M - 1) r = M - 1;
            GLDS16(A + (size_t)r * K + k0 + st_src[i], (char*)Asm + st_dst[i]);
        }
        #pragma unroll
        for (int i = 0; i < nB; i++) {
            int r = bn + st_row[i];
            GLDS16(BT + (size_t)r * K + k0 + st_src[i], (char*)Bsm + st_dst[i]);
        }
        asm volatile("s_waitcnt vmcnt(0)" ::: "memory");
        __syncthreads();
        #pragma unroll
        for (int s = 0; s < 2; s++) {
            bf16x8 af[FM], bfv[FN];
            #pragma unroll
            for (int i = 0; i < FM; i++) {
                int row  = arow0 + i * 16;
                int byte = (row << 7) + ((kb0 + s * 64) ^ ((row & 7) << 4));
                af[i] = *(const bf16x8*)((const char*)Asm + byte);
            }
            #pragma unroll
            for (int j = 0; j < FN; j++) {
                int row  = brow0 + j * 16;
                int byte = (row << 7) + ((kb0 + s * 64) ^ ((row & 7) << 4));
                bfv[j] = *(const bf16x8*)((const char*)Bsm + byte);
            }
            #pragma unroll
            for (int i = 0; i < FM; i++)
                #pragma unroll
                for (int j = 0; j < FN; j++)
                    acc[i][j] = __builtin_amdgcn_mfma_f32_16x16x32_bf16(
                        af[i], bfv[j], acc[i][j], 0, 0, 0);
        }
        __syncthreads();
    }

    float sc = 0.f;
    if constexpr (EPI == 2) sc = scale[0];
    const int col0 = bn + wc * (BN / 2) + (lane & 15);
    const int row0 = bm + wr * (BM / 2) + ((lane >> 4) << 2);
    #pragma unroll
    for (int i = 0; i < FM; i++) {
        #pragma unroll
        for (int j = 0; j < FN; j++) {
            int col = col0 + j * 16;
            float bb = bias[col];
            #pragma unroll
            for (int r = 0; r < 4; r++) {
                int row = row0 + i * 16 + r;
                if (row < M) {
                    float o = acc[i][j][r] + bb;
                    if constexpr (EPI == 1) {
                        Cb[(size_t)row * N + col] = f2bf(gelu_exact(o));
                    } else if constexpr (EPI == 2) {
                        Cf[(size_t)row * N + col] = res[(size_t)row * N + col] + sc * o;
                    } else if constexpr (EPI == 3) {
                        if (col < 256) {
                            Cb[(size_t)row * 256 + col] = f2bf(o * 0.17677669529663689f);
                        } else if (col < 512) {
                            Cb[(size_t)NN * 256 + (size_t)row * 512 + (col - 256) * 2] = f2bf(o);
                        } else {
                            Cb[(size_t)NN * 256 + (size_t)row * 512 + (col - 512) * 2 + 1] = f2bf(o);
                        }
                    } else {
                        Cf[(size_t)row * N + col] = o;
                    }
                }
            }
        }
    }
}

// -------- edge projection via MFMA, scatter-written in CSR order --------
__global__ __launch_bounds__(256) void ep_mfma(const float* __restrict__ ef,
                                               const u16* __restrict__ WeT,
                                               const float* __restrict__ be,
                                               const int* __restrict__ epos,
                                               u16* __restrict__ epc) {
    const int lane = threadIdx.x & 63;
    const int wv   = threadIdx.x >> 6;
    const int e0   = blockIdx.x * 64 + wv * 16;     // 16 edges per wave
    const int ar   = lane & 15;                      // A row within frag
    const int k8   = (lane >> 4) * 8;                // k-offset of this lane's 8 elems

    f32x4 acc[2] = {};
    #pragma unroll
    for (int s = 0; s < 2; s++) {
        const float* ap = ef + (size_t)(e0 + ar) * EDF + s * 32 + k8;
        float4 a0 = *(const float4*)ap;
        float4 a1 = *(const float4*)(ap + 4);
        bf16x8 af;
        af[0] = (__bf16)a0.x; af[1] = (__bf16)a0.y; af[2] = (__bf16)a0.z; af[3] = (__bf16)a0.w;
        af[4] = (__bf16)a1.x; af[5] = (__bf16)a1.y; af[6] = (__bf16)a1.z; af[7] = (__bf16)a1.w;
        #pragma unroll
        for (int j = 0; j < 2; j++) {
            bf16x8 bf = *(const bf16x8*)&WeT[(size_t)(j * 16 + ar) * EDF + s * 32 + k8];
            acc[j] = __builtin_amdgcn_mfma_f32_16x16x32_bf16(af, bf, acc[j], 0, 0, 0);
        }
    }
    const int row0 = (lane >> 4) << 2;
    #pragma unroll
    for (int r = 0; r < 4; r++) {
        int pos = epos[e0 + row0 + r];
        #pragma unroll
        for (int j = 0; j < 2; j++) {
            int col = j * 16 + ar;
            epc[(size_t)pos * DHD + col] = f2bf(acc[j][r] + be[col]);
        }
    }
}

// ======== CSR build over dst ========
__global__ __launch_bounds__(256) void count_kernel(const int* __restrict__ ei,
                                                    int* __restrict__ counts) {
    int e = blockIdx.x * 256 + threadIdx.x;
    if (e >= EE) return;
    atomicAdd(&counts[ei[EE + e]], 1);
}

__global__ __launch_bounds__(1024) void scan_kernel(const int* __restrict__ counts,
                                                    int* __restrict__ row_start,
                                                    int* __restrict__ cursor) {
    __shared__ int part[1024];
    const int CH = 20;
    int t = threadIdx.x;
    int base = t * CH;
    int loc[CH];
    int s = 0;
    #pragma unroll
    for (int i = 0; i < CH; i++) {
        int idx = base + i;
        int c = (idx < NN) ? counts[idx] : 0;
        loc[i] = s;
        s += c;
    }
    part[t] = s;
    __syncthreads();
    for (int o = 1; o < 1024; o <<= 1) {
        int vv = (t >= o) ? part[t - o] : 0;
        __syncthreads();
        part[t] += vv;
        __syncthreads();
    }
    int off = (t > 0) ? part[t - 1] : 0;
    #pragma unroll
    for (int i = 0; i < CH; i++) {
        int idx = base + i;
        if (idx < NN) {
            int rs = off + loc[i];
            row_start[idx] = rs;
            cursor[idx] = rs;
        }
    }
    if (t == 1023) row_start[NN] = part[1023];
}

// fill CSR with (src, ew*log2e) pairs + inverse permutation epos[e] = pos
__global__ __launch_bounds__(256) void fill_kernel(const int* __restrict__ ei,
                                                   const float* __restrict__ ew,
                                                   int* __restrict__ cursor,
                                                   int2* __restrict__ csr,
                                                   int* __restrict__ epos) {
    int e = blockIdx.x * 256 + threadIdx.x;
    if (e >= EE) return;
    int src = ei[e];
    int dst = ei[EE + e];
    int pos = atomicAdd(&cursor[dst], 1);
    csr[pos] = make_int2(src, __float_as_int(ew[e] * 1.44269504088896f));
    epos[e] = pos;
}

// ======== fused gather attention: ONE WAVE per dst node ========
// lane = h*8+g handles dims d0=h*32+g*4..+3. Per edge: csr 8B broadcast
// (src + ew*log2e), epc 64B SEQUENTIAL (CSR-ordered), kv 16B/lane coalesced.
// No max-subtraction (shift-invariant softmax, bounded scores). 4-edge
// unroll (fits VGPR budget; 8-deep regressed via compiler serialization)
// + depth-1 csr prefetch pipeline to hide the csr->kv dependent chain.
__global__ __launch_bounds__(256) void attn_kernel(const u16* __restrict__ qb,
                                                   const u16* __restrict__ kv,
                                                   const u16* __restrict__ epc,
                                                   const int2* __restrict__ csr,
                                                   const int* __restrict__ row_start,
                                                   u16* __restrict__ aggb) {
    const int dst  = blockIdx.x * 4 + (threadIdx.x >> 6);
    const int lane = threadIdx.x & 63;
    const int g    = lane & 7;
    const int d0   = (lane >> 3) * 32 + g * 4;     // first of this lane's 4 dims
    const int beg = row_start[dst];
    const int end = row_start[dst + 1];
    ushort4 q4 = *(const ushort4*)&qb[(size_t)dst * DD + d0];
    float4 qv = make_float4(bf2f(q4.x), bf2f(q4.y), bf2f(q4.z), bf2f(q4.w));
    float ss = 0.f;
    float4 acc = make_float4(0.f, 0.f, 0.f, 0.f);

    if (end > beg) {
        int2 pc[4];
        #pragma unroll
        for (int u = 0; u < 4; u++) pc[u] = csr[min(beg + u, end - 1)];
        for (int i = beg; i < end; i += 4) {
            int2 cur[4];
            #pragma unroll
            for (int u = 0; u < 4; u++) cur[u] = pc[u];
            ushort4 a[4], b[4], e4[4];
            #pragma unroll
            for (int u = 0; u < 4; u++) {
                const u16* kvr = &kv[(size_t)cur[u].x * 512 + d0 * 2];
                a[u]  = *(const ushort4*)kvr;        // k0,v0,k1,v1
                b[u]  = *(const ushort4*)(kvr + 4);  // k2,v2,k3,v3
                e4[u] = *(const ushort4*)&epc[(size_t)min(i + u, end - 1) * DHD + g * 4];
            }
            // prefetch next iteration's csr entries (hides csr->kv chain)
            #pragma unroll
            for (int u = 0; u < 4; u++) pc[u] = csr[min(i + 4 + u, end - 1)];
            float pp[4];
            #pragma unroll
            for (int u = 0; u < 4; u++) {
                float k0 = bf2f(a[u].x) + bf2f(e4[u].x);
                float k1 = bf2f(a[u].z) + bf2f(e4[u].y);
                float k2 = bf2f(b[u].x) + bf2f(e4[u].z);
                float k3 = bf2f(b[u].z) + bf2f(e4[u].w);
                pp[u] = fmaf(qv.x, k0, fmaf(qv.y, k1, fmaf(qv.z, k2, qv.w * k3)));
            }
            #pragma unroll
            for (int o = 4; o >= 1; o >>= 1) {
                #pragma unroll
                for (int u = 0; u < 4; u++) pp[u] += __shfl_xor(pp[u], o);
            }
            #pragma unroll
            for (int u = 0; u < 4; u++) {
                float wq = (i + u < end)
                         ? exp2f(pp[u] * __int_as_float(cur[u].y)) : 0.f;
                ss += wq;
                acc.x = fmaf(wq, bf2f(a[u].y), acc.x);
                acc.y = fmaf(wq, bf2f(a[u].w), acc.y);
                acc.z = fmaf(wq, bf2f(b[u].y), acc.z);
                acc.w = fmaf(wq, bf2f(b[u].w), acc.w);
            }
        }
    }
    float inv = (end > beg) ? 1.f / ss : 0.f;
    ushort4 o4;
    o4.x = f2bf(acc.x * inv);
    o4.y = f2bf(acc.y * inv);
    o4.z = f2bf(acc.z * inv);
    o4.w = f2bf(acc.w * inv);
    *(ushort4*)&aggb[(size_t)dst * DD + d0] = o4;
}

extern "C" void kernel_launch(void* const* d_in, const int* in_sizes, int n_in,
                              void* d_out, int out_size, void* d_ws, size_t ws_size,
                              hipStream_t stream) {
    const float* x    = (const float*)d_in[0];
    const float* ef   = (const float*)d_in[1];
    const float* ew   = (const float*)d_in[2];
    const int*   ei   = (const int*)d_in[3];
    const float* Wq   = (const float*)d_in[4];
    const float* bq   = (const float*)d_in[5];
    const float* Wk   = (const float*)d_in[6];
    const float* bk   = (const float*)d_in[7];
    const float* Wv   = (const float*)d_in[8];
    const float* bv   = (const float*)d_in[9];
    const float* We   = (const float*)d_in[10];
    const float* be   = (const float*)d_in[11];
    const float* Wo   = (const float*)d_in[12];
    const float* bo   = (const float*)d_in[13];
    const float* ln1g = (const float*)d_in[14];
    const float* ln1b = (const float*)d_in[15];
    const float* ln2g = (const float*)d_in[16];
    const float* ln2b = (const float*)d_in[17];
    const float* W1   = (const float*)d_in[18];
    const float* b1   = (const float*)d_in[19];
    const float* W2   = (const float*)d_in[20];
    const float* b2   = (const float*)d_in[21];
    const float* alpha = (const float*)d_in[22];
    const float* beta  = (const float*)d_in[23];

    float* ws    = (float*)d_ws;
    u16*   xn    = (u16*)(ws + XN_OFF);
    u16*   aggb  = (u16*)(ws + AGGB_OFF);
    float* x1    = ws + X1_OFF;
    u16*   qb    = (u16*)(ws + QKV_OFF);         // q bf16 [NN][256], pre-scaled
    u16*   kv    = qb + (size_t)NN * 256;        // kv bf16 [NN][512] dim-interleaved
    u16*   ff1   = (u16*)(ws + QKV_OFF);         // overlays q+kv after attn
    u16*   epc   = (u16*)(ws + EP_OFF);          // [EE][32] CSR-ordered
    u16*   wt    = (u16*)(ws + WT_OFF);
    u16*   WqkvT = wt;                      // [768][256]
    u16*   WoT   = wt + 768 * 256;          // [256][256]
    u16*   W1T   = WoT + 256 * 256;         // [1024][256]
    u16*   W2T   = W1T + 1024 * 256;        // [256][1024]
    u16*   WeT   = W2T + 256 * 1024;        // [32][64]
    float* bqkv  = ws + BQKV_OFF;
    float* out   = (float*)d_out;

    int*  counts    = (int*)(ws + CSR_OFF);
    int*  row_start = counts + NN;
    int*  cursor    = row_start + NN + 1;
    int2* csr       = (int2*)(counts + 60002);       // 8B-aligned
    int*  epos      = counts + 60002 + 2 * EE;       // [EE]

    hipMemsetAsync(counts, 0, (size_t)NN * sizeof(int), stream);

    prep_kernel<<<585, 256, 0, stream>>>(Wq, Wk, Wv, Wo, W1, W2, We, bq, bk, bv,
                                         WqkvT, WoT, W1T, W2T, WeT, bqkv);

    count_kernel<<<EE / 256, 256, 0, stream>>>(ei, counts);
    scan_kernel<<<1, 1024, 0, stream>>>(counts, row_start, cursor);
    fill_kernel<<<EE / 256, 256, 0, stream>>>(ei, ew, cursor, csr, epos);

    ln_kernel<<<NN / 4, 256, 0, stream>>>(x, ln1g, ln1b, xn);

    // fused QKV GEMM: [20000 x 256] x [256 x 768] -> q bf16 (scaled) + kv bf16
    gemm_bf16<128, 128, 3><<<dim3(157, 6), 256, 0, stream>>>(
        xn, WqkvT, bqkv, nullptr, qb, nullptr, nullptr, NN, DD, 768);

    ep_mfma<<<EE / 64, 256, 0, stream>>>(ef, WeT, be, epos, epc);

    attn_kernel<<<NN / 4, 256, 0, stream>>>(qb, kv, epc, csr, row_start, aggb);

    // Wo GEMM + residual: x1 = x + alpha*(agg @ Wo + bo)  (64x128 tiles: 626 blocks)
    gemm_bf16<64, 128, 2><<<dim3(313, 2), 256, 0, stream>>>(
        aggb, WoT, bo, x1, nullptr, x, alpha, NN, DD, DD);

    ln_kernel<<<NN / 4, 256, 0, stream>>>(x1, ln2g, ln2b, xn);

    // FFN up + GELU -> bf16
    gemm_bf16<128, 128, 1><<<dim3(157, 8), 256, 0, stream>>>(
        xn, W1T, b1, nullptr, ff1, nullptr, nullptr, NN, DD, FFD);
    // FFN down + residual: out = x1 + beta*(ff1 @ W2 + b2)  (64x128 tiles)
    gemm_bf16<64, 128, 2><<<dim3(313, 2), 256, 0, stream>>>(
        ff1, W2T, b2, out, nullptr, x1, beta, NN, FFD, DD);
}

// Round 10
// 269.877 us; speedup vs baseline: 19.5391x; 1.1180x over previous
//
#include <hip/hip_runtime.h>
#include <math.h>

// Problem constants (match reference)
#define NN 20000
#define EE 320000
#define DD 256
#define HH 8
#define DHD 32
#define EDF 64
#define FFD 1024

typedef unsigned short u16;
typedef __attribute__((ext_vector_type(8))) __bf16 bf16x8;
typedef __attribute__((ext_vector_type(8))) unsigned short u16x8;
typedef __attribute__((ext_vector_type(4))) float f32x4;

// workspace float offsets
#define XN_OFF   (0)          // xn bf16 [NN][256]
#define AGGB_OFF (2560000)    // agg bf16 [NN][256]
#define X1_OFF   (5120000)    // x1 fp32 [NN][256]
#define QKV_OFF  (10240000)   // q bf16 [NN][256] + kv bf16 [NN][512]; ff1 bf16 overlays later
#define EP_OFF   (25600000)   // epc bf16 [EE][32] (CSR-ordered edge projections)
#define WT_OFF   (35840000)   // bf16 weights: WqkvT, WoT, W1T, W2T, WeT
#define BQKV_OFF (36240000)   // bqkv fp32 [768]
#define CSR_OFF  (36250000)   // int region

__device__ __forceinline__ u16 f2bf(float f) {
    unsigned u = __float_as_uint(f);
    return (u16)((u + 0x7FFFu + ((u >> 16) & 1u)) >> 16);
}
__device__ __forceinline__ float bf2f(u16 h) {
    return __uint_as_float(((unsigned)h) << 16);
}
__device__ __forceinline__ float gelu_exact(float v) {
    return 0.5f * v * (1.0f + erff(v * 0.70710678118654752f));
}

#define GLDS16(g, l) __builtin_amdgcn_global_load_lds(             \
    (__attribute__((address_space(1))) void*)(g),                  \
    (__attribute__((address_space(3))) void*)(l), 16, 0, 0)

// -------- LayerNorm -> bf16 body: 4 rows per block --------
__device__ __forceinline__ void ln_body(const float* __restrict__ x,
                                        const float* __restrict__ g,
                                        const float* __restrict__ b,
                                        u16* __restrict__ out, int vb) {
    int row = vb * 4 + (threadIdx.x >> 6);
    if (row >= NN) return;
    int lane = threadIdx.x & 63;
    float4 v = *(const float4*)&x[(size_t)row * DD + lane * 4];
    float s  = v.x + v.y + v.z + v.w;
    float ss = v.x * v.x + v.y * v.y + v.z * v.z + v.w * v.w;
    #pragma unroll
    for (int o = 32; o >= 1; o >>= 1) {
        s  += __shfl_xor(s, o);
        ss += __shfl_xor(ss, o);
    }
    float mean = s * (1.0f / DD);
    float var  = ss * (1.0f / DD) - mean * mean;
    float inv  = rsqrtf(var + 1e-5f);
    float4 gg = *(const float4*)&g[lane * 4];
    float4 bb = *(const float4*)&b[lane * 4];
    ushort4 o4;
    o4.x = f2bf((v.x - mean) * inv * gg.x + bb.x);
    o4.y = f2bf((v.y - mean) * inv * gg.y + bb.y);
    o4.z = f2bf((v.z - mean) * inv * gg.z + bb.z);
    o4.w = f2bf((v.w - mean) * inv * gg.w + bb.w);
    *(ushort4*)&out[(size_t)row * DD + lane * 4] = o4;
}

__global__ __launch_bounds__(256) void ln_kernel(const float* __restrict__ x,
                                                 const float* __restrict__ g,
                                                 const float* __restrict__ b,
                                                 u16* __restrict__ out) {
    ln_body(x, g, b, out, blockIdx.x);
}

// -------- weight transpose+convert body: dst[n][k] = bf16(src[k][n]) --------
__device__ __forceinline__ void convw_body(const float* __restrict__ src,
                                           u16* __restrict__ dst, int K, int N,
                                           int vb) {
    int n = vb * 4 + (threadIdx.x >> 6);
    int lane = threadIdx.x & 63;
    if (n >= N) return;
    for (int k = lane * 4; k < K; k += 256) {
        ushort4 o;
        o.x = f2bf(src[(size_t)(k + 0) * N + n]);
        o.y = f2bf(src[(size_t)(k + 1) * N + n]);
        o.z = f2bf(src[(size_t)(k + 2) * N + n]);
        o.w = f2bf(src[(size_t)(k + 3) * N + n]);
        *(ushort4*)&dst[(size_t)n * K + k] = o;
    }
}

// ======== merged: weight prep (585 blk) + CSR count (1250 blk) + LN1 (5000 blk)
__global__ __launch_bounds__(256) void prep_count_ln_kernel(
    const float* __restrict__ Wq, const float* __restrict__ Wk,
    const float* __restrict__ Wv, const float* __restrict__ Wo,
    const float* __restrict__ W1, const float* __restrict__ W2,
    const float* __restrict__ We,
    const float* __restrict__ bq, const float* __restrict__ bk,
    const float* __restrict__ bv,
    u16* __restrict__ WqkvT, u16* __restrict__ WoT, u16* __restrict__ W1T,
    u16* __restrict__ W2T, u16* __restrict__ WeT, float* __restrict__ bqkv,
    const int* __restrict__ ei, int* __restrict__ counts,
    const float* __restrict__ x, const float* __restrict__ ln1g,
    const float* __restrict__ ln1b, u16* __restrict__ xn) {
    int b = blockIdx.x;
    if      (b < 64)  convw_body(Wq, WqkvT,            256, 256,  b);
    else if (b < 128) convw_body(Wk, WqkvT + 65536,    256, 256,  b - 64);
    else if (b < 192) convw_body(Wv, WqkvT + 131072,   256, 256,  b - 128);
    else if (b < 256) convw_body(Wo, WoT,              256, 256,  b - 192);
    else if (b < 512) convw_body(W1, W1T,              256, 1024, b - 256);
    else if (b < 576) convw_body(W2, W2T,              1024, 256, b - 512);
    else if (b < 584) convw_body(We, WeT,              64,  32,   b - 576);
    else if (b < 585) {
        int t = threadIdx.x;
        bqkv[t] = bq[t];
        bqkv[256 + t] = bk[t];
        bqkv[512 + t] = bv[t];
    } else if (b < 1835) {
        int e = (b - 585) * 256 + threadIdx.x;
        if (e < EE) atomicAdd(&counts[ei[EE + e]], 1);
    } else {
        ln_body(x, ln1g, ln1b, xn, b - 1835);
    }
}

// ======== bf16 MFMA GEMM body: C = A[MxK] @ BT[NxK]^T + bias ========
// BMxBN tile, BK=64, 4 waves (2x2), 16x16x32 bf16 MFMA, XOR-swizzled LDS.
// EPI: 0 = fp32 out, 1 = gelu->bf16 out, 2 = fp32 out = res + scale*(acc+bias)
//      3 = QKV: col<256 -> q bf16 * invsqrt(dh); col>=256 -> kv bf16 dim-interleaved
template <int BM, int BN, int EPI>
__device__ __forceinline__ void gemm_body(
    const u16* __restrict__ A, const u16* __restrict__ BT,
    const float* __restrict__ bias,
    float* __restrict__ Cf, u16* __restrict__ Cb,
    const float* __restrict__ res, const float* __restrict__ scale,
    int M, int K, int N, int bxx, int byy)
{
    constexpr int FM = BM / 32, FN = BN / 32;
    constexpr int nA = BM / 32, nB = BN / 32;
    constexpr int NST = (nA > nB) ? nA : nB;
    __shared__ u16 Asm[BM * 64];
    __shared__ u16 Bsm[BN * 64];
    const int tid  = threadIdx.x;
    const int lane = tid & 63;
    const int w    = tid >> 6;
    const int wr   = w >> 1, wc = w & 1;
    const int bm   = bxx * BM;
    const int bn   = byy * BN;

    f32x4 acc[FM][FN] = {};

    int st_row[NST], st_src[NST], st_dst[NST];
    #pragma unroll
    for (int i = 0; i < NST; i++) {
        int base  = i * 4096 + w * 1024;       // wave-uniform LDS byte base
        int off   = base + lane * 16;          // this lane's 16B lands here
        int row   = off >> 7;
        int inner = off & 127;
        st_row[i] = row;
        st_src[i] = (inner ^ ((row & 7) << 4)) >> 1;  // short idx within k-row
        st_dst[i] = base;
    }
    const int arow0 = wr * (BM / 2) + (lane & 15);
    const int brow0 = wc * (BN / 2) + (lane & 15);
    const int kb0   = (lane >> 4) * 16;        // byte offset of k in 128B row

    for (int k0 = 0; k0 < K; k0 += 64) {
        #pragma unroll
        for (int i = 0; i < nA; i++) {
            int r = bm + st_row[i]; if (r > M - 1) r = M - 1;
            GLDS16(A + (size_t)r * K + k0 + st_src[i], (char*)Asm + st_dst[i]);
        }
        #pragma unroll
        for (int i = 0; i < nB; i++) {
            int r = bn + st_row[i];
            GLDS16(BT + (size_t)r * K + k0 + st_src[i], (char*)Bsm + st_dst[i]);
        }
        asm volatile("s_waitcnt vmcnt(0)" ::: "memory");
        __syncthreads();
        #pragma unroll
        for (int s = 0; s < 2; s++) {
            bf16x8 af[FM], bfv[FN];
            #pragma unroll
            for (int i = 0; i < FM; i++) {
                int row  = arow0 + i * 16;
                int byte = (row << 7) + ((kb0 + s * 64) ^ ((row & 7) << 4));
                af[i] = *(const bf16x8*)((const char*)Asm + byte);
            }
            #pragma unroll
            for (int j = 0; j < FN; j++) {
                int row  = brow0 + j * 16;
                int byte = (row << 7) + ((kb0 + s * 64) ^ ((row & 7) << 4));
                bfv[j] = *(const bf16x8*)((const char*)Bsm + byte);
            }
            #pragma unroll
            for (int i = 0; i < FM; i++)
                #pragma unroll
                for (int j = 0; j < FN; j++)
                    acc[i][j] = __builtin_amdgcn_mfma_f32_16x16x32_bf16(
                        af[i], bfv[j], acc[i][j], 0, 0, 0);
        }
        __syncthreads();
    }

    float sc = 0.f;
    if constexpr (EPI == 2) sc = scale[0];
    const int col0 = bn + wc * (BN / 2) + (lane & 15);
    const int row0 = bm + wr * (BM / 2) + ((lane >> 4) << 2);
    #pragma unroll
    for (int i = 0; i < FM; i++) {
        #pragma unroll
        for (int j = 0; j < FN; j++) {
            int col = col0 + j * 16;
            float bb = bias[col];
            #pragma unroll
            for (int r = 0; r < 4; r++) {
                int row = row0 + i * 16 + r;
                if (row < M) {
                    float o = acc[i][j][r] + bb;
                    if constexpr (EPI == 1) {
                        Cb[(size_t)row * N + col] = f2bf(gelu_exact(o));
                    } else if constexpr (EPI == 2) {
                        Cf[(size_t)row * N + col] = res[(size_t)row * N + col] + sc * o;
                    } else if constexpr (EPI == 3) {
                        if (col < 256) {
                            Cb[(size_t)row * 256 + col] = f2bf(o * 0.17677669529663689f);
                        } else if (col < 512) {
                            Cb[(size_t)NN * 256 + (size_t)row * 512 + (col - 256) * 2] = f2bf(o);
                        } else {
                            Cb[(size_t)NN * 256 + (size_t)row * 512 + (col - 512) * 2 + 1] = f2bf(o);
                        }
                    } else {
                        Cf[(size_t)row * N + col] = o;
                    }
                }
            }
        }
    }
}

template <int BM, int BN, int EPI>
__global__ __launch_bounds__(256) void gemm_bf16(
    const u16* __restrict__ A, const u16* __restrict__ BT,
    const float* __restrict__ bias,
    float* __restrict__ Cf, u16* __restrict__ Cb,
    const float* __restrict__ res, const float* __restrict__ scale,
    int M, int K, int N) {
    gemm_body<BM, BN, EPI>(A, BT, bias, Cf, Cb, res, scale, M, K, N,
                           blockIdx.x, blockIdx.y);
}

// -------- edge projection via MFMA body, scatter-written in CSR order --------
__device__ __forceinline__ void ep_body(const float* __restrict__ ef,
                                        const u16* __restrict__ WeT,
                                        const float* __restrict__ be,
                                        const int* __restrict__ epos,
                                        u16* __restrict__ epc, int blk) {
    const int lane = threadIdx.x & 63;
    const int wv   = threadIdx.x >> 6;
    const int e0   = blk * 64 + wv * 16;            // 16 edges per wave
    const int ar   = lane & 15;                      // A row within frag
    const int k8   = (lane >> 4) * 8;                // k-offset of this lane's 8 elems

    f32x4 acc[2] = {};
    #pragma unroll
    for (int s = 0; s < 2; s++) {
        const float* ap = ef + (size_t)(e0 + ar) * EDF + s * 32 + k8;
        float4 a0 = *(const float4*)ap;
        float4 a1 = *(const float4*)(ap + 4);
        bf16x8 af;
        af[0] = (__bf16)a0.x; af[1] = (__bf16)a0.y; af[2] = (__bf16)a0.z; af[3] = (__bf16)a0.w;
        af[4] = (__bf16)a1.x; af[5] = (__bf16)a1.y; af[6] = (__bf16)a1.z; af[7] = (__bf16)a1.w;
        #pragma unroll
        for (int j = 0; j < 2; j++) {
            bf16x8 bf = *(const bf16x8*)&WeT[(size_t)(j * 16 + ar) * EDF + s * 32 + k8];
            acc[j] = __builtin_amdgcn_mfma_f32_16x16x32_bf16(af, bf, acc[j], 0, 0, 0);
        }
    }
    const int row0 = (lane >> 4) << 2;
    #pragma unroll
    for (int r = 0; r < 4; r++) {
        int pos = epos[e0 + row0 + r];
        #pragma unroll
        for (int j = 0; j < 2; j++) {
            int col = j * 16 + ar;
            epc[(size_t)pos * DHD + col] = f2bf(acc[j][r] + be[col]);
        }
    }
}

// ======== merged: QKV GEMM (942 blk) + edge projection (5000 blk) ========
__global__ __launch_bounds__(256) void qkv_ep_kernel(
    const u16* __restrict__ xn, const u16* __restrict__ WqkvT,
    const float* __restrict__ bqkv, u16* __restrict__ qb,
    const float* __restrict__ ef, const u16* __restrict__ WeT,
    const float* __restrict__ be, const int* __restrict__ epos,
    u16* __restrict__ epc) {
    int b = blockIdx.x;
    if (b < 942) {
        gemm_body<128, 128, 3>(xn, WqkvT, bqkv, nullptr, qb, nullptr, nullptr,
                               NN, DD, 768, b % 157, b / 157);
    } else {
        ep_body(ef, WeT, be, epos, epc, b - 942);
    }
}

// ======== CSR scan + fill ========
__global__ __launch_bounds__(1024) void scan_kernel(const int* __restrict__ counts,
                                                    int* __restrict__ row_start,
                                                    int* __restrict__ cursor) {
    __shared__ int part[1024];
    const int CH = 20;
    int t = threadIdx.x;
    int base = t * CH;
    int loc[CH];
    int s = 0;
    #pragma unroll
    for (int i = 0; i < CH; i++) {
        int idx = base + i;
        int c = (idx < NN) ? counts[idx] : 0;
        loc[i] = s;
        s += c;
    }
    part[t] = s;
    __syncthreads();
    for (int o = 1; o < 1024; o <<= 1) {
        int vv = (t >= o) ? part[t - o] : 0;
        __syncthreads();
        part[t] += vv;
        __syncthreads();
    }
    int off = (t > 0) ? part[t - 1] : 0;
    #pragma unroll
    for (int i = 0; i < CH; i++) {
        int idx = base + i;
        if (idx < NN) {
            int rs = off + loc[i];
            row_start[idx] = rs;
            cursor[idx] = rs;
        }
    }
    if (t == 1023) row_start[NN] = part[1023];
}

// fill CSR with (src, ew*log2e) pairs + inverse permutation epos[e] = pos
__global__ __launch_bounds__(256) void fill_kernel(const int* __restrict__ ei,
                                                   const float* __restrict__ ew,
                                                   int* __restrict__ cursor,
                                                   int2* __restrict__ csr,
                                                   int* __restrict__ epos) {
    int e = blockIdx.x * 256 + threadIdx.x;
    if (e >= EE) return;
    int src = ei[e];
    int dst = ei[EE + e];
    int pos = atomicAdd(&cursor[dst], 1);
    csr[pos] = make_int2(src, __float_as_int(ew[e] * 1.44269504088896f));
    epos[e] = pos;
}

// ======== fused gather attention: ONE WAVE per dst node ========
// lane = h*8+g handles dims d0 = (lane>>3)*32 + g*4 .. +3. Per edge: csr 8B
// broadcast (src + ew*log2e), epc 8B SEQUENTIAL (CSR-ordered), kv one 16B
// coalesced row read. No max-subtraction (shift-invariant softmax, bounded
// scores). Lean 4-edge unroll + scalar tail — every extra loop VALU op shows
// in wall time (round 8/9 lesson). Odd-beg peel keeps csr int4 loads aligned.
__global__ __launch_bounds__(256) void attn_kernel(const u16* __restrict__ qb,
                                                   const u16* __restrict__ kv,
                                                   const u16* __restrict__ epc,
                                                   const int2* __restrict__ csr,
                                                   const int* __restrict__ row_start,
                                                   u16* __restrict__ aggb) {
    const int dst  = blockIdx.x * 4 + (threadIdx.x >> 6);
    const int lane = threadIdx.x & 63;
    const int g    = lane & 7;
    const int d0   = (lane >> 3) * 32 + g * 4;     // first of this lane's 4 dims
    const int beg = row_start[dst];
    const int end = row_start[dst + 1];
    ushort4 q4 = *(const ushort4*)&qb[(size_t)dst * DD + d0];
    float4 qv = make_float4(bf2f(q4.x), bf2f(q4.y), bf2f(q4.z), bf2f(q4.w));
    float ss = 0.f;
    float4 acc = make_float4(0.f, 0.f, 0.f, 0.f);

    int i = beg;
    // peel one edge if beg is odd -> int4 csr loads stay 16B-aligned
    if ((i & 1) && i < end) {
        int2 p = csr[i];
        u16x8 kk = *(const u16x8*)&kv[(size_t)p.x * 512 + d0 * 2];
        ushort4 e4 = *(const ushort4*)&epc[(size_t)i * DHD + g * 4];
        float k0 = bf2f(kk[0]) + bf2f(e4.x);
        float k1 = bf2f(kk[2]) + bf2f(e4.y);
        float k2 = bf2f(kk[4]) + bf2f(e4.z);
        float k3 = bf2f(kk[6]) + bf2f(e4.w);
        float pv = fmaf(qv.x, k0, fmaf(qv.y, k1, fmaf(qv.z, k2, qv.w * k3)));
        #pragma unroll
        for (int o = 4; o >= 1; o >>= 1) pv += __shfl_xor(pv, o);
        float wq = exp2f(pv * __int_as_float(p.y));
        ss += wq;
        acc.x = fmaf(wq, bf2f(kk[1]), acc.x);
        acc.y = fmaf(wq, bf2f(kk[3]), acc.y);
        acc.z = fmaf(wq, bf2f(kk[5]), acc.z);
        acc.w = fmaf(wq, bf2f(kk[7]), acc.w);
        ++i;
    }
    for (; i + 4 <= end; i += 4) {
        int4 c01 = *(const int4*)&csr[i];        // src0,w0,src1,w1
        int4 c23 = *(const int4*)&csr[i + 2];    // src2,w2,src3,w3
        int   sr[4] = {c01.x, c01.z, c23.x, c23.z};
        float wt[4] = {__int_as_float(c01.y), __int_as_float(c01.w),
                       __int_as_float(c23.y), __int_as_float(c23.w)};
        u16x8 kk[4];
        ushort4 e4[4];
        #pragma unroll
        for (int u = 0; u < 4; u++) {
            kk[u] = *(const u16x8*)&kv[(size_t)sr[u] * 512 + d0 * 2];
            e4[u] = *(const ushort4*)&epc[(size_t)(i + u) * DHD + g * 4];
        }
        float pp[4];
        #pragma unroll
        for (int u = 0; u < 4; u++) {
            float k0 = bf2f(kk[u][0]) + bf2f(e4[u].x);
            float k1 = bf2f(kk[u][2]) + bf2f(e4[u].y);
            float k2 = bf2f(kk[u][4]) + bf2f(e4[u].z);
            float k3 = bf2f(kk[u][6]) + bf2f(e4[u].w);
            pp[u] = fmaf(qv.x, k0, fmaf(qv.y, k1, fmaf(qv.z, k2, qv.w * k3)));
        }
        #pragma unroll
        for (int o = 4; o >= 1; o >>= 1) {
            #pragma unroll
            for (int u = 0; u < 4; u++) pp[u] += __shfl_xor(pp[u], o);
        }
        #pragma unroll
        for (int u = 0; u < 4; u++) {
            float wq = exp2f(pp[u] * wt[u]);
            ss += wq;
            acc.x = fmaf(wq, bf2f(kk[u][1]), acc.x);
            acc.y = fmaf(wq, bf2f(kk[u][3]), acc.y);
            acc.z = fmaf(wq, bf2f(kk[u][5]), acc.z);
            acc.w = fmaf(wq, bf2f(kk[u][7]), acc.w);
        }
    }
    for (; i < end; ++i) {
        int2 p = csr[i];
        u16x8 kk = *(const u16x8*)&kv[(size_t)p.x * 512 + d0 * 2];
        ushort4 e4 = *(const ushort4*)&epc[(size_t)i * DHD + g * 4];
        float k0 = bf2f(kk[0]) + bf2f(e4.x);
        float k1 = bf2f(kk[2]) + bf2f(e4.y);
        float k2 = bf2f(kk[4]) + bf2f(e4.z);
        float k3 = bf2f(kk[6]) + bf2f(e4.w);
        float pv = fmaf(qv.x, k0, fmaf(qv.y, k1, fmaf(qv.z, k2, qv.w * k3)));
        #pragma unroll
        for (int o = 4; o >= 1; o >>= 1) pv += __shfl_xor(pv, o);
        float wq = exp2f(pv * __int_as_float(p.y));
        ss += wq;
        acc.x = fmaf(wq, bf2f(kk[1]), acc.x);
        acc.y = fmaf(wq, bf2f(kk[3]), acc.y);
        acc.z = fmaf(wq, bf2f(kk[5]), acc.z);
        acc.w = fmaf(wq, bf2f(kk[7]), acc.w);
    }
    float inv = (end > beg) ? 1.f / ss : 0.f;
    ushort4 o4;
    o4.x = f2bf(acc.x * inv);
    o4.y = f2bf(acc.y * inv);
    o4.z = f2bf(acc.z * inv);
    o4.w = f2bf(acc.w * inv);
    *(ushort4*)&aggb[(size_t)dst * DD + d0] = o4;
}

extern "C" void kernel_launch(void* const* d_in, const int* in_sizes, int n_in,
                              void* d_out, int out_size, void* d_ws, size_t ws_size,
                              hipStream_t stream) {
    const float* x    = (const float*)d_in[0];
    const float* ef   = (const float*)d_in[1];
    const float* ew   = (const float*)d_in[2];
    const int*   ei   = (const int*)d_in[3];
    const float* Wq   = (const float*)d_in[4];
    const float* bq   = (const float*)d_in[5];
    const float* Wk   = (const float*)d_in[6];
    const float* bk   = (const float*)d_in[7];
    const float* Wv   = (const float*)d_in[8];
    const float* bv   = (const float*)d_in[9];
    const float* We   = (const float*)d_in[10];
    const float* be   = (const float*)d_in[11];
    const float* Wo   = (const float*)d_in[12];
    const float* bo   = (const float*)d_in[13];
    const float* ln1g = (const float*)d_in[14];
    const float* ln1b = (const float*)d_in[15];
    const float* ln2g = (const float*)d_in[16];
    const float* ln2b = (const float*)d_in[17];
    const float* W1   = (const float*)d_in[18];
    const float* b1   = (const float*)d_in[19];
    const float* W2   = (const float*)d_in[20];
    const float* b2   = (const float*)d_in[21];
    const float* alpha = (const float*)d_in[22];
    const float* beta  = (const float*)d_in[23];

    float* ws    = (float*)d_ws;
    u16*   xn    = (u16*)(ws + XN_OFF);
    u16*   aggb  = (u16*)(ws + AGGB_OFF);
    float* x1    = ws + X1_OFF;
    u16*   qb    = (u16*)(ws + QKV_OFF);         // q bf16 [NN][256], pre-scaled
    u16*   kv    = qb + (size_t)NN * 256;        // kv bf16 [NN][512] dim-interleaved
    u16*   ff1   = (u16*)(ws + QKV_OFF);         // overlays q+kv after attn
    u16*   epc   = (u16*)(ws + EP_OFF);          // [EE][32] CSR-ordered
    u16*   wt    = (u16*)(ws + WT_OFF);
    u16*   WqkvT = wt;                      // [768][256]
    u16*   WoT   = wt + 768 * 256;          // [256][256]
    u16*   W1T   = WoT + 256 * 256;         // [1024][256]
    u16*   W2T   = W1T + 1024 * 256;        // [256][1024]
    u16*   WeT   = W2T + 256 * 1024;        // [32][64]
    float* bqkv  = ws + BQKV_OFF;
    float* out   = (float*)d_out;

    int*  counts    = (int*)(ws + CSR_OFF);
    int*  row_start = counts + NN;
    int*  cursor    = row_start + NN + 1;
    int2* csr       = (int2*)(counts + 60004);       // 16B-aligned
    int*  epos      = counts + 60004 + 2 * EE;       // [EE]

    hipMemsetAsync(counts, 0, (size_t)NN * sizeof(int), stream);

    // prep (585) + CSR count (1250) + LN1 (5000) in one launch
    prep_count_ln_kernel<<<6835, 256, 0, stream>>>(
        Wq, Wk, Wv, Wo, W1, W2, We, bq, bk, bv,
        WqkvT, WoT, W1T, W2T, WeT, bqkv, ei, counts, x, ln1g, ln1b, xn);

    scan_kernel<<<1, 1024, 0, stream>>>(counts, row_start, cursor);
    fill_kernel<<<EE / 256, 256, 0, stream>>>(ei, ew, cursor, csr, epos);

    // fused QKV GEMM (942) + edge projection (5000) in one launch
    qkv_ep_kernel<<<5942, 256, 0, stream>>>(xn, WqkvT, bqkv, qb,
                                            ef, WeT, be, epos, epc);

    attn_kernel<<<NN / 4, 256, 0, stream>>>(qb, kv, epc, csr, row_start, aggb);

    // Wo GEMM + residual: x1 = x + alpha*(agg @ Wo + bo)  (64x128 tiles)
    gemm_bf16<64, 128, 2><<<dim3(313, 2), 256, 0, stream>>>(
        aggb, WoT, bo, x1, nullptr, x, alpha, NN, DD, DD);

    ln_kernel<<<NN / 4, 256, 0, stream>>>(x1, ln2g, ln2b, xn);

    // FFN up + GELU -> bf16
    gemm_bf16<128, 128, 1><<<dim3(157, 8), 256, 0, stream>>>(
        xn, W1T, b1, nullptr, ff1, nullptr, nullptr, NN, DD, FFD);
    // FFN down + residual: out = x1 + beta*(ff1 @ W2 + b2)  (64x128 tiles)
    gemm_bf16<64, 128, 2><<<dim3(313, 2), 256, 0, stream>>>(
        ff1, W2T, b2, out, nullptr, x1, beta, NN, FFD, DD);
}

// Round 11
// 263.927 us; speedup vs baseline: 19.9795x; 1.0225x over previous
//
#include <hip/hip_runtime.h>
#include <math.h>

// Problem constants (match reference)
#define NN 20000
#define EE 320000
#define DD 256
#define HH 8
#define DHD 32
#define EDF 64
#define FFD 1024

typedef unsigned short u16;
typedef __attribute__((ext_vector_type(8))) __bf16 bf16x8;
typedef __attribute__((ext_vector_type(8))) unsigned short u16x8;
typedef __attribute__((ext_vector_type(4))) float f32x4;

// workspace float offsets
#define XN_OFF   (0)          // xn bf16 [NN][256]
#define AGGB_OFF (2560000)    // agg bf16 [NN][256]
#define X1_OFF   (5120000)    // x1 fp32 [NN][256]
#define QKV_OFF  (10240000)   // q bf16 [NN][256] + kv bf16 [NN][512]; ff1 bf16 overlays later
#define EP_OFF   (25600000)   // epc bf16 [EE][32] (CSR-ordered edge projections)
#define WT_OFF   (35840000)   // bf16 weights: WqkvT, WoT, W1T, W2T, WeT
#define BQKV_OFF (36240000)   // bqkv fp32 [768]
#define CSR_OFF  (36250000)   // int region

__device__ __forceinline__ u16 f2bf(float f) {
    unsigned u = __float_as_uint(f);
    return (u16)((u + 0x7FFFu + ((u >> 16) & 1u)) >> 16);
}
__device__ __forceinline__ float bf2f(u16 h) {
    return __uint_as_float(((unsigned)h) << 16);
}
__device__ __forceinline__ float gelu_exact(float v) {
    return 0.5f * v * (1.0f + erff(v * 0.70710678118654752f));
}

#define GLDS16(g, l) __builtin_amdgcn_global_load_lds(             \
    (__attribute__((address_space(1))) void*)(g),                  \
    (__attribute__((address_space(3))) void*)(l), 16, 0, 0)

// -------- LayerNorm -> bf16 body: 4 rows per block --------
__device__ __forceinline__ void ln_body(const float* __restrict__ x,
                                        const float* __restrict__ g,
                                        const float* __restrict__ b,
                                        u16* __restrict__ out, int vb) {
    int row = vb * 4 + (threadIdx.x >> 6);
    if (row >= NN) return;
    int lane = threadIdx.x & 63;
    float4 v = *(const float4*)&x[(size_t)row * DD + lane * 4];
    float s  = v.x + v.y + v.z + v.w;
    float ss = v.x * v.x + v.y * v.y + v.z * v.z + v.w * v.w;
    #pragma unroll
    for (int o = 32; o >= 1; o >>= 1) {
        s  += __shfl_xor(s, o);
        ss += __shfl_xor(ss, o);
    }
    float mean = s * (1.0f / DD);
    float var  = ss * (1.0f / DD) - mean * mean;
    float inv  = rsqrtf(var + 1e-5f);
    float4 gg = *(const float4*)&g[lane * 4];
    float4 bb = *(const float4*)&b[lane * 4];
    ushort4 o4;
    o4.x = f2bf((v.x - mean) * inv * gg.x + bb.x);
    o4.y = f2bf((v.y - mean) * inv * gg.y + bb.y);
    o4.z = f2bf((v.z - mean) * inv * gg.z + bb.z);
    o4.w = f2bf((v.w - mean) * inv * gg.w + bb.w);
    *(ushort4*)&out[(size_t)row * DD + lane * 4] = o4;
}

__global__ __launch_bounds__(256) void ln_kernel(const float* __restrict__ x,
                                                 const float* __restrict__ g,
                                                 const float* __restrict__ b,
                                                 u16* __restrict__ out) {
    ln_body(x, g, b, out, blockIdx.x);
}

// -------- 64x64 tile transpose+convert via LDS: dst[n][k] = bf16(src[k][n]) --
// Coalesced global read (float4 along n) and write (ushort4 x4 along k).
__device__ __forceinline__ void transp_body(const float* __restrict__ src,
                                            u16* __restrict__ dst,
                                            int K, int N, int k0, int n0) {
    __shared__ float Ws[64][65];
    int t = threadIdx.x;
    int rr = t >> 4, cc = (t & 15) * 4;
    if (n0 + cc < N) {
        #pragma unroll
        for (int p = 0; p < 4; p++) {
            int k = rr + p * 16;
            float4 v = *(const float4*)&src[(size_t)(k0 + k) * N + n0 + cc];
            Ws[k][cc + 0] = v.x; Ws[k][cc + 1] = v.y;
            Ws[k][cc + 2] = v.z; Ws[k][cc + 3] = v.w;
        }
    }
    __syncthreads();
    int n = t >> 2, kc = (t & 3) * 16;
    if (n0 + n < N) {
        u16 o[16];
        #pragma unroll
        for (int j = 0; j < 16; j++) o[j] = f2bf(Ws[kc + j][n]);
        u16* dp = dst + (size_t)(n0 + n) * K + k0 + kc;
        *(ushort4*)(dp + 0)  = *(ushort4*)&o[0];
        *(ushort4*)(dp + 4)  = *(ushort4*)&o[4];
        *(ushort4*)(dp + 8)  = *(ushort4*)&o[8];
        *(ushort4*)(dp + 12) = *(ushort4*)&o[12];
    }
}

// ======== merged: weight transpose (193) + bias (1) + CSR count (1250) + LN1 (5000)
__global__ __launch_bounds__(256) void prep_count_ln_kernel(
    const float* __restrict__ Wq, const float* __restrict__ Wk,
    const float* __restrict__ Wv, const float* __restrict__ Wo,
    const float* __restrict__ W1, const float* __restrict__ W2,
    const float* __restrict__ We,
    const float* __restrict__ bq, const float* __restrict__ bk,
    const float* __restrict__ bv,
    u16* __restrict__ WqkvT, u16* __restrict__ WoT, u16* __restrict__ W1T,
    u16* __restrict__ W2T, u16* __restrict__ WeT, float* __restrict__ bqkv,
    const int* __restrict__ ei, int* __restrict__ counts,
    const float* __restrict__ x, const float* __restrict__ ln1g,
    const float* __restrict__ ln1b, u16* __restrict__ xn) {
    int b = blockIdx.x;
    if (b < 193) {
        const float* src; u16* dst; int K, N, ti;
        if      (b < 16)  { src = Wq; dst = WqkvT;          K = 256;  N = 256;  ti = b; }
        else if (b < 32)  { src = Wk; dst = WqkvT + 65536;  K = 256;  N = 256;  ti = b - 16; }
        else if (b < 48)  { src = Wv; dst = WqkvT + 131072; K = 256;  N = 256;  ti = b - 32; }
        else if (b < 64)  { src = Wo; dst = WoT;            K = 256;  N = 256;  ti = b - 48; }
        else if (b < 128) { src = W1; dst = W1T;            K = 256;  N = 1024; ti = b - 64; }
        else if (b < 192) { src = W2; dst = W2T;            K = 1024; N = 256;  ti = b - 128; }
        else              { src = We; dst = WeT;            K = 64;   N = 32;   ti = 0; }
        int ntn = N >> 6; if (ntn == 0) ntn = 1;
        int tk = ti / ntn, tn = ti % ntn;
        transp_body(src, dst, K, N, tk * 64, tn * 64);
    } else if (b == 193) {
        int t = threadIdx.x;
        bqkv[t] = bq[t];
        bqkv[256 + t] = bk[t];
        bqkv[512 + t] = bv[t];
    } else if (b < 1444) {
        int e = (b - 194) * 256 + threadIdx.x;
        if (e < EE) atomicAdd(&counts[ei[EE + e]], 1);
    } else {
        ln_body(x, ln1g, ln1b, xn, b - 1444);
    }
}

// ======== bf16 MFMA GEMM body: C = A[MxK] @ BT[NxK]^T + bias ========
// BMxBN tile, BK=64, 4 waves (2x2), 16x16x32 bf16 MFMA, XOR-swizzled LDS.
// EPI: 0 = fp32 out, 1 = gelu->bf16 out, 2 = fp32 out = res + scale*(acc+bias)
//      3 = QKV: col<256 -> q bf16 * invsqrt(dh); col>=256 -> kv bf16 dim-interleaved
template <int BM, int BN, int EPI>
__device__ __forceinline__ void gemm_body(
    char* smem,
    const u16* __restrict__ A, const u16* __restrict__ BT,
    const float* __restrict__ bias,
    float* __restrict__ Cf, u16* __restrict__ Cb,
    const float* __restrict__ res, const float* __restrict__ scale,
    int M, int K, int N, int bxx, int byy)
{
    constexpr int FM = BM / 32, FN = BN / 32;
    constexpr int nA = BM / 32, nB = BN / 32;
    constexpr int NST = (nA > nB) ? nA : nB;
    u16* Asm = (u16*)smem;
    u16* Bsm = (u16*)(smem + BM * 64 * 2);
    const int tid  = threadIdx.x;
    const int lane = tid & 63;
    const int w    = tid >> 6;
    const int wr   = w >> 1, wc = w & 1;
    const int bm   = bxx * BM;
    const int bn   = byy * BN;

    f32x4 acc[FM][FN] = {};

    int st_row[NST], st_src[NST], st_dst[NST];
    #pragma unroll
    for (int i = 0; i < NST; i++) {
        int base  = i * 4096 + w * 1024;       // wave-uniform LDS byte base
        int off   = base + lane * 16;          // this lane's 16B lands here
        int row   = off >> 7;
        int inner = off & 127;
        st_row[i] = row;
        st_src[i] = (inner ^ ((row & 7) << 4)) >> 1;  // short idx within k-row
        st_dst[i] = base;
    }
    const int arow0 = wr * (BM / 2) + (lane & 15);
    const int brow0 = wc * (BN / 2) + (lane & 15);
    const int kb0   = (lane >> 4) * 16;        // byte offset of k in 128B row

    for (int k0 = 0; k0 < K; k0 += 64) {
        #pragma unroll
        for (int i = 0; i < nA; i++) {
            int r = bm + st_row[i]; if (r > M - 1) r = M - 1;
            GLDS16(A + (size_t)r * K + k0 + st_src[i], (char*)Asm + st_dst[i]);
        }
        #pragma unroll
        for (int i = 0; i < nB; i++) {
            int r = bn + st_row[i];
            GLDS16(BT + (size_t)r * K + k0 + st_src[i], (char*)Bsm + st_dst[i]);
        }
        asm volatile("s_waitcnt vmcnt(0)" ::: "memory");
        __syncthreads();
        #pragma unroll
        for (int s = 0; s < 2; s++) {
            bf16x8 af[FM], bfv[FN];
            #pragma unroll
            for (int i = 0; i < FM; i++) {
                int row  = arow0 + i * 16;
                int byte = (row << 7) + ((kb0 + s * 64) ^ ((row & 7) << 4));
                af[i] = *(const bf16x8*)((const char*)Asm + byte);
            }
            #pragma unroll
            for (int j = 0; j < FN; j++) {
                int row  = brow0 + j * 16;
                int byte = (row << 7) + ((kb0 + s * 64) ^ ((row & 7) << 4));
                bfv[j] = *(const bf16x8*)((const char*)Bsm + byte);
            }
            #pragma unroll
            for (int i = 0; i < FM; i++)
                #pragma unroll
                for (int j = 0; j < FN; j++)
                    acc[i][j] = __builtin_amdgcn_mfma_f32_16x16x32_bf16(
                        af[i], bfv[j], acc[i][j], 0, 0, 0);
        }
        __syncthreads();
    }

    float sc = 0.f;
    if constexpr (EPI == 2) sc = scale[0];
    const int col0 = bn + wc * (BN / 2) + (lane & 15);
    const int row0 = bm + wr * (BM / 2) + ((lane >> 4) << 2);
    #pragma unroll
    for (int i = 0; i < FM; i++) {
        #pragma unroll
        for (int j = 0; j < FN; j++) {
            int col = col0 + j * 16;
            float bb = bias[col];
            #pragma unroll
            for (int r = 0; r < 4; r++) {
                int row = row0 + i * 16 + r;
                if (row < M) {
                    float o = acc[i][j][r] + bb;
                    if constexpr (EPI == 1) {
                        Cb[(size_t)row * N + col] = f2bf(gelu_exact(o));
                    } else if constexpr (EPI == 2) {
                        Cf[(size_t)row * N + col] = res[(size_t)row * N + col] + sc * o;
                    } else if constexpr (EPI == 3) {
                        if (col < 256) {
                            Cb[(size_t)row * 256 + col] = f2bf(o * 0.17677669529663689f);
                        } else if (col < 512) {
                            Cb[(size_t)NN * 256 + (size_t)row * 512 + (col - 256) * 2] = f2bf(o);
                        } else {
                            Cb[(size_t)NN * 256 + (size_t)row * 512 + (col - 512) * 2 + 1] = f2bf(o);
                        }
                    } else {
                        Cf[(size_t)row * N + col] = o;
                    }
                }
            }
        }
    }
}

template <int BM, int BN, int EPI>
__global__ __launch_bounds__(256) void gemm_bf16(
    const u16* __restrict__ A, const u16* __restrict__ BT,
    const float* __restrict__ bias,
    float* __restrict__ Cf, u16* __restrict__ Cb,
    const float* __restrict__ res, const float* __restrict__ scale,
    int M, int K, int N) {
    __shared__ char smem[(BM + BN) * 64 * 2];
    gemm_body<BM, BN, EPI>(smem, A, BT, bias, Cf, Cb, res, scale, M, K, N,
                           blockIdx.x, blockIdx.y);
}

// -------- edge projection via MFMA, LDS-staged ef, CSR-order scatter --------
// Stage ef[64 edges][64 k] fp32 into LDS via coalesced global_load_lds with
// inverse-swizzled SOURCE (rule 21): linear LDS dest, per-lane global addr
// c = cs ^ ((e&15)<<4). Fragment reads use the matching XOR -> 2-way bank
// aliasing only (free). MFMA and scatter epilogue unchanged.
__device__ __forceinline__ void ep_body(char* smem,
                                        const float* __restrict__ ef,
                                        const u16* __restrict__ WeT,
                                        const float* __restrict__ be,
                                        const int* __restrict__ epos,
                                        u16* __restrict__ epc, int blk) {
    const int tid  = threadIdx.x;
    const int lane = tid & 63;
    const int w    = tid >> 6;
    const int e0b  = blk * 64;

    // stage 16KB: 1024 granules of 16B; wave w iter j covers granules (w*4+j)*64 + lane
    #pragma unroll
    for (int j = 0; j < 4; j++) {
        int gidx = (w * 4 + j) * 64 + lane;
        int e    = gidx >> 4;
        int cs   = (gidx & 15) << 4;               // LDS col byte (linear)
        int c    = cs ^ ((e & 15) << 4);           // pre-swizzled source col
        GLDS16((const char*)ef + (size_t)(e0b + e) * 256 + c,
               smem + (w * 4 + j) * 1024);
    }
    asm volatile("s_waitcnt vmcnt(0)" ::: "memory");
    __syncthreads();

    const int ar = lane & 15;                      // A row within frag
    const int r  = w * 16 + ar;                    // LDS row (edge in block)
    const int e0 = e0b + w * 16;                   // this wave's first edge

    f32x4 acc[2] = {};
    #pragma unroll
    for (int s = 0; s < 2; s++) {
        int cbyte = (lane >> 4) * 32 + s * 128;    // k-offset bytes (8 floats)
        const char* base = smem + r * 256;
        float4 a0 = *(const float4*)(base + ((cbyte)      ^ (ar << 4)));
        float4 a1 = *(const float4*)(base + ((cbyte + 16) ^ (ar << 4)));
        bf16x8 af;
        af[0] = (__bf16)a0.x; af[1] = (__bf16)a0.y; af[2] = (__bf16)a0.z; af[3] = (__bf16)a0.w;
        af[4] = (__bf16)a1.x; af[5] = (__bf16)a1.y; af[6] = (__bf16)a1.z; af[7] = (__bf16)a1.w;
        #pragma unroll
        for (int j = 0; j < 2; j++) {
            bf16x8 bf = *(const bf16x8*)&WeT[(size_t)(j * 16 + ar) * EDF + s * 32 + ((lane >> 4) * 8)];
            acc[j] = __builtin_amdgcn_mfma_f32_16x16x32_bf16(af, bf, acc[j], 0, 0, 0);
        }
    }
    const int row0 = (lane >> 4) << 2;
    #pragma unroll
    for (int rr = 0; rr < 4; rr++) {
        int pos = epos[e0 + row0 + rr];
        #pragma unroll
        for (int j = 0; j < 2; j++) {
            int col = j * 16 + ar;
            epc[(size_t)pos * DHD + col] = f2bf(acc[j][rr] + be[col]);
        }
    }
}

// ======== merged: QKV GEMM (942 blk) + edge projection (5000 blk) ========
__global__ __launch_bounds__(256) void qkv_ep_kernel(
    const u16* __restrict__ xn, const u16* __restrict__ WqkvT,
    const float* __restrict__ bqkv, u16* __restrict__ qb,
    const float* __restrict__ ef, const u16* __restrict__ WeT,
    const float* __restrict__ be, const int* __restrict__ epos,
    u16* __restrict__ epc) {
    __shared__ char smem[32768];
    int b = blockIdx.x;
    if (b < 942) {
        gemm_body<128, 128, 3>(smem, xn, WqkvT, bqkv, nullptr, qb, nullptr,
                               nullptr, NN, DD, 768, b % 157, b / 157);
    } else {
        ep_body(smem, ef, WeT, be, epos, epc, b - 942);
    }
}

// ======== CSR scan + fill ========
__global__ __launch_bounds__(1024) void scan_kernel(const int* __restrict__ counts,
                                                    int* __restrict__ row_start,
                                                    int* __restrict__ cursor) {
    __shared__ int part[1024];
    const int CH = 20;
    int t = threadIdx.x;
    int base = t * CH;
    int loc[CH];
    int s = 0;
    #pragma unroll
    for (int i = 0; i < CH; i++) {
        int idx = base + i;
        int c = (idx < NN) ? counts[idx] : 0;
        loc[i] = s;
        s += c;
    }
    part[t] = s;
    __syncthreads();
    for (int o = 1; o < 1024; o <<= 1) {
        int vv = (t >= o) ? part[t - o] : 0;
        __syncthreads();
        part[t] += vv;
        __syncthreads();
    }
    int off = (t > 0) ? part[t - 1] : 0;
    #pragma unroll
    for (int i = 0; i < CH; i++) {
        int idx = base + i;
        if (idx < NN) {
            int rs = off + loc[i];
            row_start[idx] = rs;
            cursor[idx] = rs;
        }
    }
    if (t == 1023) row_start[NN] = part[1023];
}

// fill CSR with (src, ew*log2e) pairs + inverse permutation epos[e] = pos
__global__ __launch_bounds__(256) void fill_kernel(const int* __restrict__ ei,
                                                   const float* __restrict__ ew,
                                                   int* __restrict__ cursor,
                                                   int2* __restrict__ csr,
                                                   int* __restrict__ epos) {
    int e = blockIdx.x * 256 + threadIdx.x;
    if (e >= EE) return;
    int src = ei[e];
    int dst = ei[EE + e];
    int pos = atomicAdd(&cursor[dst], 1);
    csr[pos] = make_int2(src, __float_as_int(ew[e] * 1.44269504088896f));
    epos[e] = pos;
}

// ======== fused gather attention: ONE WAVE per dst node ========
// lane = h*8+g handles dims d0 = (lane>>3)*32 + g*4 .. +3. Per edge: csr 8B
// broadcast (src + ew*log2e), epc 8B SEQUENTIAL (CSR-ordered), kv one 16B
// coalesced row read. No max-subtraction (shift-invariant softmax, bounded
// scores). Lean 4-edge unroll + scalar tail (round 8/9 lesson: extra loop
// VALU shows in wall time). Odd-beg peel keeps csr int4 loads aligned.
__global__ __launch_bounds__(256) void attn_kernel(const u16* __restrict__ qb,
                                                   const u16* __restrict__ kv,
                                                   const u16* __restrict__ epc,
                                                   const int2* __restrict__ csr,
                                                   const int* __restrict__ row_start,
                                                   u16* __restrict__ aggb) {
    const int dst  = blockIdx.x * 4 + (threadIdx.x >> 6);
    const int lane = threadIdx.x & 63;
    const int g    = lane & 7;
    const int d0   = (lane >> 3) * 32 + g * 4;     // first of this lane's 4 dims
    const int beg = row_start[dst];
    const int end = row_start[dst + 1];
    ushort4 q4 = *(const ushort4*)&qb[(size_t)dst * DD + d0];
    float4 qv = make_float4(bf2f(q4.x), bf2f(q4.y), bf2f(q4.z), bf2f(q4.w));
    float ss = 0.f;
    float4 acc = make_float4(0.f, 0.f, 0.f, 0.f);

    int i = beg;
    // peel one edge if beg is odd -> int4 csr loads stay 16B-aligned
    if ((i & 1) && i < end) {
        int2 p = csr[i];
        u16x8 kk = *(const u16x8*)&kv[(size_t)p.x * 512 + d0 * 2];
        ushort4 e4 = *(const ushort4*)&epc[(size_t)i * DHD + g * 4];
        float k0 = bf2f(kk[0]) + bf2f(e4.x);
        float k1 = bf2f(kk[2]) + bf2f(e4.y);
        float k2 = bf2f(kk[4]) + bf2f(e4.z);
        float k3 = bf2f(kk[6]) + bf2f(e4.w);
        float pv = fmaf(qv.x, k0, fmaf(qv.y, k1, fmaf(qv.z, k2, qv.w * k3)));
        #pragma unroll
        for (int o = 4; o >= 1; o >>= 1) pv += __shfl_xor(pv, o);
        float wq = exp2f(pv * __int_as_float(p.y));
        ss += wq;
        acc.x = fmaf(wq, bf2f(kk[1]), acc.x);
        acc.y = fmaf(wq, bf2f(kk[3]), acc.y);
        acc.z = fmaf(wq, bf2f(kk[5]), acc.z);
        acc.w = fmaf(wq, bf2f(kk[7]), acc.w);
        ++i;
    }
    for (; i + 4 <= end; i += 4) {
        int4 c01 = *(const int4*)&csr[i];        // src0,w0,src1,w1
        int4 c23 = *(const int4*)&csr[i + 2];    // src2,w2,src3,w3
        int   sr[4] = {c01.x, c01.z, c23.x, c23.z};
        float wt[4] = {__int_as_float(c01.y), __int_as_float(c01.w),
                       __int_as_float(c23.y), __int_as_float(c23.w)};
        u16x8 kk[4];
        ushort4 e4[4];
        #pragma unroll
        for (int u = 0; u < 4; u++) {
            kk[u] = *(const u16x8*)&kv[(size_t)sr[u] * 512 + d0 * 2];
            e4[u] = *(const ushort4*)&epc[(size_t)(i + u) * DHD + g * 4];
        }
        float pp[4];
        #pragma unroll
        for (int u = 0; u < 4; u++) {
            float k0 = bf2f(kk[u][0]) + bf2f(e4[u].x);
            float k1 = bf2f(kk[u][2]) + bf2f(e4[u].y);
            float k2 = bf2f(kk[u][4]) + bf2f(e4[u].z);
            float k3 = bf2f(kk[u][6]) + bf2f(e4[u].w);
            pp[u] = fmaf(qv.x, k0, fmaf(qv.y, k1, fmaf(qv.z, k2, qv.w * k3)));
        }
        #pragma unroll
        for (int o = 4; o >= 1; o >>= 1) {
            #pragma unroll
            for (int u = 0; u < 4; u++) pp[u] += __shfl_xor(pp[u], o);
        }
        #pragma unroll
        for (int u = 0; u < 4; u++) {
            float wq = exp2f(pp[u] * wt[u]);
            ss += wq;
            acc.x = fmaf(wq, bf2f(kk[u][1]), acc.x);
            acc.y = fmaf(wq, bf2f(kk[u][3]), acc.y);
            acc.z = fmaf(wq, bf2f(kk[u][5]), acc.z);
            acc.w = fmaf(wq, bf2f(kk[u][7]), acc.w);
        }
    }
    for (; i < end; ++i) {
        int2 p = csr[i];
        u16x8 kk = *(const u16x8*)&kv[(size_t)p.x * 512 + d0 * 2];
        ushort4 e4 = *(const ushort4*)&epc[(size_t)i * DHD + g * 4];
        float k0 = bf2f(kk[0]) + bf2f(e4.x);
        float k1 = bf2f(kk[2]) + bf2f(e4.y);
        float k2 = bf2f(kk[4]) + bf2f(e4.z);
        float k3 = bf2f(kk[6]) + bf2f(e4.w);
        float pv = fmaf(qv.x, k0, fmaf(qv.y, k1, fmaf(qv.z, k2, qv.w * k3)));
        #pragma unroll
        for (int o = 4; o >= 1; o >>= 1) pv += __shfl_xor(pv, o);
        float wq = exp2f(pv * __int_as_float(p.y));
        ss += wq;
        acc.x = fmaf(wq, bf2f(kk[1]), acc.x);
        acc.y = fmaf(wq, bf2f(kk[3]), acc.y);
        acc.z = fmaf(wq, bf2f(kk[5]), acc.z);
        acc.w = fmaf(wq, bf2f(kk[7]), acc.w);
    }
    float inv = (end > beg) ? 1.f / ss : 0.f;
    ushort4 o4;
    o4.x = f2bf(acc.x * inv);
    o4.y = f2bf(acc.y * inv);
    o4.z = f2bf(acc.z * inv);
    o4.w = f2bf(acc.w * inv);
    *(ushort4*)&aggb[(size_t)dst * DD + d0] = o4;
}

extern "C" void kernel_launch(void* const* d_in, const int* in_sizes, int n_in,
                              void* d_out, int out_size, void* d_ws, size_t ws_size,
                              hipStream_t stream) {
    const float* x    = (const float*)d_in[0];
    const float* ef   = (const float*)d_in[1];
    const float* ew   = (const float*)d_in[2];
    const int*   ei   = (const int*)d_in[3];
    const float* Wq   = (const float*)d_in[4];
    const float* bq   = (const float*)d_in[5];
    const float* Wk   = (const float*)d_in[6];
    const float* bk   = (const float*)d_in[7];
    const float* Wv   = (const float*)d_in[8];
    const float* bv   = (const float*)d_in[9];
    const float* We   = (const float*)d_in[10];
    const float* be   = (const float*)d_in[11];
    const float* Wo   = (const float*)d_in[12];
    const float* bo   = (const float*)d_in[13];
    const float* ln1g = (const float*)d_in[14];
    const float* ln1b = (const float*)d_in[15];
    const float* ln2g = (const float*)d_in[16];
    const float* ln2b = (const float*)d_in[17];
    const float* W1   = (const float*)d_in[18];
    const float* b1   = (const float*)d_in[19];
    const float* W2   = (const float*)d_in[20];
    const float* b2   = (const float*)d_in[21];
    const float* alpha = (const float*)d_in[22];
    const float* beta  = (const float*)d_in[23];

    float* ws    = (float*)d_ws;
    u16*   xn    = (u16*)(ws + XN_OFF);
    u16*   aggb  = (u16*)(ws + AGGB_OFF);
    float* x1    = ws + X1_OFF;
    u16*   qb    = (u16*)(ws + QKV_OFF);         // q bf16 [NN][256], pre-scaled
    u16*   kv    = qb + (size_t)NN * 256;        // kv bf16 [NN][512] dim-interleaved
    u16*   ff1   = (u16*)(ws + QKV_OFF);         // overlays q+kv after attn
    u16*   epc   = (u16*)(ws + EP_OFF);          // [EE][32] CSR-ordered
    u16*   wt    = (u16*)(ws + WT_OFF);
    u16*   WqkvT = wt;                      // [768][256]
    u16*   WoT   = wt + 768 * 256;          // [256][256]
    u16*   W1T   = WoT + 256 * 256;         // [1024][256]
    u16*   W2T   = W1T + 1024 * 256;        // [256][1024]
    u16*   WeT   = W2T + 256 * 1024;        // [32][64]
    float* bqkv  = ws + BQKV_OFF;
    float* out   = (float*)d_out;

    int*  counts    = (int*)(ws + CSR_OFF);
    int*  row_start = counts + NN;
    int*  cursor    = row_start + NN + 1;
    int2* csr       = (int2*)(counts + 60004);       // 16B-aligned
    int*  epos      = counts + 60004 + 2 * EE;       // [EE]

    hipMemsetAsync(counts, 0, (size_t)NN * sizeof(int), stream);

    // weight transpose (193) + bias (1) + CSR count (1250) + LN1 (5000)
    prep_count_ln_kernel<<<6444, 256, 0, stream>>>(
        Wq, Wk, Wv, Wo, W1, W2, We, bq, bk, bv,
        WqkvT, WoT, W1T, W2T, WeT, bqkv, ei, counts, x, ln1g, ln1b, xn);

    scan_kernel<<<1, 1024, 0, stream>>>(counts, row_start, cursor);
    fill_kernel<<<EE / 256, 256, 0, stream>>>(ei, ew, cursor, csr, epos);

    // fused QKV GEMM (942) + edge projection (5000) in one launch
    qkv_ep_kernel<<<5942, 256, 0, stream>>>(xn, WqkvT, bqkv, qb,
                                            ef, WeT, be, epos, epc);

    attn_kernel<<<NN / 4, 256, 0, stream>>>(qb, kv, epc, csr, row_start, aggb);

    // Wo GEMM + residual: x1 = x + alpha*(agg @ Wo + bo)  (64x128 tiles)
    gemm_bf16<64, 128, 2><<<dim3(313, 2), 256, 0, stream>>>(
        aggb, WoT, bo, x1, nullptr, x, alpha, NN, DD, DD);

    ln_kernel<<<NN / 4, 256, 0, stream>>>(x1, ln2g, ln2b, xn);

    // FFN up + GELU -> bf16
    gemm_bf16<128, 128, 1><<<dim3(157, 8), 256, 0, stream>>>(
        xn, W1T, b1, nullptr, ff1, nullptr, nullptr, NN, DD, FFD);
    // FFN down + residual: out = x1 + beta*(ff1 @ W2 + b2)  (64x128 tiles)
    gemm_bf16<64, 128, 2><<<dim3(313, 2), 256, 0, stream>>>(
        ff1, W2T, b2, out, nullptr, x1, beta, NN, FFD, DD);
}